// Round 6
// baseline (1095.356 us; speedup 1.0000x reference)
//
#include <hip/hip_runtime.h>
#include <math.h>

#define NG 76800
#define EG 307200
#define NL 38400
#define EL 153600
#define NB 64
#define NH 8

typedef __attribute__((ext_vector_type(8))) short bf16x8;
typedef __attribute__((ext_vector_type(4))) float f32x4;
typedef unsigned short u16;

__device__ __forceinline__ float sigmoidf(float x) { return 1.f / (1.f + expf(-x)); }
__device__ __forceinline__ u16 f2bf(float x) {
    unsigned u = __float_as_uint(x);
    return (u16)((u + 0x7FFFu + ((u >> 16) & 1u)) >> 16);
}
__device__ __forceinline__ float bf2f(u16 v) { return __uint_as_float(((unsigned)v) << 16); }

// ---------------- fp32 -> padded bf16 [M x Kpad] ----------------
__global__ __launch_bounds__(256) void convert_pad_kernel(const float* __restrict__ src,
                                                          u16* __restrict__ dst,
                                                          int M, int K, int Kpad) {
    int i = blockIdx.x * 256 + threadIdx.x;
    if (i >= M * Kpad) return;
    int m = i / Kpad, k = i - m * Kpad;
    dst[i] = (k < K) ? f2bf(src[(size_t)m * K + k]) : (u16)0;
}

// ---------------- W[K x Nfull] -> bf16 Wt[Nalloc x Kpad] (zero padded) ----------------
__global__ __launch_bounds__(256) void wtrans_kernel(const float* __restrict__ W, int ldw,
                                                     u16* __restrict__ dst,
                                                     int K, int N, int Nalloc, int Kpad) {
    int i = blockIdx.x * 256 + threadIdx.x;
    if (i >= Nalloc * Kpad) return;
    int n = i / Kpad, k = i - n * Kpad;
    dst[i] = (n < N && k < K) ? f2bf(W[(size_t)k * ldw + n]) : (u16)0;
}

// ---------------- head-padded transform: FE 36->40, 8 heads, R=320 rows ----------------
__global__ __launch_bounds__(256) void wtrans_hp_kernel(const float* __restrict__ W, int ldw,
                                                        u16* __restrict__ dst,
                                                        int K, int Kpad) {
    int i = blockIdx.x * 256 + threadIdx.x;
    if (i >= 320 * Kpad) return;
    int n = i / Kpad, k = i - n * Kpad;
    int hh = n / 40, f = n - hh * 40;
    float v = (k < K && f < 36) ? W[(size_t)k * ldw + hh * 36 + f] : 0.f;
    dst[i] = f2bf(v);
}

// ---------------- meta: padded attn1 + concat biases ----------------
__global__ __launch_bounds__(256) void meta_kernel(const float* __restrict__ attn1,
                                                   const float* __restrict__ bias1,
                                                   const float* __restrict__ b2a,
                                                   const float* __restrict__ b2b,
                                                   float* __restrict__ attn_p1,
                                                   float* __restrict__ bias_cat1,
                                                   float* __restrict__ bias_cat2a,
                                                   float* __restrict__ bias_cat2b) {
    int i = blockIdx.x * 256 + threadIdx.x;
    if (i < 320) {
        int hh = i / 40, f = i - hh * 40;
        attn_p1[i] = (f < 36) ? attn1[hh * 36 + f] : 0.f;
    } else if (i < 960) {
        int j = i - 320;
        float v = 0.f;
        if (j < 320) {
            int hh = j / 40, f = j - hh * 40;
            v = (f < 36) ? bias1[hh * 36 + f] : 0.f;
        }
        bias_cat1[j] = v;
    } else if (i < 1600) {
        int j = i - 960;
        bias_cat2a[j] = (j < 320) ? b2a[j] : 0.f;
    } else if (i < 2240) {
        int j = i - 1600;
        bias_cat2b[j] = (j < 320) ? b2b[j] : 0.f;
    }
}

// ---------------- LDS-free bf16 MFMA GEMM, LDS-staged full-line epilogue ----------------
// Staging tile padded [16][72] to break the q-group 8-way bank conflict.
template <int KPAD>
__global__ __launch_bounds__(256) void gemm_bf_kernel(const u16* __restrict__ A,
                                                      const u16* __restrict__ Wt,
                                                      const float* __restrict__ bias,
                                                      u16* __restrict__ C, int Ncols,
                                                      int Nstride) {
    __shared__ u16 st[4][16 * 72];
    const int m0 = blockIdx.x * 64;
    const int n0 = blockIdx.y * 64;
    const int wv = threadIdx.x >> 6;
    const int lane = threadIdx.x & 63;
    const int q = lane >> 4;
    const int mr = lane & 15;

    const u16* Arow = A + (size_t)(m0 + wv * 16 + mr) * KPAD;
    f32x4 acc[4];
#pragma unroll
    for (int t = 0; t < 4; ++t) acc[t] = (f32x4){0.f, 0.f, 0.f, 0.f};

#pragma unroll
    for (int k0 = 0; k0 < KPAD; k0 += 32) {
        bf16x8 af = *(const bf16x8*)(Arow + k0 + q * 8);
#pragma unroll
        for (int t = 0; t < 4; ++t) {
            bf16x8 bv = *(const bf16x8*)(Wt + (size_t)(n0 + t * 16 + mr) * KPAD + k0 + q * 8);
            acc[t] = __builtin_amdgcn_mfma_f32_16x16x32_bf16(af, bv, acc[t], 0, 0, 0);
        }
    }

    u16* myst = st[wv];
#pragma unroll
    for (int t = 0; t < 4; ++t) {
        const int colme = n0 + t * 16 + mr;
        const float bb = (bias && colme < Ncols) ? bias[colme] : 0.f;
#pragma unroll
        for (int r = 0; r < 4; ++r)
            myst[(q * 4 + r) * 72 + t * 16 + mr] = f2bf(acc[t][r] + bb);
    }
    // wave-private region: same-wave LDS ordering via lgkmcnt, no barrier needed
    const int rrow = lane >> 3;        // 0..7
    const int rcol = (lane & 7) * 8;   // 0,8,..,56
    bf16x8 v0 = *(const bf16x8*)(myst + rrow * 72 + rcol);
    bf16x8 v1 = *(const bf16x8*)(myst + (rrow + 8) * 72 + rcol);
    const int gcol = n0 + rcol;
    if (gcol < Ncols) {
        const int grow = m0 + wv * 16 + rrow;
        *(bf16x8*)(C + (size_t)grow * Nstride + gcol) = v0;
        *(bf16x8*)(C + (size_t)(grow + 8) * Nstride + gcol) = v1;
    }
}

// ---------------- ef2a = bf16(lg_ef + repeat(y2n,2)), padded to 64 ----------------
__global__ __launch_bounds__(256) void ef2a_kernel(const float* __restrict__ lg_ef,
                                                   const float* __restrict__ y2n,
                                                   u16* __restrict__ dst) {
    int i = blockIdx.x * 256 + threadIdx.x;
    if (i >= EL * 64) return;
    int e = i >> 6, c = i & 63;
    dst[i] = (c < 40) ? f2bf(lg_ef[(size_t)e * 40 + c] + y2n[(size_t)(e >> 1) * 40 + c]) : (u16)0;
}

// ---------------- FUSED: per-edge node+edge projection (MFMA) + combine ----------------
// Block = 32 consecutive edges, 256 threads (4 waves). No Pn slab at all:
// f[e] = nf[src[e]]@W_ni + nf[dst[e]]@W_nj + ef[e]@W_fij + bias, computed by
// chained MFMAs with gathered per-lane A-row pointers (nf rows are small and
// L2-hot). Phase 1 wave wv: rows (wv&1)*16..+16, cols (wv>>1)*160..+160.
// Bias enters via accumulator init (C/D layout: col==mr for all 4 regs).
// Phase 2: pure LDS+VALU combine, 8 edges per wave.
// FSMODE: 0 none; 1 fp32 out stride 36 (f<36, e<fsumE); 2 bf16 out stride 64.
// NOTE (FSMODE 2): fsum aliases ef. Safe: block reads only its own ef rows in
// phase 1, writes the same rows in phase 2, barrier between; blocks disjoint.
template <int KN, int KE, int FSMODE>
__global__ __launch_bounds__(256) void pe_edge_kernel(
    const u16* __restrict__ nf,       // [N][KN] node features bf16 (padded)
    const u16* __restrict__ ef,       // [E][KE] edge features bf16 (padded)
    const u16* __restrict__ wt_ni,    // [320][KN]
    const u16* __restrict__ wt_nj,    // [320][KN]
    const u16* __restrict__ wt_fij,   // [320][KE]
    const float* __restrict__ bias320,// [320]
    const int* __restrict__ src, const int* __restrict__ dst,
    const float* __restrict__ attn,   // [320]
    float* __restrict__ esc,          // [E][8]
    void* __restrict__ fsum,
    int fsumE) {
    constexpr int SN = KN / 32;
    constexpr int SE = KE / 32;
    __shared__ u16 pe[32][328];       // padded row pitch 656B
    const int wv = threadIdx.x >> 6;  // 0..3
    const int lane = threadIdx.x & 63;
    const int q = lane >> 4;
    const int mr = lane & 15;
    const int m0 = blockIdx.x * 32;

    // ---- phase 1: 3 chained GEMMs into LDS ----
    {
        const int rg0 = (wv & 1) * 16;
        const int t0 = (wv >> 1) * 10;
        const int er = m0 + rg0 + mr;
        const u16* pS = nf + (size_t)src[er] * KN;
        const u16* pD = nf + (size_t)dst[er] * KN;
        const u16* pE = ef + (size_t)er * KE;
        bf16x8 afs[SN], afd[SN], afe[SE];
#pragma unroll
        for (int k = 0; k < SN; ++k) {
            afs[k] = *(const bf16x8*)(pS + k * 32 + q * 8);
            afd[k] = *(const bf16x8*)(pD + k * 32 + q * 8);
        }
#pragma unroll
        for (int k = 0; k < SE; ++k) afe[k] = *(const bf16x8*)(pE + k * 32 + q * 8);

#pragma unroll
        for (int t = 0; t < 10; ++t) {
            const int nrow = (t0 + t) * 16 + mr;
            const float b = bias320[nrow];
            f32x4 a = (f32x4){b, b, b, b};
#pragma unroll
            for (int k = 0; k < SN; ++k) {
                bf16x8 bv = *(const bf16x8*)(wt_ni + (size_t)nrow * KN + k * 32 + q * 8);
                a = __builtin_amdgcn_mfma_f32_16x16x32_bf16(afs[k], bv, a, 0, 0, 0);
            }
#pragma unroll
            for (int k = 0; k < SN; ++k) {
                bf16x8 bv = *(const bf16x8*)(wt_nj + (size_t)nrow * KN + k * 32 + q * 8);
                a = __builtin_amdgcn_mfma_f32_16x16x32_bf16(afd[k], bv, a, 0, 0, 0);
            }
#pragma unroll
            for (int k = 0; k < SE; ++k) {
                bf16x8 bv = *(const bf16x8*)(wt_fij + (size_t)nrow * KE + k * 32 + q * 8);
                a = __builtin_amdgcn_mfma_f32_16x16x32_bf16(afe[k], bv, a, 0, 0, 0);
            }
#pragma unroll
            for (int r = 0; r < 4; ++r)
                pe[rg0 + q * 4 + r][(t0 + t) * 16 + mr] = f2bf(a[r]);
        }
    }
    __syncthreads();

    // ---- phase 2: combine, 8 edges per wave, pure LDS/VALU ----
    const int lc = (lane < 40) ? lane : 39;
    const int h = lc / 5, o = lc - h * 5;
    const int c = h * 40 + o * 8;
    const bool act = (lane < 40);

    float attn_r[8];
#pragma unroll
    for (int j = 0; j < 8; ++j) attn_r[j] = attn[c + j];

#pragma unroll
    for (int ei = 0; ei < 8; ++ei) {
        const int row = wv * 8 + ei;
        const int e = m0 + row;
        bf16x8 ape = *(const bf16x8*)(&pe[row][c]);

        float v[8];
        float ehp = 0.f;
#pragma unroll
        for (int j = 0; j < 8; ++j) {
            float x = bf2f((u16)ape[j]);
            x = x > 0.f ? x : 0.01f * x;   // leaky_relu(0.01)
            v[j] = x;
            ehp += x * attn_r[j];
        }
        float eh = 0.f;
#pragma unroll
        for (int k = 0; k < 5; ++k) eh += __shfl(ehp, h * 5 + k, 64);
        if (act && o == 0) esc[(size_t)e * 8 + h] = eh;

        if (FSMODE != 0 && e < fsumE) {
#pragma unroll
            for (int m = 4; m >= 1; m >>= 1) {
                const int p = (h ^ m) * 5 + o;
#pragma unroll
                for (int j = 0; j < 8; ++j) v[j] += __shfl(v[j], p, 64);
            }
            if (act && h == 0) {
#pragma unroll
                for (int j = 0; j < 8; ++j) {
                    const int f = o * 8 + j;
                    if (FSMODE == 1) {
                        if (f < 36) ((float*)fsum)[(size_t)e * 36 + f] = v[j];
                    } else {
                        ((u16*)fsum)[(size_t)e * 64 + f] = f2bf(v[j]);
                    }
                }
            }
        }
    }
}

// ---------------- CSR build ----------------
__global__ __launch_bounds__(256) void hist_kernel(const int* __restrict__ dst,
                                                   int* __restrict__ cnt, int E) {
    int i = blockIdx.x * 256 + threadIdx.x;
    if (i < E) atomicAdd(&cnt[dst[i]], 1);
}

__global__ __launch_bounds__(1024) void scan_block_kernel(const int* __restrict__ cnt,
                                                          int* __restrict__ excl,
                                                          int* __restrict__ bsum, int N) {
    __shared__ int sd[1024];
    const int tid = threadIdx.x;
    const int i = blockIdx.x * 1024 + tid;
    int v = (i < N) ? cnt[i] : 0;
    sd[tid] = v;
    __syncthreads();
    for (int off = 1; off < 1024; off <<= 1) {
        int t = (tid >= off) ? sd[tid - off] : 0;
        __syncthreads();
        sd[tid] += t;
        __syncthreads();
    }
    if (i < N) excl[i] = sd[tid] - v;
    if (tid == 1023) bsum[blockIdx.x] = sd[1023];
}

__global__ void scan_top_kernel(int* __restrict__ bsum, int nblk) {
    if (threadIdx.x == 0 && blockIdx.x == 0) {
        int run = 0;
        for (int b = 0; b < nblk; ++b) {
            int t = bsum[b];
            bsum[b] = run;
            run += t;
        }
    }
}

__global__ __launch_bounds__(256) void scan_add_kernel(int* __restrict__ row_ptr,
                                                       const int* __restrict__ bsum,
                                                       int N, int E) {
    int i = blockIdx.x * 256 + threadIdx.x;
    if (i < N) row_ptr[i] += bsum[i >> 10];
    if (i == 0) row_ptr[N] = E;
}

// scatter: eidx (edge id) + srcs_csr (source node ids, CSR order)
__global__ __launch_bounds__(256) void scatter_kernel(const int* __restrict__ dst,
                                                      const int* __restrict__ src,
                                                      const int* __restrict__ row_ptr,
                                                      int* __restrict__ cur,
                                                      int* __restrict__ eidx,
                                                      int* __restrict__ srcs, int E) {
    int i = blockIdx.x * 256 + threadIdx.x;
    if (i < E) {
        int d = dst[i];
        int pos = row_ptr[d] + atomicAdd(&cur[d], 1);
        eidx[pos] = i;
        srcs[pos] = src[i];
    }
}

// ---------------- CSR softmax: scores (edge order) -> weights in CSR order ----------------
template <int GH>
__global__ __launch_bounds__(256) void csr_softmax_kernel(
    const int* __restrict__ row_ptr, const int* __restrict__ eidx,
    const float* __restrict__ esc, float* __restrict__ wcsr, int N) {
    constexpr int NS = 64 / GH;
    const int wid = threadIdx.x >> 6;
    const int lane = threadIdx.x & 63;
    const int nid = blockIdx.x * 4 + wid;
    if (nid >= N) return;
    const int r0 = row_ptr[nid], r1 = row_ptr[nid + 1];
    const int h = lane & (GH - 1);
    const int slot = lane / GH;

    float mx = -1e30f;
    for (int i = r0 + slot; i < r1; i += NS)
        mx = fmaxf(mx, esc[(size_t)eidx[i] * GH + h]);
#pragma unroll
    for (int m = GH; m < 64; m <<= 1) mx = fmaxf(mx, __shfl_xor(mx, m, 64));

    float den = 0.f;
    for (int i = r0 + slot; i < r1; i += NS)
        den += expf(esc[(size_t)eidx[i] * GH + h] - mx);
#pragma unroll
    for (int m = GH; m < 64; m <<= 1) den += __shfl_xor(den, m, 64);
    const float rden = 1.f / den;

    for (int i = r0 + slot; i < r1; i += NS)
        wcsr[(size_t)i * GH + h] = expf(esc[(size_t)eidx[i] * GH + h] - mx) * rden;
}

// ---------------- node aggregation: 4-edge batched gathers for MLP ----------------
// OM 0: fp32 out stride Fn. OM 1: bf16 out stride 96 zero-padded 92..95.
// STR: row stride (elements) of Pnode.
template <int Fn, int GH, int OM, int STR>
__global__ __launch_bounds__(256) void node_agg_kernel(
    const int* __restrict__ row_ptr,
    const int* __restrict__ srcs,     // [E] CSR-ordered source node ids
    const float* __restrict__ wcsr,   // [E, GH] CSR-ordered softmax weights
    const u16* __restrict__ Pnode,    // [N, STR] bf16
    void* __restrict__ outp, int N) {
    constexpr int PAIRS = Fn / 2;     // Fn even: 20 / 46
    const int wid = threadIdx.x >> 6;
    const int lane = threadIdx.x & 63;
    const int nid = blockIdx.x * 4 + wid;
    if (nid >= N) return;
    const int r0 = row_ptr[nid], r1 = row_ptr[nid + 1];
    const int col = 2 * lane;
    const bool act = (lane < PAIRS);

    float a0 = 0.f, a1 = 0.f;
    for (int i = r0; i < r1; i += 4) {
        const u16* prs[4];
        float wv[4][GH];
#pragma unroll
        for (int b = 0; b < 4; ++b) {
            const int ii = (i + b < r1) ? (i + b) : (r1 - 1);
            prs[b] = Pnode + (size_t)srcs[ii] * STR;
            const float live = (i + b < r1) ? 1.f : 0.f;
            const float* wp = wcsr + (size_t)ii * GH;
#pragma unroll
            for (int hh = 0; hh < GH; ++hh) wv[b][hh] = wp[hh] * live;
        }
        if (act) {
            unsigned pv[4][GH];
#pragma unroll
            for (int b = 0; b < 4; ++b)
#pragma unroll
                for (int hh = 0; hh < GH; ++hh)
                    pv[b][hh] = *(const unsigned*)(prs[b] + hh * Fn + col);
#pragma unroll
            for (int b = 0; b < 4; ++b)
#pragma unroll
                for (int hh = 0; hh < GH; ++hh) {
                    a0 += wv[b][hh] * bf2f((u16)(pv[b][hh] & 0xFFFFu));
                    a1 += wv[b][hh] * bf2f((u16)(pv[b][hh] >> 16));
                }
        }
    }
    if (OM == 0) {
        if (act) {
            float* op = (float*)outp + (size_t)nid * Fn + col;
            op[0] = a0;
            op[1] = a1;
        }
    } else {
        unsigned* ob = (unsigned*)((u16*)outp + (size_t)nid * 96);
        if (act) {
            unsigned pk = (unsigned)f2bf(a0) | ((unsigned)f2bf(a1) << 16);
            ob[lane] = pk;
        } else if (lane < 48) {
            ob[lane] = 0u;
        }
    }
}

// ---------------- readout ----------------
__global__ __launch_bounds__(256) void readout_kernel(const u16* __restrict__ nfb,
                                                      const float* __restrict__ y22p,
                                                      const float* __restrict__ Wr1,
                                                      const float* __restrict__ br1,
                                                      const float* __restrict__ Wr2,
                                                      const float* __restrict__ br2,
                                                      float* __restrict__ out) {
    const int b = blockIdx.x;
    const int t = threadIdx.x;
    __shared__ float y[128];
    __shared__ float hh[128];
    __shared__ float red[128];
    if (t < 92) {
        float s = 0.f;
        const u16* base = nfb + (size_t)b * 600 * 96 + t;
        for (int i = 0; i < 600; ++i) s += bf2f(base[(size_t)i * 96]);
        y[t] = s * (1.f / 600.f);
    } else if (t >= 128 && t < 164) {
        int f = t - 128;
        float s = 0.f;
        const float* base = y22p + (size_t)b * 1200 * 36 + f;
        for (int i = 0; i < 1200; ++i) s += base[(size_t)i * 36];
        y[92 + f] = s * (1.f / 1200.f);
    }
    __syncthreads();
    if (t < 128) {
        float s = br1[t];
        for (int c = 0; c < 128; ++c) s += y[c] * Wr1[(size_t)c * 128 + t];
        hh[t] = sigmoidf(s);
    }
    __syncthreads();
    if (t < 128) red[t] = hh[t] * Wr2[t];
    __syncthreads();
    for (int k = 64; k > 0; k >>= 1) {
        if (t < k) red[t] += red[t + k];
        __syncthreads();
    }
    if (t == 0) out[b] = sigmoidf(red[0] + br2[0]);
}

// ---------------- host side ----------------
static inline int cdiv(int a, int b) { return (a + b - 1) / b; }

extern "C" void kernel_launch(void* const* d_in, const int* in_sizes, int n_in,
                              void* d_out, int out_size, void* d_ws, size_t ws_size,
                              hipStream_t stream) {
    const int* gg_src = (const int*)d_in[0];
    const int* gg_dst = (const int*)d_in[1];
    const float* gg_nf = (const float*)d_in[2];
    const float* gg_ef = (const float*)d_in[3];
    const int* lg_src = (const int*)d_in[4];
    const int* lg_dst = (const int*)d_in[5];
    const float* lg_nf = (const float*)d_in[6];
    const float* lg_ef = (const float*)d_in[7];
    const float* W_node1 = (const float*)d_in[8];
    const float* b_node1 = (const float*)d_in[9];
    const float* W_ni1 = (const float*)d_in[10];
    const float* W_nj1 = (const float*)d_in[11];
    const float* W_fij1 = (const float*)d_in[12];
    const float* attn1 = (const float*)d_in[13];
    const float* bias1 = (const float*)d_in[14];
    const float* W_node2a = (const float*)d_in[15];
    const float* b_node2a = (const float*)d_in[16];
    const float* W_ni2a = (const float*)d_in[17];
    const float* W_nj2a = (const float*)d_in[18];
    const float* W_fij2a = (const float*)d_in[19];
    const float* attn2a = (const float*)d_in[20];
    const float* bias2a = (const float*)d_in[21];
    const float* W_node2b = (const float*)d_in[22];
    const float* b_node2b = (const float*)d_in[23];
    const float* W_ni2b = (const float*)d_in[24];
    const float* W_nj2b = (const float*)d_in[25];
    const float* W_fij2b = (const float*)d_in[26];
    const float* attn2b = (const float*)d_in[27];
    const float* bias2b = (const float*)d_in[28];
    const float* Wr1 = (const float*)d_in[29];
    const float* br1 = (const float*)d_in[30];
    const float* Wr2 = (const float*)d_in[31];
    const float* br2 = (const float*)d_in[32];
    float* out = (float*)d_out;

    char* ws = (char*)d_ws;
    size_t off = 0;
    auto take = [&](size_t bytes) {
        size_t o = off;
        off += (bytes + 255) & ~(size_t)255;
        return (void*)(ws + o);
    };
    float* y2n = (float*)take((size_t)NG * 40 * 4);
    float* y22p = (float*)take((size_t)NG * 36 * 4);
    float* esc = (float*)take((size_t)EG * 8 * 4);
    float* wcsr = (float*)take((size_t)EG * 8 * 4);
    int* gg_row = (int*)take((size_t)(NG + 1) * 4);
    int* gg_eidx = (int*)take((size_t)EG * 4);
    int* gg_srcs = (int*)take((size_t)EG * 4);
    int* gg_cnt = (int*)take((size_t)NG * 4);
    int* lg_row = (int*)take((size_t)(NL + 1) * 4);
    int* lg_eidx = (int*)take((size_t)EL * 4);
    int* lg_srcs = (int*)take((size_t)EL * 4);
    int* lg_cnt = (int*)take((size_t)NL * 4);
    int* bsum = (int*)take((size_t)128 * 4);
    u16* gg_nf_bf = (u16*)take((size_t)NG * 64 * 2);
    u16* gg_ef_bf = (u16*)take((size_t)EG * 32 * 2);
    u16* lg_nf_bf = (u16*)take((size_t)NL * 96 * 2);
    u16* nfa_bf = (u16*)take((size_t)NL * 96 * 2);
    u16* nfb_bf = (u16*)take((size_t)NL * 96 * 2);
    u16* ef_shared = (u16*)take((size_t)EL * 64 * 2);   // ef2a input, then efa fsum
    u16* wt_ninj1 = (u16*)take((size_t)640 * 64 * 2);
    u16* wt_node1 = (u16*)take((size_t)320 * 64 * 2);
    u16* wt_fij1 = (u16*)take((size_t)320 * 32 * 2);
    u16* wt_ninj2a = (u16*)take((size_t)640 * 96 * 2);
    u16* wt_ninj2b = (u16*)take((size_t)640 * 96 * 2);
    u16* wt_fij2a = (u16*)take((size_t)320 * 64 * 2);
    u16* wt_fij2b = (u16*)take((size_t)320 * 64 * 2);
    u16* wt_node2a = (u16*)take((size_t)768 * 96 * 2);
    u16* wt_node2b = (u16*)take((size_t)768 * 96 * 2);
    float* attn_p1 = (float*)take((size_t)320 * 4);
    float* bias_cat1 = (float*)take((size_t)640 * 4);
    float* bias_cat2a = (float*)take((size_t)640 * 4);
    float* bias_cat2b = (float*)take((size_t)640 * 4);
    u16* slab = (u16*)take((size_t)NL * 768 * 2 > (size_t)NG * 320 * 2
                               ? (size_t)NL * 768 * 2
                               : (size_t)NG * 320 * 2);   // Pnode slabs only

    auto cvt = [&](const float* s, u16* d, int M, int K, int Kpad) {
        convert_pad_kernel<<<cdiv(M * Kpad, 256), 256, 0, stream>>>(s, d, M, K, Kpad);
    };
    auto wtr = [&](const float* W, int ldw, u16* d, int K, int N, int Nalloc, int Kpad) {
        wtrans_kernel<<<cdiv(Nalloc * Kpad, 256), 256, 0, stream>>>(W, ldw, d, K, N, Nalloc, Kpad);
    };
    auto build_csr = [&](const int* dst, const int* src, int* row_ptr, int* eidx, int* srcs,
                         int* cnt, int N, int E) {
        hipMemsetAsync(cnt, 0, (size_t)N * 4, stream);
        hist_kernel<<<cdiv(E, 256), 256, 0, stream>>>(dst, cnt, E);
        int nblk = cdiv(N, 1024);
        scan_block_kernel<<<nblk, 1024, 0, stream>>>(cnt, row_ptr, bsum, N);
        scan_top_kernel<<<1, 64, 0, stream>>>(bsum, nblk);
        scan_add_kernel<<<cdiv(N, 256), 256, 0, stream>>>(row_ptr, bsum, N, E);
        hipMemsetAsync(cnt, 0, (size_t)N * 4, stream);
        scatter_kernel<<<cdiv(E, 256), 256, 0, stream>>>(dst, src, row_ptr, cnt, eidx, srcs, E);
    };

    build_csr(gg_dst, gg_src, gg_row, gg_eidx, gg_srcs, gg_cnt, NG, EG);
    build_csr(lg_dst, lg_src, lg_row, lg_eidx, lg_srcs, lg_cnt, NL, EL);

    // prep: conversions + weight transforms + meta
    cvt(gg_nf, gg_nf_bf, NG, 40, 64);
    cvt(gg_ef, gg_ef_bf, EG, 10, 32);
    cvt(lg_nf, lg_nf_bf, NL, 92, 96);
    wtrans_hp_kernel<<<cdiv(320 * 64, 256), 256, 0, stream>>>(W_ni1, 288, wt_ninj1, 40, 64);
    wtrans_hp_kernel<<<cdiv(320 * 64, 256), 256, 0, stream>>>(W_nj1, 288, wt_ninj1 + 320 * 64, 40, 64);
    wtrans_hp_kernel<<<cdiv(320 * 32, 256), 256, 0, stream>>>(W_fij1, 288, wt_fij1, 10, 32);
    wtr(W_node1, 320, wt_node1, 40, 320, 320, 64);
    wtr(W_ni2a, 320, wt_ninj2a, 92, 320, 320, 96);
    wtr(W_nj2a, 320, wt_ninj2a + 320 * 96, 92, 320, 320, 96);
    wtr(W_ni2b, 320, wt_ninj2b, 92, 320, 320, 96);
    wtr(W_nj2b, 320, wt_ninj2b + 320 * 96, 92, 320, 320, 96);
    wtr(W_fij2a, 320, wt_fij2a, 40, 320, 320, 64);
    wtr(W_fij2b, 320, wt_fij2b, 40, 320, 320, 64);
    wtr(W_node2a, 736, wt_node2a, 92, 736, 768, 96);
    wtr(W_node2b, 736, wt_node2b, 92, 736, 768, 96);
    meta_kernel<<<cdiv(2240, 256), 256, 0, stream>>>(attn1, bias1, bias2a, bias2b,
                                                     attn_p1, bias_cat1, bias_cat2a, bias_cat2b);

    // ---------------- stage 1 (gg): fully fused edge pipeline ----------------
    {
        pe_edge_kernel<64, 32, 1><<<EG / 32, 256, 0, stream>>>(
            gg_nf_bf, gg_ef_bf, wt_ninj1, wt_ninj1 + 320 * 64, wt_fij1, bias_cat1,
            gg_src, gg_dst, attn_p1, esc, y22p, NG);
        csr_softmax_kernel<8><<<NG / 4, 256, 0, stream>>>(gg_row, gg_eidx, esc, wcsr, NG);
        u16* Pnode1 = slab;
        gemm_bf_kernel<64><<<dim3(NG / 64, 5), 256, 0, stream>>>(
            gg_nf_bf, wt_node1, b_node1, Pnode1, 320, 320);
        node_agg_kernel<40, 8, 0, 320><<<NG / 4, 256, 0, stream>>>(gg_row, gg_srcs, wcsr,
                                                                   Pnode1, y2n, NG);
    }

    // ef for lg layer 2a
    ef2a_kernel<<<cdiv(EL * 64, 256), 256, 0, stream>>>(lg_ef, y2n, ef_shared);

    // ---------------- stage 2 (lg), two layers ----------------
    for (int layer = 0; layer < 2; ++layer) {
        const bool a = (layer == 0);
        const u16* nf_in = a ? lg_nf_bf : nfa_bf;
        const u16* Wninj = a ? wt_ninj2a : wt_ninj2b;
        const u16* Wfij = a ? wt_fij2a : wt_fij2b;
        const u16* Wnode = a ? wt_node2a : wt_node2b;
        const float* bn = a ? b_node2a : b_node2b;
        const float* bcat = a ? bias_cat2a : bias_cat2b;
        const float* at = a ? attn2a : attn2b;
        u16* nf_out = a ? nfa_bf : nfb_bf;

        if (a)
            pe_edge_kernel<96, 64, 2><<<EL / 32, 256, 0, stream>>>(
                nf_in, ef_shared, Wninj, Wninj + 320 * 96, Wfij, bcat,
                lg_src, lg_dst, at, esc, ef_shared, EL);
        else
            pe_edge_kernel<96, 64, 0><<<EL / 32, 256, 0, stream>>>(
                nf_in, ef_shared, Wninj, Wninj + 320 * 96, Wfij, bcat,
                lg_src, lg_dst, at, esc, nullptr, 0);
        csr_softmax_kernel<8><<<NL / 4, 256, 0, stream>>>(lg_row, lg_eidx, esc, wcsr, NL);
        u16* Pnode2 = slab;   // stride 768 (row 1536B, 128B-aligned)
        gemm_bf_kernel<96><<<dim3(NL / 64, 12), 256, 0, stream>>>(nf_in, Wnode, bn, Pnode2, 736, 768);
        node_agg_kernel<92, 8, 1, 768><<<NL / 4, 256, 0, stream>>>(lg_row, lg_srcs, wcsr,
                                                                   Pnode2, nf_out, NL);
    }

    // ---------------- readout ----------------
    readout_kernel<<<NB, 256, 0, stream>>>(nfb_bf, y22p, Wr1, br1, Wr2, br2, out);
}

// Round 7
// 986.901 us; speedup vs baseline: 1.1099x; 1.1099x over previous
//
#include <hip/hip_runtime.h>
#include <math.h>

#define NG 76800
#define EG 307200
#define NL 38400
#define EL 153600
#define NB 64
#define NH 8

typedef __attribute__((ext_vector_type(8))) short bf16x8;
typedef __attribute__((ext_vector_type(4))) float f32x4;
typedef unsigned short u16;

__device__ __forceinline__ float sigmoidf(float x) { return 1.f / (1.f + expf(-x)); }
__device__ __forceinline__ u16 f2bf(float x) {
    unsigned u = __float_as_uint(x);
    return (u16)((u + 0x7FFFu + ((u >> 16) & 1u)) >> 16);
}
__device__ __forceinline__ float bf2f(u16 v) { return __uint_as_float(((unsigned)v) << 16); }

// ---------------- fp32 -> padded bf16 [M x Kpad] ----------------
__global__ __launch_bounds__(256) void convert_pad_kernel(const float* __restrict__ src,
                                                          u16* __restrict__ dst,
                                                          int M, int K, int Kpad) {
    int i = blockIdx.x * 256 + threadIdx.x;
    if (i >= M * Kpad) return;
    int m = i / Kpad, k = i - m * Kpad;
    dst[i] = (k < K) ? f2bf(src[(size_t)m * K + k]) : (u16)0;
}

// ---------------- W[K x Nfull] -> bf16 Wt[Nalloc x Kpad] (zero padded) ----------------
__global__ __launch_bounds__(256) void wtrans_kernel(const float* __restrict__ W, int ldw,
                                                     u16* __restrict__ dst,
                                                     int K, int N, int Nalloc, int Kpad) {
    int i = blockIdx.x * 256 + threadIdx.x;
    if (i >= Nalloc * Kpad) return;
    int n = i / Kpad, k = i - n * Kpad;
    dst[i] = (n < N && k < K) ? f2bf(W[(size_t)k * ldw + n]) : (u16)0;
}

// ---------------- head-padded transform: FE 36->40, 8 heads, R=320 rows ----------------
__global__ __launch_bounds__(256) void wtrans_hp_kernel(const float* __restrict__ W, int ldw,
                                                        u16* __restrict__ dst,
                                                        int K, int Kpad) {
    int i = blockIdx.x * 256 + threadIdx.x;
    if (i >= 320 * Kpad) return;
    int n = i / Kpad, k = i - n * Kpad;
    int hh = n / 40, f = n - hh * 40;
    float v = (k < K && f < 36) ? W[(size_t)k * ldw + hh * 36 + f] : 0.f;
    dst[i] = f2bf(v);
}

// ---------------- meta: padded attn1 + concat biases ----------------
__global__ __launch_bounds__(256) void meta_kernel(const float* __restrict__ attn1,
                                                   const float* __restrict__ bias1,
                                                   const float* __restrict__ b2a,
                                                   const float* __restrict__ b2b,
                                                   float* __restrict__ attn_p1,
                                                   float* __restrict__ bias_cat1,
                                                   float* __restrict__ bias_cat2a,
                                                   float* __restrict__ bias_cat2b) {
    int i = blockIdx.x * 256 + threadIdx.x;
    if (i < 320) {
        int hh = i / 40, f = i - hh * 40;
        attn_p1[i] = (f < 36) ? attn1[hh * 36 + f] : 0.f;
    } else if (i < 960) {
        int j = i - 320;
        float v = 0.f;
        if (j < 320) {
            int hh = j / 40, f = j - hh * 40;
            v = (f < 36) ? bias1[hh * 36 + f] : 0.f;
        }
        bias_cat1[j] = v;
    } else if (i < 1600) {
        int j = i - 960;
        bias_cat2a[j] = (j < 320) ? b2a[j] : 0.f;
    } else if (i < 2240) {
        int j = i - 1600;
        bias_cat2b[j] = (j < 320) ? b2b[j] : 0.f;
    }
}

// ---------------- LDS-free bf16 MFMA GEMM, LDS-staged full-line epilogue ----------------
// Staging tile padded [16][72] to break the q-group 8-way bank conflict.
template <int KPAD>
__global__ __launch_bounds__(256) void gemm_bf_kernel(const u16* __restrict__ A,
                                                      const u16* __restrict__ Wt,
                                                      const float* __restrict__ bias,
                                                      u16* __restrict__ C, int Ncols,
                                                      int Nstride) {
    __shared__ u16 st[4][16 * 72];
    const int m0 = blockIdx.x * 64;
    const int n0 = blockIdx.y * 64;
    const int wv = threadIdx.x >> 6;
    const int lane = threadIdx.x & 63;
    const int q = lane >> 4;
    const int mr = lane & 15;

    const u16* Arow = A + (size_t)(m0 + wv * 16 + mr) * KPAD;
    f32x4 acc[4];
#pragma unroll
    for (int t = 0; t < 4; ++t) acc[t] = (f32x4){0.f, 0.f, 0.f, 0.f};

#pragma unroll
    for (int k0 = 0; k0 < KPAD; k0 += 32) {
        bf16x8 af = *(const bf16x8*)(Arow + k0 + q * 8);
#pragma unroll
        for (int t = 0; t < 4; ++t) {
            bf16x8 bv = *(const bf16x8*)(Wt + (size_t)(n0 + t * 16 + mr) * KPAD + k0 + q * 8);
            acc[t] = __builtin_amdgcn_mfma_f32_16x16x32_bf16(af, bv, acc[t], 0, 0, 0);
        }
    }

    u16* myst = st[wv];
#pragma unroll
    for (int t = 0; t < 4; ++t) {
        const int colme = n0 + t * 16 + mr;
        const float bb = (bias && colme < Ncols) ? bias[colme] : 0.f;
#pragma unroll
        for (int r = 0; r < 4; ++r)
            myst[(q * 4 + r) * 72 + t * 16 + mr] = f2bf(acc[t][r] + bb);
    }
    // wave-private region: same-wave LDS ordering via lgkmcnt, no barrier needed
    const int rrow = lane >> 3;        // 0..7
    const int rcol = (lane & 7) * 8;   // 0,8,..,56
    bf16x8 v0 = *(const bf16x8*)(myst + rrow * 72 + rcol);
    bf16x8 v1 = *(const bf16x8*)(myst + (rrow + 8) * 72 + rcol);
    const int gcol = n0 + rcol;
    if (gcol < Ncols) {
        const int grow = m0 + wv * 16 + rrow;
        *(bf16x8*)(C + (size_t)grow * Nstride + gcol) = v0;
        *(bf16x8*)(C + (size_t)(grow + 8) * Nstride + gcol) = v1;
    }
}

// ---------------- ef2a = bf16(lg_ef + repeat(y2n,2)), padded to 64 ----------------
__global__ __launch_bounds__(256) void ef2a_kernel(const float* __restrict__ lg_ef,
                                                   const float* __restrict__ y2n,
                                                   u16* __restrict__ dst) {
    int i = blockIdx.x * 256 + threadIdx.x;
    if (i >= EL * 64) return;
    int e = i >> 6, c = i & 63;
    dst[i] = (c < 40) ? f2bf(lg_ef[(size_t)e * 40 + c] + y2n[(size_t)(e >> 1) * 40 + c]) : (u16)0;
}

// ---------------- FUSED: edge-projection GEMM (-> LDS) + edge combine ----------------
// Block = 32 consecutive edges, 256 threads (4 waves). LDS 21KB.
// Phase 1: Pe tile [32][320] = A[32][KPAD] @ Wt[320][KPAD]^T via MFMA into LDS.
//          Wave wv: rows (wv&1)*16..+16, col half (wv>>1)*160..+160 (acc[10]).
// Phase 2: each wave processes 8 edges; ALL 16 Pn gathers (8 edges x api+apj)
//          issued upfront into statically-indexed register buffers, so up to
//          15 stay in flight while edges drain (latency hiding via vmcnt).
// FSMODE: 0 none; 1 fp32 out stride 36 (f<36, e<fsumE); 2 bf16 out stride 64.
// NOTE (FSMODE 2): fsum may alias A (ef_shared). Safe: each block reads only
// its own A rows in phase 1 and writes only the same rows in phase 2, with a
// barrier between; blocks touch disjoint row ranges.
template <int KPAD, int FSMODE>
__global__ __launch_bounds__(256) void pe_edge_kernel(
    const u16* __restrict__ A,        // [CH][KPAD] edge features
    const u16* __restrict__ Wt,       // [320][KPAD]
    const int* __restrict__ src, const int* __restrict__ dst,
    const u16* __restrict__ Pn,       // [N][640]
    const float* __restrict__ attn,   // [320]
    float* __restrict__ esc,          // [E][8]
    void* __restrict__ fsum,
    int e0, int CH, int fsumE) {
    __shared__ u16 pe[32][328];       // padded row pitch 656B
    const int wv = threadIdx.x >> 6;  // 0..3
    const int lane = threadIdx.x & 63;
    const int q = lane >> 4;
    const int mr = lane & 15;
    const int m0 = blockIdx.x * 32;

    // ---- phase 1: GEMM into LDS ----
    {
        const int rg0 = (wv & 1) * 16;
        const int t0 = (wv >> 1) * 10;
        const u16* Arow = A + (size_t)(m0 + rg0 + mr) * KPAD;
        f32x4 acc[10];
#pragma unroll
        for (int t = 0; t < 10; ++t) acc[t] = (f32x4){0.f, 0.f, 0.f, 0.f};
#pragma unroll
        for (int k0 = 0; k0 < KPAD; k0 += 32) {
            bf16x8 af = *(const bf16x8*)(Arow + k0 + q * 8);
#pragma unroll
            for (int t = 0; t < 10; ++t) {
                bf16x8 bv = *(const bf16x8*)(Wt + (size_t)((t0 + t) * 16 + mr) * KPAD + k0 + q * 8);
                acc[t] = __builtin_amdgcn_mfma_f32_16x16x32_bf16(af, bv, acc[t], 0, 0, 0);
            }
        }
#pragma unroll
        for (int t = 0; t < 10; ++t)
#pragma unroll
            for (int r = 0; r < 4; ++r)
                pe[rg0 + q * 4 + r][(t0 + t) * 16 + mr] = f2bf(acc[t][r]);
    }
    __syncthreads();

    // ---- phase 2: combine, 8 edges per wave, all gathers upfront ----
    const int lc = (lane < 40) ? lane : 39;
    const int h = lc / 5, o = lc - h * 5;
    const int c = h * 40 + o * 8;
    const bool act = (lane < 40);

    float attn_r[8];
#pragma unroll
    for (int j = 0; j < 8; ++j) attn_r[j] = attn[c + j];

    const int ebase = e0 + m0 + wv * 8;
    bf16x8 bapi[8], bapj[8];
#pragma unroll
    for (int p = 0; p < 8; ++p) {
        const int pe_ = ebase + p;
        bapi[p] = *(const bf16x8*)(Pn + (size_t)src[pe_] * 640 + c);
        bapj[p] = *(const bf16x8*)(Pn + (size_t)dst[pe_] * 640 + 320 + c);
    }

#pragma unroll
    for (int ei = 0; ei < 8; ++ei) {
        const int row = wv * 8 + ei;
        const int e = ebase + ei;
        bf16x8 ape = *(const bf16x8*)(&pe[row][c]);

        float v[8];
        float ehp = 0.f;
#pragma unroll
        for (int j = 0; j < 8; ++j) {
            float x = bf2f((u16)bapi[ei][j]) + bf2f((u16)bapj[ei][j]) + bf2f((u16)ape[j]);
            x = x > 0.f ? x : 0.01f * x;   // leaky_relu(0.01)
            v[j] = x;
            ehp += x * attn_r[j];
        }
        float eh = 0.f;
#pragma unroll
        for (int k = 0; k < 5; ++k) eh += __shfl(ehp, h * 5 + k, 64);
        if (act && o == 0) esc[(size_t)e * 8 + h] = eh;

        if (FSMODE != 0 && e < fsumE) {
#pragma unroll
            for (int m = 4; m >= 1; m >>= 1) {
                const int p = (h ^ m) * 5 + o;
#pragma unroll
                for (int j = 0; j < 8; ++j) v[j] += __shfl(v[j], p, 64);
            }
            if (act && h == 0) {
#pragma unroll
                for (int j = 0; j < 8; ++j) {
                    const int f = o * 8 + j;
                    if (FSMODE == 1) {
                        if (f < 36) ((float*)fsum)[(size_t)e * 36 + f] = v[j];
                    } else {
                        ((u16*)fsum)[(size_t)e * 64 + f] = f2bf(v[j]);
                    }
                }
            }
        }
    }
}

// ---------------- CSR build ----------------
__global__ __launch_bounds__(256) void hist_kernel(const int* __restrict__ dst,
                                                   int* __restrict__ cnt, int E) {
    int i = blockIdx.x * 256 + threadIdx.x;
    if (i < E) atomicAdd(&cnt[dst[i]], 1);
}

__global__ __launch_bounds__(1024) void scan_block_kernel(const int* __restrict__ cnt,
                                                          int* __restrict__ excl,
                                                          int* __restrict__ bsum, int N) {
    __shared__ int sd[1024];
    const int tid = threadIdx.x;
    const int i = blockIdx.x * 1024 + tid;
    int v = (i < N) ? cnt[i] : 0;
    sd[tid] = v;
    __syncthreads();
    for (int off = 1; off < 1024; off <<= 1) {
        int t = (tid >= off) ? sd[tid - off] : 0;
        __syncthreads();
        sd[tid] += t;
        __syncthreads();
    }
    if (i < N) excl[i] = sd[tid] - v;
    if (tid == 1023) bsum[blockIdx.x] = sd[1023];
}

__global__ void scan_top_kernel(int* __restrict__ bsum, int nblk) {
    if (threadIdx.x == 0 && blockIdx.x == 0) {
        int run = 0;
        for (int b = 0; b < nblk; ++b) {
            int t = bsum[b];
            bsum[b] = run;
            run += t;
        }
    }
}

__global__ __launch_bounds__(256) void scan_add_kernel(int* __restrict__ row_ptr,
                                                       const int* __restrict__ bsum,
                                                       int N, int E) {
    int i = blockIdx.x * 256 + threadIdx.x;
    if (i < N) row_ptr[i] += bsum[i >> 10];
    if (i == 0) row_ptr[N] = E;
}

// scatter: eidx (edge id) + srcs_csr (source node ids, CSR order)
__global__ __launch_bounds__(256) void scatter_kernel(const int* __restrict__ dst,
                                                      const int* __restrict__ src,
                                                      const int* __restrict__ row_ptr,
                                                      int* __restrict__ cur,
                                                      int* __restrict__ eidx,
                                                      int* __restrict__ srcs, int E) {
    int i = blockIdx.x * 256 + threadIdx.x;
    if (i < E) {
        int d = dst[i];
        int pos = row_ptr[d] + atomicAdd(&cur[d], 1);
        eidx[pos] = i;
        srcs[pos] = src[i];
    }
}

// ---------------- CSR softmax: scores (edge order) -> weights in CSR order ----------------
template <int GH>
__global__ __launch_bounds__(256) void csr_softmax_kernel(
    const int* __restrict__ row_ptr, const int* __restrict__ eidx,
    const float* __restrict__ esc, float* __restrict__ wcsr, int N) {
    constexpr int NS = 64 / GH;
    const int wid = threadIdx.x >> 6;
    const int lane = threadIdx.x & 63;
    const int nid = blockIdx.x * 4 + wid;
    if (nid >= N) return;
    const int r0 = row_ptr[nid], r1 = row_ptr[nid + 1];
    const int h = lane & (GH - 1);
    const int slot = lane / GH;

    float mx = -1e30f;
    for (int i = r0 + slot; i < r1; i += NS)
        mx = fmaxf(mx, esc[(size_t)eidx[i] * GH + h]);
#pragma unroll
    for (int m = GH; m < 64; m <<= 1) mx = fmaxf(mx, __shfl_xor(mx, m, 64));

    float den = 0.f;
    for (int i = r0 + slot; i < r1; i += NS)
        den += expf(esc[(size_t)eidx[i] * GH + h] - mx);
#pragma unroll
    for (int m = GH; m < 64; m <<= 1) den += __shfl_xor(den, m, 64);
    const float rden = 1.f / den;

    for (int i = r0 + slot; i < r1; i += NS)
        wcsr[(size_t)i * GH + h] = expf(esc[(size_t)eidx[i] * GH + h] - mx) * rden;
}

// ---------------- node aggregation: 4-edge batched gathers for MLP ----------------
// OM 0: fp32 out stride Fn. OM 1: bf16 out stride 96 zero-padded 92..95.
// STR: row stride (elements) of Pnode.
template <int Fn, int GH, int OM, int STR>
__global__ __launch_bounds__(256) void node_agg_kernel(
    const int* __restrict__ row_ptr,
    const int* __restrict__ srcs,     // [E] CSR-ordered source node ids
    const float* __restrict__ wcsr,   // [E, GH] CSR-ordered softmax weights
    const u16* __restrict__ Pnode,    // [N, STR] bf16
    void* __restrict__ outp, int N) {
    constexpr int PAIRS = Fn / 2;     // Fn even: 20 / 46
    const int wid = threadIdx.x >> 6;
    const int lane = threadIdx.x & 63;
    const int nid = blockIdx.x * 4 + wid;
    if (nid >= N) return;
    const int r0 = row_ptr[nid], r1 = row_ptr[nid + 1];
    const int col = 2 * lane;
    const bool act = (lane < PAIRS);

    float a0 = 0.f, a1 = 0.f;
    for (int i = r0; i < r1; i += 4) {
        const u16* prs[4];
        float wv[4][GH];
#pragma unroll
        for (int b = 0; b < 4; ++b) {
            const int ii = (i + b < r1) ? (i + b) : (r1 - 1);
            prs[b] = Pnode + (size_t)srcs[ii] * STR;
            const float live = (i + b < r1) ? 1.f : 0.f;
            const float* wp = wcsr + (size_t)ii * GH;
#pragma unroll
            for (int hh = 0; hh < GH; ++hh) wv[b][hh] = wp[hh] * live;
        }
        if (act) {
            unsigned pv[4][GH];
#pragma unroll
            for (int b = 0; b < 4; ++b)
#pragma unroll
                for (int hh = 0; hh < GH; ++hh)
                    pv[b][hh] = *(const unsigned*)(prs[b] + hh * Fn + col);
#pragma unroll
            for (int b = 0; b < 4; ++b)
#pragma unroll
                for (int hh = 0; hh < GH; ++hh) {
                    a0 += wv[b][hh] * bf2f((u16)(pv[b][hh] & 0xFFFFu));
                    a1 += wv[b][hh] * bf2f((u16)(pv[b][hh] >> 16));
                }
        }
    }
    if (OM == 0) {
        if (act) {
            float* op = (float*)outp + (size_t)nid * Fn + col;
            op[0] = a0;
            op[1] = a1;
        }
    } else {
        unsigned* ob = (unsigned*)((u16*)outp + (size_t)nid * 96);
        if (act) {
            unsigned pk = (unsigned)f2bf(a0) | ((unsigned)f2bf(a1) << 16);
            ob[lane] = pk;
        } else if (lane < 48) {
            ob[lane] = 0u;
        }
    }
}

// ---------------- readout ----------------
__global__ __launch_bounds__(256) void readout_kernel(const u16* __restrict__ nfb,
                                                      const float* __restrict__ y22p,
                                                      const float* __restrict__ Wr1,
                                                      const float* __restrict__ br1,
                                                      const float* __restrict__ Wr2,
                                                      const float* __restrict__ br2,
                                                      float* __restrict__ out) {
    const int b = blockIdx.x;
    const int t = threadIdx.x;
    __shared__ float y[128];
    __shared__ float hh[128];
    __shared__ float red[128];
    if (t < 92) {
        float s = 0.f;
        const u16* base = nfb + (size_t)b * 600 * 96 + t;
        for (int i = 0; i < 600; ++i) s += bf2f(base[(size_t)i * 96]);
        y[t] = s * (1.f / 600.f);
    } else if (t >= 128 && t < 164) {
        int f = t - 128;
        float s = 0.f;
        const float* base = y22p + (size_t)b * 1200 * 36 + f;
        for (int i = 0; i < 1200; ++i) s += base[(size_t)i * 36];
        y[92 + f] = s * (1.f / 1200.f);
    }
    __syncthreads();
    if (t < 128) {
        float s = br1[t];
        for (int c = 0; c < 128; ++c) s += y[c] * Wr1[(size_t)c * 128 + t];
        hh[t] = sigmoidf(s);
    }
    __syncthreads();
    if (t < 128) red[t] = hh[t] * Wr2[t];
    __syncthreads();
    for (int k = 64; k > 0; k >>= 1) {
        if (t < k) red[t] += red[t + k];
        __syncthreads();
    }
    if (t == 0) out[b] = sigmoidf(red[0] + br2[0]);
}

// ---------------- host side ----------------
static inline int cdiv(int a, int b) { return (a + b - 1) / b; }

extern "C" void kernel_launch(void* const* d_in, const int* in_sizes, int n_in,
                              void* d_out, int out_size, void* d_ws, size_t ws_size,
                              hipStream_t stream) {
    const int* gg_src = (const int*)d_in[0];
    const int* gg_dst = (const int*)d_in[1];
    const float* gg_nf = (const float*)d_in[2];
    const float* gg_ef = (const float*)d_in[3];
    const int* lg_src = (const int*)d_in[4];
    const int* lg_dst = (const int*)d_in[5];
    const float* lg_nf = (const float*)d_in[6];
    const float* lg_ef = (const float*)d_in[7];
    const float* W_node1 = (const float*)d_in[8];
    const float* b_node1 = (const float*)d_in[9];
    const float* W_ni1 = (const float*)d_in[10];
    const float* W_nj1 = (const float*)d_in[11];
    const float* W_fij1 = (const float*)d_in[12];
    const float* attn1 = (const float*)d_in[13];
    const float* bias1 = (const float*)d_in[14];
    const float* W_node2a = (const float*)d_in[15];
    const float* b_node2a = (const float*)d_in[16];
    const float* W_ni2a = (const float*)d_in[17];
    const float* W_nj2a = (const float*)d_in[18];
    const float* W_fij2a = (const float*)d_in[19];
    const float* attn2a = (const float*)d_in[20];
    const float* bias2a = (const float*)d_in[21];
    const float* W_node2b = (const float*)d_in[22];
    const float* b_node2b = (const float*)d_in[23];
    const float* W_ni2b = (const float*)d_in[24];
    const float* W_nj2b = (const float*)d_in[25];
    const float* W_fij2b = (const float*)d_in[26];
    const float* attn2b = (const float*)d_in[27];
    const float* bias2b = (const float*)d_in[28];
    const float* Wr1 = (const float*)d_in[29];
    const float* br1 = (const float*)d_in[30];
    const float* Wr2 = (const float*)d_in[31];
    const float* br2 = (const float*)d_in[32];
    float* out = (float*)d_out;

    char* ws = (char*)d_ws;
    size_t off = 0;
    auto take = [&](size_t bytes) {
        size_t o = off;
        off += (bytes + 255) & ~(size_t)255;
        return (void*)(ws + o);
    };
    float* y2n = (float*)take((size_t)NG * 40 * 4);
    float* y22p = (float*)take((size_t)NG * 36 * 4);
    float* esc = (float*)take((size_t)EG * 8 * 4);
    float* wcsr = (float*)take((size_t)EG * 8 * 4);
    int* gg_row = (int*)take((size_t)(NG + 1) * 4);
    int* gg_eidx = (int*)take((size_t)EG * 4);
    int* gg_srcs = (int*)take((size_t)EG * 4);
    int* gg_cnt = (int*)take((size_t)NG * 4);
    int* lg_row = (int*)take((size_t)(NL + 1) * 4);
    int* lg_eidx = (int*)take((size_t)EL * 4);
    int* lg_srcs = (int*)take((size_t)EL * 4);
    int* lg_cnt = (int*)take((size_t)NL * 4);
    int* bsum = (int*)take((size_t)128 * 4);
    u16* gg_nf_bf = (u16*)take((size_t)NG * 64 * 2);
    u16* gg_ef_bf = (u16*)take((size_t)EG * 32 * 2);
    u16* lg_nf_bf = (u16*)take((size_t)NL * 96 * 2);
    u16* nfa_bf = (u16*)take((size_t)NL * 96 * 2);
    u16* nfb_bf = (u16*)take((size_t)NL * 96 * 2);
    u16* ef_shared = (u16*)take((size_t)EL * 64 * 2);   // ef2a input, then efa fsum
    u16* wt_ninj1 = (u16*)take((size_t)640 * 64 * 2);
    u16* wt_node1 = (u16*)take((size_t)320 * 64 * 2);
    u16* wt_fij1 = (u16*)take((size_t)320 * 32 * 2);
    u16* wt_ninj2a = (u16*)take((size_t)640 * 96 * 2);
    u16* wt_ninj2b = (u16*)take((size_t)640 * 96 * 2);
    u16* wt_fij2a = (u16*)take((size_t)320 * 64 * 2);
    u16* wt_fij2b = (u16*)take((size_t)320 * 64 * 2);
    u16* wt_node2a = (u16*)take((size_t)768 * 96 * 2);
    u16* wt_node2b = (u16*)take((size_t)768 * 96 * 2);
    float* attn_p1 = (float*)take((size_t)320 * 4);
    float* bias_cat1 = (float*)take((size_t)640 * 4);
    float* bias_cat2a = (float*)take((size_t)640 * 4);
    float* bias_cat2b = (float*)take((size_t)640 * 4);
    u16* slab = (u16*)take((size_t)NG * 640 * 2);   // Pn1 / Pn2 / Pnode slabs

    auto cvt = [&](const float* s, u16* d, int M, int K, int Kpad) {
        convert_pad_kernel<<<cdiv(M * Kpad, 256), 256, 0, stream>>>(s, d, M, K, Kpad);
    };
    auto wtr = [&](const float* W, int ldw, u16* d, int K, int N, int Nalloc, int Kpad) {
        wtrans_kernel<<<cdiv(Nalloc * Kpad, 256), 256, 0, stream>>>(W, ldw, d, K, N, Nalloc, Kpad);
    };
    auto build_csr = [&](const int* dst, const int* src, int* row_ptr, int* eidx, int* srcs,
                         int* cnt, int N, int E) {
        hipMemsetAsync(cnt, 0, (size_t)N * 4, stream);
        hist_kernel<<<cdiv(E, 256), 256, 0, stream>>>(dst, cnt, E);
        int nblk = cdiv(N, 1024);
        scan_block_kernel<<<nblk, 1024, 0, stream>>>(cnt, row_ptr, bsum, N);
        scan_top_kernel<<<1, 64, 0, stream>>>(bsum, nblk);
        scan_add_kernel<<<cdiv(N, 256), 256, 0, stream>>>(row_ptr, bsum, N, E);
        hipMemsetAsync(cnt, 0, (size_t)N * 4, stream);
        scatter_kernel<<<cdiv(E, 256), 256, 0, stream>>>(dst, src, row_ptr, cnt, eidx, srcs, E);
    };

    build_csr(gg_dst, gg_src, gg_row, gg_eidx, gg_srcs, gg_cnt, NG, EG);
    build_csr(lg_dst, lg_src, lg_row, lg_eidx, lg_srcs, lg_cnt, NL, EL);

    // prep: conversions + weight transforms + meta
    cvt(gg_nf, gg_nf_bf, NG, 40, 64);
    cvt(gg_ef, gg_ef_bf, EG, 10, 32);
    cvt(lg_nf, lg_nf_bf, NL, 92, 96);
    wtrans_hp_kernel<<<cdiv(320 * 64, 256), 256, 0, stream>>>(W_ni1, 288, wt_ninj1, 40, 64);
    wtrans_hp_kernel<<<cdiv(320 * 64, 256), 256, 0, stream>>>(W_nj1, 288, wt_ninj1 + 320 * 64, 40, 64);
    wtrans_hp_kernel<<<cdiv(320 * 32, 256), 256, 0, stream>>>(W_fij1, 288, wt_fij1, 10, 32);
    wtr(W_node1, 320, wt_node1, 40, 320, 320, 64);
    wtr(W_ni2a, 320, wt_ninj2a, 92, 320, 320, 96);
    wtr(W_nj2a, 320, wt_ninj2a + 320 * 96, 92, 320, 320, 96);
    wtr(W_ni2b, 320, wt_ninj2b, 92, 320, 320, 96);
    wtr(W_nj2b, 320, wt_ninj2b + 320 * 96, 92, 320, 320, 96);
    wtr(W_fij2a, 320, wt_fij2a, 40, 320, 320, 64);
    wtr(W_fij2b, 320, wt_fij2b, 40, 320, 320, 64);
    wtr(W_node2a, 736, wt_node2a, 92, 736, 768, 96);
    wtr(W_node2b, 736, wt_node2b, 92, 736, 768, 96);
    meta_kernel<<<cdiv(2240, 256), 256, 0, stream>>>(attn1, bias1, bias2a, bias2b,
                                                     attn_p1, bias_cat1, bias_cat2a, bias_cat2b);

    // ---------------- stage 1 (gg): fused Pe-GEMM + edge combine, single pass ----------------
    {
        u16* Pn1 = slab;                                  // [NG][640]
        gemm_bf_kernel<64><<<dim3(NG / 64, 10), 256, 0, stream>>>(
            gg_nf_bf, wt_ninj1, bias_cat1, Pn1, 640, 640);
        pe_edge_kernel<32, 1><<<EG / 32, 256, 0, stream>>>(
            gg_ef_bf, wt_fij1, gg_src, gg_dst, Pn1, attn_p1, esc, y22p, 0, EG, NG);
        csr_softmax_kernel<8><<<NG / 4, 256, 0, stream>>>(gg_row, gg_eidx, esc, wcsr, NG);
        u16* Pnode1 = slab;   // alias: Pn1 dead
        gemm_bf_kernel<64><<<dim3(NG / 64, 5), 256, 0, stream>>>(
            gg_nf_bf, wt_node1, b_node1, Pnode1, 320, 320);
        node_agg_kernel<40, 8, 0, 320><<<NG / 4, 256, 0, stream>>>(gg_row, gg_srcs, wcsr,
                                                                   Pnode1, y2n, NG);
    }

    // ef for lg layer 2a
    ef2a_kernel<<<cdiv(EL * 64, 256), 256, 0, stream>>>(lg_ef, y2n, ef_shared);

    // ---------------- stage 2 (lg), two layers ----------------
    for (int layer = 0; layer < 2; ++layer) {
        const bool a = (layer == 0);
        const u16* nf_in = a ? lg_nf_bf : nfa_bf;
        const u16* Wninj = a ? wt_ninj2a : wt_ninj2b;
        const u16* Wfij = a ? wt_fij2a : wt_fij2b;
        const u16* Wnode = a ? wt_node2a : wt_node2b;
        const float* bn = a ? b_node2a : b_node2b;
        const float* bcat = a ? bias_cat2a : bias_cat2b;
        const float* at = a ? attn2a : attn2b;
        u16* nf_out = a ? nfa_bf : nfb_bf;

        u16* Pn2 = slab;                                  // [NL][640]
        gemm_bf_kernel<96><<<dim3(NL / 64, 10), 256, 0, stream>>>(nf_in, Wninj, bcat, Pn2, 640, 640);
        if (a)
            pe_edge_kernel<64, 2><<<EL / 32, 256, 0, stream>>>(
                ef_shared, Wfij, lg_src, lg_dst, Pn2, at, esc, ef_shared, 0, EL, EL);
        else
            pe_edge_kernel<64, 0><<<EL / 32, 256, 0, stream>>>(
                ef_shared, Wfij, lg_src, lg_dst, Pn2, at, esc, nullptr, 0, EL, 0);
        csr_softmax_kernel<8><<<NL / 4, 256, 0, stream>>>(lg_row, lg_eidx, esc, wcsr, NL);
        u16* Pnode2 = slab;   // alias: Pn2 dead; stride 768 (row 1536B, 128B-aligned)
        gemm_bf_kernel<96><<<dim3(NL / 64, 12), 256, 0, stream>>>(nf_in, Wnode, bn, Pnode2, 736, 768);
        node_agg_kernel<92, 8, 1, 768><<<NL / 4, 256, 0, stream>>>(lg_row, lg_srcs, wcsr,
                                                                   Pnode2, nf_out, NL);
    }

    // ---------------- readout ----------------
    readout_kernel<<<NB, 256, 0, stream>>>(nfb_bf, y22p, Wr1, br1, Wr2, br2, out);
}

// Round 8
// 973.610 us; speedup vs baseline: 1.1250x; 1.0137x over previous
//
#include <hip/hip_runtime.h>
#include <math.h>

#define NG 76800
#define EG 307200
#define NL 38400
#define EL 153600
#define NB 64
#define NH 8

typedef __attribute__((ext_vector_type(8))) short bf16x8;
typedef __attribute__((ext_vector_type(4))) float f32x4;
typedef unsigned short u16;

__device__ __forceinline__ float sigmoidf(float x) { return 1.f / (1.f + expf(-x)); }
__device__ __forceinline__ u16 f2bf(float x) {
    unsigned u = __float_as_uint(x);
    return (u16)((u + 0x7FFFu + ((u >> 16) & 1u)) >> 16);
}
__device__ __forceinline__ float bf2f(u16 v) { return __uint_as_float(((unsigned)v) << 16); }

// ---------------- fp32 -> padded bf16 [M x Kpad] ----------------
__global__ __launch_bounds__(256) void convert_pad_kernel(const float* __restrict__ src,
                                                          u16* __restrict__ dst,
                                                          int M, int K, int Kpad) {
    int i = blockIdx.x * 256 + threadIdx.x;
    if (i >= M * Kpad) return;
    int m = i / Kpad, k = i - m * Kpad;
    dst[i] = (k < K) ? f2bf(src[(size_t)m * K + k]) : (u16)0;
}

// ---------------- W[K x Nfull] -> bf16 Wt[Nalloc x Kpad] (zero padded) ----------------
__global__ __launch_bounds__(256) void wtrans_kernel(const float* __restrict__ W, int ldw,
                                                     u16* __restrict__ dst,
                                                     int K, int N, int Nalloc, int Kpad) {
    int i = blockIdx.x * 256 + threadIdx.x;
    if (i >= Nalloc * Kpad) return;
    int n = i / Kpad, k = i - n * Kpad;
    dst[i] = (n < N && k < K) ? f2bf(W[(size_t)k * ldw + n]) : (u16)0;
}

// ---------------- head-padded transform: FE 36->40, 8 heads, R=320 rows ----------------
__global__ __launch_bounds__(256) void wtrans_hp_kernel(const float* __restrict__ W, int ldw,
                                                        u16* __restrict__ dst,
                                                        int K, int Kpad) {
    int i = blockIdx.x * 256 + threadIdx.x;
    if (i >= 320 * Kpad) return;
    int n = i / Kpad, k = i - n * Kpad;
    int hh = n / 40, f = n - hh * 40;
    float v = (k < K && f < 36) ? W[(size_t)k * ldw + hh * 36 + f] : 0.f;
    dst[i] = f2bf(v);
}

// ---------------- W_node[Fin][H*Fout] -> Wcat^T bf16 [Nalloc][H*Fin] ----------------
// Wcat[k=h*Fin+f][n] = W[f][h*Fout+n];  dst[n][k] = that (zero pad n>=Fout).
__global__ __launch_bounds__(256) void wtrans_cat_kernel(const float* __restrict__ W, int ldw,
                                                         u16* __restrict__ dst,
                                                         int Fin, int Fout, int Nalloc, int KIN) {
    int i = blockIdx.x * 256 + threadIdx.x;
    if (i >= Nalloc * KIN) return;
    int n = i / KIN, k = i - n * KIN;
    int h = k / Fin, f = k - h * Fin;
    float v = (n < Fout) ? W[(size_t)f * ldw + h * Fout + n] : 0.f;
    dst[i] = f2bf(v);
}

// ---------------- bias head-sum: out[f] = sum_h b[h*Fout+f], zero padded ----------------
__global__ __launch_bounds__(256) void bias_headsum_kernel(const float* __restrict__ b,
                                                           float* __restrict__ outp,
                                                           int Fout, int H, int Npad) {
    int i = blockIdx.x * 256 + threadIdx.x;
    if (i >= Npad) return;
    float s = 0.f;
    if (i < Fout)
        for (int h = 0; h < H; ++h) s += b[h * Fout + i];
    outp[i] = s;
}

// ---------------- meta: padded attn1 + concat biases ----------------
__global__ __launch_bounds__(256) void meta_kernel(const float* __restrict__ attn1,
                                                   const float* __restrict__ bias1,
                                                   const float* __restrict__ b2a,
                                                   const float* __restrict__ b2b,
                                                   float* __restrict__ attn_p1,
                                                   float* __restrict__ bias_cat1,
                                                   float* __restrict__ bias_cat2a,
                                                   float* __restrict__ bias_cat2b) {
    int i = blockIdx.x * 256 + threadIdx.x;
    if (i < 320) {
        int hh = i / 40, f = i - hh * 40;
        attn_p1[i] = (f < 36) ? attn1[hh * 36 + f] : 0.f;
    } else if (i < 960) {
        int j = i - 320;
        float v = 0.f;
        if (j < 320) {
            int hh = j / 40, f = j - hh * 40;
            v = (f < 36) ? bias1[hh * 36 + f] : 0.f;
        }
        bias_cat1[j] = v;
    } else if (i < 1600) {
        int j = i - 960;
        bias_cat2a[j] = (j < 320) ? b2a[j] : 0.f;
    } else if (i < 2240) {
        int j = i - 1600;
        bias_cat2b[j] = (j < 320) ? b2b[j] : 0.f;
    }
}

// ---------------- LDS-free bf16 MFMA GEMM, LDS-staged full-line epilogue ----------------
// Staging tile padded [16][72] to break the q-group 8-way bank conflict.
template <int KPAD>
__global__ __launch_bounds__(256) void gemm_bf_kernel(const u16* __restrict__ A,
                                                      const u16* __restrict__ Wt,
                                                      const float* __restrict__ bias,
                                                      u16* __restrict__ C, int Ncols,
                                                      int Nstride) {
    __shared__ u16 st[4][16 * 72];
    const int m0 = blockIdx.x * 64;
    const int n0 = blockIdx.y * 64;
    const int wv = threadIdx.x >> 6;
    const int lane = threadIdx.x & 63;
    const int q = lane >> 4;
    const int mr = lane & 15;

    const u16* Arow = A + (size_t)(m0 + wv * 16 + mr) * KPAD;
    f32x4 acc[4];
#pragma unroll
    for (int t = 0; t < 4; ++t) acc[t] = (f32x4){0.f, 0.f, 0.f, 0.f};

#pragma unroll
    for (int k0 = 0; k0 < KPAD; k0 += 32) {
        bf16x8 af = *(const bf16x8*)(Arow + k0 + q * 8);
#pragma unroll
        for (int t = 0; t < 4; ++t) {
            bf16x8 bv = *(const bf16x8*)(Wt + (size_t)(n0 + t * 16 + mr) * KPAD + k0 + q * 8);
            acc[t] = __builtin_amdgcn_mfma_f32_16x16x32_bf16(af, bv, acc[t], 0, 0, 0);
        }
    }

    u16* myst = st[wv];
#pragma unroll
    for (int t = 0; t < 4; ++t) {
        const int colme = n0 + t * 16 + mr;
        const float bb = (bias && colme < Ncols) ? bias[colme] : 0.f;
#pragma unroll
        for (int r = 0; r < 4; ++r)
            myst[(q * 4 + r) * 72 + t * 16 + mr] = f2bf(acc[t][r] + bb);
    }
    // wave-private region: same-wave LDS ordering via lgkmcnt, no barrier needed
    const int rrow = lane >> 3;        // 0..7
    const int rcol = (lane & 7) * 8;   // 0,8,..,56
    bf16x8 v0 = *(const bf16x8*)(myst + rrow * 72 + rcol);
    bf16x8 v1 = *(const bf16x8*)(myst + (rrow + 8) * 72 + rcol);
    const int gcol = n0 + rcol;
    if (gcol < Ncols) {
        const int grow = m0 + wv * 16 + rrow;
        *(bf16x8*)(C + (size_t)grow * Nstride + gcol) = v0;
        *(bf16x8*)(C + (size_t)(grow + 8) * Nstride + gcol) = v1;
    }
}

// ---------------- ef2a = bf16(lg_ef + repeat(y2n,2)), padded to 64 ----------------
__global__ __launch_bounds__(256) void ef2a_kernel(const float* __restrict__ lg_ef,
                                                   const u16* __restrict__ y2n,
                                                   u16* __restrict__ dst) {
    int i = blockIdx.x * 256 + threadIdx.x;
    if (i >= EL * 64) return;
    int e = i >> 6, c = i & 63;
    dst[i] = (c < 40) ? f2bf(lg_ef[(size_t)e * 40 + c] + bf2f(y2n[(size_t)(e >> 1) * 40 + c]))
                      : (u16)0;
}

// ---------------- FUSED: edge-projection GEMM (-> LDS) + edge combine ----------------
// Block = 32 consecutive edges, 256 threads (4 waves). LDS 21KB.
// Phase 1: Pe tile [32][320] = A[32][KPAD] @ Wt[320][KPAD]^T via MFMA into LDS.
// Phase 2: 8 edges/wave with 1-deep prefetch of the next edge's Pn gathers.
// FSMODE: 0 none; 1 fp32 out stride 36 (f<36, e<fsumE); 2 bf16 out stride 64.
// NOTE (FSMODE 2): fsum may alias A (ef_shared). Safe: each block reads only
// its own A rows in phase 1 and writes only the same rows in phase 2, with a
// barrier between; blocks touch disjoint row ranges.
template <int KPAD, int FSMODE>
__global__ __launch_bounds__(256) void pe_edge_kernel(
    const u16* __restrict__ A,        // [CH][KPAD] edge features
    const u16* __restrict__ Wt,       // [320][KPAD]
    const int* __restrict__ src, const int* __restrict__ dst,
    const u16* __restrict__ Pn,       // [N][640]
    const float* __restrict__ attn,   // [320]
    float* __restrict__ esc,          // [E][8]
    void* __restrict__ fsum,
    int e0, int CH, int fsumE) {
    __shared__ u16 pe[32][328];       // padded row pitch 656B
    const int wv = threadIdx.x >> 6;  // 0..3
    const int lane = threadIdx.x & 63;
    const int q = lane >> 4;
    const int mr = lane & 15;
    const int m0 = blockIdx.x * 32;

    // ---- phase 1: GEMM into LDS ----
    {
        const int rg0 = (wv & 1) * 16;
        const int t0 = (wv >> 1) * 10;
        const u16* Arow = A + (size_t)(m0 + rg0 + mr) * KPAD;
        f32x4 acc[10];
#pragma unroll
        for (int t = 0; t < 10; ++t) acc[t] = (f32x4){0.f, 0.f, 0.f, 0.f};
#pragma unroll
        for (int k0 = 0; k0 < KPAD; k0 += 32) {
            bf16x8 af = *(const bf16x8*)(Arow + k0 + q * 8);
#pragma unroll
            for (int t = 0; t < 10; ++t) {
                bf16x8 bv = *(const bf16x8*)(Wt + (size_t)((t0 + t) * 16 + mr) * KPAD + k0 + q * 8);
                acc[t] = __builtin_amdgcn_mfma_f32_16x16x32_bf16(af, bv, acc[t], 0, 0, 0);
            }
        }
#pragma unroll
        for (int t = 0; t < 10; ++t)
#pragma unroll
            for (int r = 0; r < 4; ++r)
                pe[rg0 + q * 4 + r][(t0 + t) * 16 + mr] = f2bf(acc[t][r]);
    }
    __syncthreads();

    // ---- phase 2: combine, 8 edges per wave, 1-deep prefetch ----
    const int lc = (lane < 40) ? lane : 39;
    const int h = lc / 5, o = lc - h * 5;
    const int c = h * 40 + o * 8;
    const bool act = (lane < 40);

    float attn_r[8];
#pragma unroll
    for (int j = 0; j < 8; ++j) attn_r[j] = attn[c + j];

    const int row0 = wv * 8;
    int e = e0 + m0 + row0;
    int s = src[e], d = dst[e];
    bf16x8 api = *(const bf16x8*)(Pn + (size_t)s * 640 + c);
    bf16x8 apj = *(const bf16x8*)(Pn + (size_t)d * 640 + 320 + c);

#pragma unroll
    for (int ei = 0; ei < 8; ++ei) {
        bf16x8 napi, napj;
        if (ei < 7) {
            const int ne = e + 1;
            const int ns = src[ne], nd = dst[ne];
            napi = *(const bf16x8*)(Pn + (size_t)ns * 640 + c);
            napj = *(const bf16x8*)(Pn + (size_t)nd * 640 + 320 + c);
        }
        const int row = row0 + ei;
        bf16x8 ape = *(const bf16x8*)(&pe[row][c]);

        float v[8];
        float ehp = 0.f;
#pragma unroll
        for (int j = 0; j < 8; ++j) {
            float x = bf2f((u16)api[j]) + bf2f((u16)apj[j]) + bf2f((u16)ape[j]);
            x = x > 0.f ? x : 0.01f * x;   // leaky_relu(0.01)
            v[j] = x;
            ehp += x * attn_r[j];
        }
        float eh = 0.f;
#pragma unroll
        for (int k = 0; k < 5; ++k) eh += __shfl(ehp, h * 5 + k, 64);
        if (act && o == 0) esc[(size_t)e * 8 + h] = eh;

        if (FSMODE != 0 && e < fsumE) {
#pragma unroll
            for (int m = 4; m >= 1; m >>= 1) {
                const int p = (h ^ m) * 5 + o;
#pragma unroll
                for (int j = 0; j < 8; ++j) v[j] += __shfl(v[j], p, 64);
            }
            if (act && h == 0) {
#pragma unroll
                for (int j = 0; j < 8; ++j) {
                    const int f = o * 8 + j;
                    if (FSMODE == 1) {
                        if (f < 36) ((float*)fsum)[(size_t)e * 36 + f] = v[j];
                    } else {
                        ((u16*)fsum)[(size_t)e * 64 + f] = f2bf(v[j]);
                    }
                }
            }
        }
        if (ei < 7) {
            api = napi;
            apj = napj;
        }
        ++e;
    }
}

// ---------------- CSR build ----------------
__global__ __launch_bounds__(256) void hist_kernel(const int* __restrict__ dst,
                                                   int* __restrict__ cnt, int E) {
    int i = blockIdx.x * 256 + threadIdx.x;
    if (i < E) atomicAdd(&cnt[dst[i]], 1);
}

__global__ __launch_bounds__(1024) void scan_block_kernel(const int* __restrict__ cnt,
                                                          int* __restrict__ excl,
                                                          int* __restrict__ bsum, int N) {
    __shared__ int sd[1024];
    const int tid = threadIdx.x;
    const int i = blockIdx.x * 1024 + tid;
    int v = (i < N) ? cnt[i] : 0;
    sd[tid] = v;
    __syncthreads();
    for (int off = 1; off < 1024; off <<= 1) {
        int t = (tid >= off) ? sd[tid - off] : 0;
        __syncthreads();
        sd[tid] += t;
        __syncthreads();
    }
    if (i < N) excl[i] = sd[tid] - v;
    if (tid == 1023) bsum[blockIdx.x] = sd[1023];
}

__global__ void scan_top_kernel(int* __restrict__ bsum, int nblk) {
    if (threadIdx.x == 0 && blockIdx.x == 0) {
        int run = 0;
        for (int b = 0; b < nblk; ++b) {
            int t = bsum[b];
            bsum[b] = run;
            run += t;
        }
    }
}

__global__ __launch_bounds__(256) void scan_add_kernel(int* __restrict__ row_ptr,
                                                       const int* __restrict__ bsum,
                                                       int N, int E) {
    int i = blockIdx.x * 256 + threadIdx.x;
    if (i < N) row_ptr[i] += bsum[i >> 10];
    if (i == 0) row_ptr[N] = E;
}

// scatter: eidx (edge id) + srcs_csr (source node ids, CSR order)
__global__ __launch_bounds__(256) void scatter_kernel(const int* __restrict__ dst,
                                                      const int* __restrict__ src,
                                                      const int* __restrict__ row_ptr,
                                                      int* __restrict__ cur,
                                                      int* __restrict__ eidx,
                                                      int* __restrict__ srcs, int E) {
    int i = blockIdx.x * 256 + threadIdx.x;
    if (i < E) {
        int d = dst[i];
        int pos = row_ptr[d] + atomicAdd(&cur[d], 1);
        eidx[pos] = i;
        srcs[pos] = src[i];
    }
}

// ---------------- CSR softmax: scores (edge order) -> weights in CSR order ----------------
template <int GH>
__global__ __launch_bounds__(256) void csr_softmax_kernel(
    const int* __restrict__ row_ptr, const int* __restrict__ eidx,
    const float* __restrict__ esc, float* __restrict__ wcsr, int N) {
    constexpr int NS = 64 / GH;
    const int wid = threadIdx.x >> 6;
    const int lane = threadIdx.x & 63;
    const int nid = blockIdx.x * 4 + wid;
    if (nid >= N) return;
    const int r0 = row_ptr[nid], r1 = row_ptr[nid + 1];
    const int h = lane & (GH - 1);
    const int slot = lane / GH;

    float mx = -1e30f;
    for (int i = r0 + slot; i < r1; i += NS)
        mx = fmaxf(mx, esc[(size_t)eidx[i] * GH + h]);
#pragma unroll
    for (int m = GH; m < 64; m <<= 1) mx = fmaxf(mx, __shfl_xor(mx, m, 64));

    float den = 0.f;
    for (int i = r0 + slot; i < r1; i += NS)
        den += expf(esc[(size_t)eidx[i] * GH + h] - mx);
#pragma unroll
    for (int m = GH; m < 64; m <<= 1) den += __shfl_xor(den, m, 64);
    const float rden = 1.f / den;

    for (int i = r0 + slot; i < r1; i += NS)
        wcsr[(size_t)i * GH + h] = expf(esc[(size_t)eidx[i] * GH + h] - mx) * rden;
}

// ---------------- RAW node aggregation: agg[n][h*Fn+f] = sum_e a[e,h]*nf[src_e][f] ----------------
// Gathers RAW node-feature rows (tiny, L2/L3-hot) instead of projected rows.
// Fn: feature count; NFS: nf row stride (elems). Output agg bf16 [N][GH*Fn].
template <int Fn, int GH, int NFS>
__global__ __launch_bounds__(256) void node_agg_raw_kernel(
    const int* __restrict__ row_ptr,
    const int* __restrict__ srcs,     // [E] CSR-ordered source node ids
    const float* __restrict__ wcsr,   // [E, GH] CSR-ordered softmax weights
    const u16* __restrict__ nf,       // [N, NFS] bf16 raw node features
    u16* __restrict__ agg, int N) {
    constexpr int PAIRS = Fn / 2;     // 20 / 46
    const int wid = threadIdx.x >> 6;
    const int lane = threadIdx.x & 63;
    const int nid = blockIdx.x * 4 + wid;
    if (nid >= N) return;
    const int r0 = row_ptr[nid], r1 = row_ptr[nid + 1];
    const int col = 2 * lane;
    const bool act = (lane < PAIRS);

    float a0[GH], a1[GH];
#pragma unroll
    for (int h = 0; h < GH; ++h) { a0[h] = 0.f; a1[h] = 0.f; }

    for (int i = r0; i < r1; i += 4) {
        const u16* prs[4];
        float wv[4][GH];
#pragma unroll
        for (int b = 0; b < 4; ++b) {
            const int ii = (i + b < r1) ? (i + b) : (r1 - 1);
            prs[b] = nf + (size_t)srcs[ii] * NFS;
            const float live = (i + b < r1) ? 1.f : 0.f;
            const float* wp = wcsr + (size_t)ii * GH;
#pragma unroll
            for (int h = 0; h < GH; ++h) wv[b][h] = wp[h] * live;
        }
        if (act) {
            unsigned pv[4];
#pragma unroll
            for (int b = 0; b < 4; ++b) pv[b] = *(const unsigned*)(prs[b] + col);
#pragma unroll
            for (int b = 0; b < 4; ++b) {
                const float lo = bf2f((u16)(pv[b] & 0xFFFFu));
                const float hi = bf2f((u16)(pv[b] >> 16));
#pragma unroll
                for (int h = 0; h < GH; ++h) {
                    a0[h] += wv[b][h] * lo;
                    a1[h] += wv[b][h] * hi;
                }
            }
        }
    }
    if (act) {
        u16* ob = agg + (size_t)nid * (GH * Fn);
#pragma unroll
        for (int h = 0; h < GH; ++h) {
            unsigned pk = (unsigned)f2bf(a0[h]) | ((unsigned)f2bf(a1[h]) << 16);
            *(unsigned*)(ob + h * Fn + col) = pk;
        }
    }
}

// ---------------- readout ----------------
__global__ __launch_bounds__(256) void readout_kernel(const u16* __restrict__ nfb,
                                                      const float* __restrict__ y22p,
                                                      const float* __restrict__ Wr1,
                                                      const float* __restrict__ br1,
                                                      const float* __restrict__ Wr2,
                                                      const float* __restrict__ br2,
                                                      float* __restrict__ out) {
    const int b = blockIdx.x;
    const int t = threadIdx.x;
    __shared__ float y[128];
    __shared__ float hh[128];
    __shared__ float red[128];
    if (t < 92) {
        float s = 0.f;
        const u16* base = nfb + (size_t)b * 600 * 96 + t;
        for (int i = 0; i < 600; ++i) s += bf2f(base[(size_t)i * 96]);
        y[t] = s * (1.f / 600.f);
    } else if (t >= 128 && t < 164) {
        int f = t - 128;
        float s = 0.f;
        const float* base = y22p + (size_t)b * 1200 * 36 + f;
        for (int i = 0; i < 1200; ++i) s += base[(size_t)i * 36];
        y[92 + f] = s * (1.f / 1200.f);
    }
    __syncthreads();
    if (t < 128) {
        float s = br1[t];
        for (int c = 0; c < 128; ++c) s += y[c] * Wr1[(size_t)c * 128 + t];
        hh[t] = sigmoidf(s);
    }
    __syncthreads();
    if (t < 128) red[t] = hh[t] * Wr2[t];
    __syncthreads();
    for (int k = 64; k > 0; k >>= 1) {
        if (t < k) red[t] += red[t + k];
        __syncthreads();
    }
    if (t == 0) out[b] = sigmoidf(red[0] + br2[0]);
}

// ---------------- host side ----------------
static inline int cdiv(int a, int b) { return (a + b - 1) / b; }

extern "C" void kernel_launch(void* const* d_in, const int* in_sizes, int n_in,
                              void* d_out, int out_size, void* d_ws, size_t ws_size,
                              hipStream_t stream) {
    const int* gg_src = (const int*)d_in[0];
    const int* gg_dst = (const int*)d_in[1];
    const float* gg_nf = (const float*)d_in[2];
    const float* gg_ef = (const float*)d_in[3];
    const int* lg_src = (const int*)d_in[4];
    const int* lg_dst = (const int*)d_in[5];
    const float* lg_nf = (const float*)d_in[6];
    const float* lg_ef = (const float*)d_in[7];
    const float* W_node1 = (const float*)d_in[8];
    const float* b_node1 = (const float*)d_in[9];
    const float* W_ni1 = (const float*)d_in[10];
    const float* W_nj1 = (const float*)d_in[11];
    const float* W_fij1 = (const float*)d_in[12];
    const float* attn1 = (const float*)d_in[13];
    const float* bias1 = (const float*)d_in[14];
    const float* W_node2a = (const float*)d_in[15];
    const float* b_node2a = (const float*)d_in[16];
    const float* W_ni2a = (const float*)d_in[17];
    const float* W_nj2a = (const float*)d_in[18];
    const float* W_fij2a = (const float*)d_in[19];
    const float* attn2a = (const float*)d_in[20];
    const float* bias2a = (const float*)d_in[21];
    const float* W_node2b = (const float*)d_in[22];
    const float* b_node2b = (const float*)d_in[23];
    const float* W_ni2b = (const float*)d_in[24];
    const float* W_nj2b = (const float*)d_in[25];
    const float* W_fij2b = (const float*)d_in[26];
    const float* attn2b = (const float*)d_in[27];
    const float* bias2b = (const float*)d_in[28];
    const float* Wr1 = (const float*)d_in[29];
    const float* br1 = (const float*)d_in[30];
    const float* Wr2 = (const float*)d_in[31];
    const float* br2 = (const float*)d_in[32];
    float* out = (float*)d_out;

    char* ws = (char*)d_ws;
    size_t off = 0;
    auto take = [&](size_t bytes) {
        size_t o = off;
        off += (bytes + 255) & ~(size_t)255;
        return (void*)(ws + o);
    };
    u16* y2n = (u16*)take((size_t)NG * 40 * 2);          // bf16 now
    float* y22p = (float*)take((size_t)NG * 36 * 4);
    float* esc = (float*)take((size_t)EG * 8 * 4);
    float* wcsr = (float*)take((size_t)EG * 8 * 4);
    int* gg_row = (int*)take((size_t)(NG + 1) * 4);
    int* gg_eidx = (int*)take((size_t)EG * 4);
    int* gg_srcs = (int*)take((size_t)EG * 4);
    int* gg_cnt = (int*)take((size_t)NG * 4);
    int* lg_row = (int*)take((size_t)(NL + 1) * 4);
    int* lg_eidx = (int*)take((size_t)EL * 4);
    int* lg_srcs = (int*)take((size_t)EL * 4);
    int* lg_cnt = (int*)take((size_t)NL * 4);
    int* bsum = (int*)take((size_t)128 * 4);
    u16* gg_nf_bf = (u16*)take((size_t)NG * 64 * 2);
    u16* gg_ef_bf = (u16*)take((size_t)EG * 32 * 2);
    u16* lg_nf_bf = (u16*)take((size_t)NL * 96 * 2);
    u16* nfa_bf = (u16*)take((size_t)NL * 96 * 2);
    u16* nfb_bf = (u16*)take((size_t)NL * 96 * 2);
    u16* ef_shared = (u16*)take((size_t)EL * 64 * 2);   // ef2a input, then efa fsum
    u16* wt_ninj1 = (u16*)take((size_t)640 * 64 * 2);
    u16* wt_fij1 = (u16*)take((size_t)320 * 32 * 2);
    u16* wt_ninj2a = (u16*)take((size_t)640 * 96 * 2);
    u16* wt_ninj2b = (u16*)take((size_t)640 * 96 * 2);
    u16* wt_fij2a = (u16*)take((size_t)320 * 64 * 2);
    u16* wt_fij2b = (u16*)take((size_t)320 * 64 * 2);
    u16* wt_cat1 = (u16*)take((size_t)64 * 320 * 2);
    u16* wt_cat2a = (u16*)take((size_t)128 * 736 * 2);
    u16* wt_cat2b = (u16*)take((size_t)128 * 736 * 2);
    float* bsum1 = (float*)take((size_t)64 * 4);
    float* bsum2a = (float*)take((size_t)128 * 4);
    float* bsum2b = (float*)take((size_t)128 * 4);
    float* attn_p1 = (float*)take((size_t)320 * 4);
    float* bias_cat1 = (float*)take((size_t)640 * 4);
    float* bias_cat2a = (float*)take((size_t)640 * 4);
    float* bias_cat2b = (float*)take((size_t)640 * 4);
    u16* slab = (u16*)take((size_t)NG * 640 * 2);   // Pn1 / Pn2 / agg slabs

    auto cvt = [&](const float* s, u16* d, int M, int K, int Kpad) {
        convert_pad_kernel<<<cdiv(M * Kpad, 256), 256, 0, stream>>>(s, d, M, K, Kpad);
    };
    auto wtr = [&](const float* W, int ldw, u16* d, int K, int N, int Nalloc, int Kpad) {
        wtrans_kernel<<<cdiv(Nalloc * Kpad, 256), 256, 0, stream>>>(W, ldw, d, K, N, Nalloc, Kpad);
    };
    auto build_csr = [&](const int* dst, const int* src, int* row_ptr, int* eidx, int* srcs,
                         int* cnt, int N, int E) {
        hipMemsetAsync(cnt, 0, (size_t)N * 4, stream);
        hist_kernel<<<cdiv(E, 256), 256, 0, stream>>>(dst, cnt, E);
        int nblk = cdiv(N, 1024);
        scan_block_kernel<<<nblk, 1024, 0, stream>>>(cnt, row_ptr, bsum, N);
        scan_top_kernel<<<1, 64, 0, stream>>>(bsum, nblk);
        scan_add_kernel<<<cdiv(N, 256), 256, 0, stream>>>(row_ptr, bsum, N, E);
        hipMemsetAsync(cnt, 0, (size_t)N * 4, stream);
        scatter_kernel<<<cdiv(E, 256), 256, 0, stream>>>(dst, src, row_ptr, cnt, eidx, srcs, E);
    };

    build_csr(gg_dst, gg_src, gg_row, gg_eidx, gg_srcs, gg_cnt, NG, EG);
    build_csr(lg_dst, lg_src, lg_row, lg_eidx, lg_srcs, lg_cnt, NL, EL);

    // prep: conversions + weight transforms + meta
    cvt(gg_nf, gg_nf_bf, NG, 40, 64);
    cvt(gg_ef, gg_ef_bf, EG, 10, 32);
    cvt(lg_nf, lg_nf_bf, NL, 92, 96);
    wtrans_hp_kernel<<<cdiv(320 * 64, 256), 256, 0, stream>>>(W_ni1, 288, wt_ninj1, 40, 64);
    wtrans_hp_kernel<<<cdiv(320 * 64, 256), 256, 0, stream>>>(W_nj1, 288, wt_ninj1 + 320 * 64, 40, 64);
    wtrans_hp_kernel<<<cdiv(320 * 32, 256), 256, 0, stream>>>(W_fij1, 288, wt_fij1, 10, 32);
    wtr(W_ni2a, 320, wt_ninj2a, 92, 320, 320, 96);
    wtr(W_nj2a, 320, wt_ninj2a + 320 * 96, 92, 320, 320, 96);
    wtr(W_ni2b, 320, wt_ninj2b, 92, 320, 320, 96);
    wtr(W_nj2b, 320, wt_ninj2b + 320 * 96, 92, 320, 320, 96);
    wtr(W_fij2a, 320, wt_fij2a, 40, 320, 320, 64);
    wtr(W_fij2b, 320, wt_fij2b, 40, 320, 320, 64);
    wtrans_cat_kernel<<<cdiv(64 * 320, 256), 256, 0, stream>>>(W_node1, 320, wt_cat1, 40, 40, 64, 320);
    wtrans_cat_kernel<<<cdiv(128 * 736, 256), 256, 0, stream>>>(W_node2a, 736, wt_cat2a, 92, 92, 128, 736);
    wtrans_cat_kernel<<<cdiv(128 * 736, 256), 256, 0, stream>>>(W_node2b, 736, wt_cat2b, 92, 92, 128, 736);
    bias_headsum_kernel<<<1, 256, 0, stream>>>(b_node1, bsum1, 40, 8, 64);
    bias_headsum_kernel<<<1, 256, 0, stream>>>(b_node2a, bsum2a, 92, 8, 128);
    bias_headsum_kernel<<<1, 256, 0, stream>>>(b_node2b, bsum2b, 92, 8, 128);
    meta_kernel<<<cdiv(2240, 256), 256, 0, stream>>>(attn1, bias1, bias2a, bias2b,
                                                     attn_p1, bias_cat1, bias_cat2a, bias_cat2b);

    // ---------------- stage 1 (gg) ----------------
    {
        u16* Pn1 = slab;                                  // [NG][640]
        gemm_bf_kernel<64><<<dim3(NG / 64, 10), 256, 0, stream>>>(
            gg_nf_bf, wt_ninj1, bias_cat1, Pn1, 640, 640);
        pe_edge_kernel<32, 1><<<EG / 32, 256, 0, stream>>>(
            gg_ef_bf, wt_fij1, gg_src, gg_dst, Pn1, attn_p1, esc, y22p, 0, EG, NG);
        csr_softmax_kernel<8><<<NG / 4, 256, 0, stream>>>(gg_row, gg_eidx, esc, wcsr, NG);
        u16* agg1 = slab;   // alias: Pn1 dead; [NG][320]
        node_agg_raw_kernel<40, 8, 64><<<NG / 4, 256, 0, stream>>>(gg_row, gg_srcs, wcsr,
                                                                   gg_nf_bf, agg1, NG);
        gemm_bf_kernel<320><<<dim3(NG / 64, 1), 256, 0, stream>>>(
            agg1, wt_cat1, bsum1, y2n, 40, 40);
    }

    // ef for lg layer 2a
    ef2a_kernel<<<cdiv(EL * 64, 256), 256, 0, stream>>>(lg_ef, y2n, ef_shared);

    // ---------------- stage 2 (lg), two layers ----------------
    for (int layer = 0; layer < 2; ++layer) {
        const bool a = (layer == 0);
        const u16* nf_in = a ? lg_nf_bf : nfa_bf;
        const u16* Wninj = a ? wt_ninj2a : wt_ninj2b;
        const u16* Wfij = a ? wt_fij2a : wt_fij2b;
        const u16* Wcat = a ? wt_cat2a : wt_cat2b;
        const float* bs = a ? bsum2a : bsum2b;
        const float* bcat = a ? bias_cat2a : bias_cat2b;
        const float* at = a ? attn2a : attn2b;
        u16* nf_out = a ? nfa_bf : nfb_bf;

        u16* Pn2 = slab;                                  // [NL][640]
        gemm_bf_kernel<96><<<dim3(NL / 64, 10), 256, 0, stream>>>(nf_in, Wninj, bcat, Pn2, 640, 640);
        if (a)
            pe_edge_kernel<64, 2><<<EL / 32, 256, 0, stream>>>(
                ef_shared, Wfij, lg_src, lg_dst, Pn2, at, esc, ef_shared, 0, EL, EL);
        else
            pe_edge_kernel<64, 0><<<EL / 32, 256, 0, stream>>>(
                ef_shared, Wfij, lg_src, lg_dst, Pn2, at, esc, nullptr, 0, EL, 0);
        csr_softmax_kernel<8><<<NL / 4, 256, 0, stream>>>(lg_row, lg_eidx, esc, wcsr, NL);
        u16* agg2 = slab;   // alias: Pn2 dead; [NL][736]
        node_agg_raw_kernel<92, 8, 96><<<NL / 4, 256, 0, stream>>>(lg_row, lg_srcs, wcsr,
                                                                   nf_in, agg2, NL);
        gemm_bf_kernel<736><<<dim3(NL / 64, 2), 256, 0, stream>>>(
            agg2, Wcat, bs, nf_out, 96, 96);
    }

    // ---------------- readout ----------------
    readout_kernel<<<NB, 256, 0, stream>>>(nfb_bf, y22p, Wr1, br1, Wr2, br2, out);
}

// Round 9
// 965.542 us; speedup vs baseline: 1.1344x; 1.0084x over previous
//
#include <hip/hip_runtime.h>
#include <math.h>

#define NG 76800
#define EG 307200
#define NL 38400
#define EL 153600
#define NB 64
#define NH 8

typedef __attribute__((ext_vector_type(8))) short bf16x8;
typedef __attribute__((ext_vector_type(4))) float f32x4;
typedef unsigned short u16;

__device__ __forceinline__ float sigmoidf(float x) { return 1.f / (1.f + expf(-x)); }
__device__ __forceinline__ u16 f2bf(float x) {
    unsigned u = __float_as_uint(x);
    return (u16)((u + 0x7FFFu + ((u >> 16) & 1u)) >> 16);
}
__device__ __forceinline__ float bf2f(u16 v) { return __uint_as_float(((unsigned)v) << 16); }

// ---------------- fp32 -> padded bf16 [M x Kpad] ----------------
__global__ __launch_bounds__(256) void convert_pad_kernel(const float* __restrict__ src,
                                                          u16* __restrict__ dst,
                                                          int M, int K, int Kpad) {
    int i = blockIdx.x * 256 + threadIdx.x;
    if (i >= M * Kpad) return;
    int m = i / Kpad, k = i - m * Kpad;
    dst[i] = (k < K) ? f2bf(src[(size_t)m * K + k]) : (u16)0;
}

// ---------------- W[K x Nfull] -> bf16 Wt[Nalloc x Kpad] (zero padded) ----------------
__global__ __launch_bounds__(256) void wtrans_kernel(const float* __restrict__ W, int ldw,
                                                     u16* __restrict__ dst,
                                                     int K, int N, int Nalloc, int Kpad) {
    int i = blockIdx.x * 256 + threadIdx.x;
    if (i >= Nalloc * Kpad) return;
    int n = i / Kpad, k = i - n * Kpad;
    dst[i] = (n < N && k < K) ? f2bf(W[(size_t)k * ldw + n]) : (u16)0;
}

// ---------------- head-padded transform: FE 36->40, 8 heads, R=320 rows ----------------
__global__ __launch_bounds__(256) void wtrans_hp_kernel(const float* __restrict__ W, int ldw,
                                                        u16* __restrict__ dst,
                                                        int K, int Kpad) {
    int i = blockIdx.x * 256 + threadIdx.x;
    if (i >= 320 * Kpad) return;
    int n = i / Kpad, k = i - n * Kpad;
    int hh = n / 40, f = n - hh * 40;
    float v = (k < K && f < 36) ? W[(size_t)k * ldw + hh * 36 + f] : 0.f;
    dst[i] = f2bf(v);
}

// ---------------- W_node[Fin][H*Fout] -> Wcat^T bf16 [Nalloc][H*Fin] ----------------
// Wcat[k=h*Fin+f][n] = W[f][h*Fout+n];  dst[n][k] = that (zero pad n>=Fout).
__global__ __launch_bounds__(256) void wtrans_cat_kernel(const float* __restrict__ W, int ldw,
                                                         u16* __restrict__ dst,
                                                         int Fin, int Fout, int Nalloc, int KIN) {
    int i = blockIdx.x * 256 + threadIdx.x;
    if (i >= Nalloc * KIN) return;
    int n = i / KIN, k = i - n * KIN;
    int h = k / Fin, f = k - h * Fin;
    float v = (n < Fout) ? W[(size_t)f * ldw + h * Fout + n] : 0.f;
    dst[i] = f2bf(v);
}

// ---------------- bias head-sum: out[f] = sum_h b[h*Fout+f], zero padded ----------------
__global__ __launch_bounds__(256) void bias_headsum_kernel(const float* __restrict__ b,
                                                           float* __restrict__ outp,
                                                           int Fout, int H, int Npad) {
    int i = blockIdx.x * 256 + threadIdx.x;
    if (i >= Npad) return;
    float s = 0.f;
    if (i < Fout)
        for (int h = 0; h < H; ++h) s += b[h * Fout + i];
    outp[i] = s;
}

// ---------------- meta: padded attn1 + concat biases ----------------
__global__ __launch_bounds__(256) void meta_kernel(const float* __restrict__ attn1,
                                                   const float* __restrict__ bias1,
                                                   const float* __restrict__ b2a,
                                                   const float* __restrict__ b2b,
                                                   float* __restrict__ attn_p1,
                                                   float* __restrict__ bias_cat1,
                                                   float* __restrict__ bias_cat2a,
                                                   float* __restrict__ bias_cat2b) {
    int i = blockIdx.x * 256 + threadIdx.x;
    if (i < 320) {
        int hh = i / 40, f = i - hh * 40;
        attn_p1[i] = (f < 36) ? attn1[hh * 36 + f] : 0.f;
    } else if (i < 960) {
        int j = i - 320;
        float v = 0.f;
        if (j < 320) {
            int hh = j / 40, f = j - hh * 40;
            v = (f < 36) ? bias1[hh * 36 + f] : 0.f;
        }
        bias_cat1[j] = v;
    } else if (i < 1600) {
        int j = i - 960;
        bias_cat2a[j] = (j < 320) ? b2a[j] : 0.f;
    } else if (i < 2240) {
        int j = i - 1600;
        bias_cat2b[j] = (j < 320) ? b2b[j] : 0.f;
    }
}

// ---------------- LDS-free bf16 MFMA GEMM, LDS-staged full-line epilogue ----------------
// Staging tile padded [16][72] to break the q-group 8-way bank conflict.
template <int KPAD>
__global__ __launch_bounds__(256) void gemm_bf_kernel(const u16* __restrict__ A,
                                                      const u16* __restrict__ Wt,
                                                      const float* __restrict__ bias,
                                                      u16* __restrict__ C, int Ncols,
                                                      int Nstride) {
    __shared__ u16 st[4][16 * 72];
    const int m0 = blockIdx.x * 64;
    const int n0 = blockIdx.y * 64;
    const int wv = threadIdx.x >> 6;
    const int lane = threadIdx.x & 63;
    const int q = lane >> 4;
    const int mr = lane & 15;

    const u16* Arow = A + (size_t)(m0 + wv * 16 + mr) * KPAD;
    f32x4 acc[4];
#pragma unroll
    for (int t = 0; t < 4; ++t) acc[t] = (f32x4){0.f, 0.f, 0.f, 0.f};

#pragma unroll
    for (int k0 = 0; k0 < KPAD; k0 += 32) {
        bf16x8 af = *(const bf16x8*)(Arow + k0 + q * 8);
#pragma unroll
        for (int t = 0; t < 4; ++t) {
            bf16x8 bv = *(const bf16x8*)(Wt + (size_t)(n0 + t * 16 + mr) * KPAD + k0 + q * 8);
            acc[t] = __builtin_amdgcn_mfma_f32_16x16x32_bf16(af, bv, acc[t], 0, 0, 0);
        }
    }

    u16* myst = st[wv];
#pragma unroll
    for (int t = 0; t < 4; ++t) {
        const int colme = n0 + t * 16 + mr;
        const float bb = (bias && colme < Ncols) ? bias[colme] : 0.f;
#pragma unroll
        for (int r = 0; r < 4; ++r)
            myst[(q * 4 + r) * 72 + t * 16 + mr] = f2bf(acc[t][r] + bb);
    }
    // wave-private region: same-wave LDS ordering via lgkmcnt, no barrier needed
    const int rrow = lane >> 3;        // 0..7
    const int rcol = (lane & 7) * 8;   // 0,8,..,56
    bf16x8 v0 = *(const bf16x8*)(myst + rrow * 72 + rcol);
    bf16x8 v1 = *(const bf16x8*)(myst + (rrow + 8) * 72 + rcol);
    const int gcol = n0 + rcol;
    if (gcol < Ncols) {
        const int grow = m0 + wv * 16 + rrow;
        *(bf16x8*)(C + (size_t)grow * Nstride + gcol) = v0;
        *(bf16x8*)(C + (size_t)(grow + 8) * Nstride + gcol) = v1;
    }
}

// ---------------- ef2a = bf16(lg_ef + repeat(y2n,2)), padded to 64 ----------------
__global__ __launch_bounds__(256) void ef2a_kernel(const float* __restrict__ lg_ef,
                                                   const u16* __restrict__ y2n,
                                                   u16* __restrict__ dst) {
    int i = blockIdx.x * 256 + threadIdx.x;
    if (i >= EL * 64) return;
    int e = i >> 6, c = i & 63;
    dst[i] = (c < 40) ? f2bf(lg_ef[(size_t)e * 40 + c] + bf2f(y2n[(size_t)(e >> 1) * 40 + c]))
                      : (u16)0;
}

// ---------------- FUSED: edge-projection GEMM (-> LDS) + edge combine ----------------
// Block = 16 consecutive edges, 128 threads (2 waves). LDS 10.5KB -> ~15 blocks/CU.
// Phase 1: Pe tile [16][320] = A[16][KPAD] @ Wt[320][KPAD]^T via MFMA into LDS.
//          Wave wv covers col half wv*160..+160 (acc[10]).
// Phase 2: 8 edges/wave with 1-deep prefetch of the next edge's Pn gathers
//          (1-deep is the measured sweet spot: deeper thrashes L2 reuse, r7).
// FSMODE: 0 none; 1 fp32 out stride 36 (f<36, e<fsumE); 2 bf16 out stride 64.
// NOTE (FSMODE 2): fsum may alias A (ef_shared). Safe: each block reads only
// its own A rows in phase 1 and writes only the same rows in phase 2, with a
// barrier between; blocks touch disjoint row ranges.
template <int KPAD, int FSMODE>
__global__ __launch_bounds__(128) void pe_edge_kernel(
    const u16* __restrict__ A,        // [CH][KPAD] edge features
    const u16* __restrict__ Wt,       // [320][KPAD]
    const int* __restrict__ src, const int* __restrict__ dst,
    const u16* __restrict__ Pn,       // [N][640]
    const float* __restrict__ attn,   // [320]
    float* __restrict__ esc,          // [E][8]
    void* __restrict__ fsum,
    int e0, int CH, int fsumE) {
    __shared__ u16 pe[16][328];       // padded row pitch 656B
    const int wv = threadIdx.x >> 6;  // 0..1
    const int lane = threadIdx.x & 63;
    const int q = lane >> 4;
    const int mr = lane & 15;
    const int m0 = blockIdx.x * 16;

    // ---- phase 1: GEMM into LDS ----
    {
        const int t0 = wv * 10;
        const u16* Arow = A + (size_t)(m0 + mr) * KPAD;
        f32x4 acc[10];
#pragma unroll
        for (int t = 0; t < 10; ++t) acc[t] = (f32x4){0.f, 0.f, 0.f, 0.f};
#pragma unroll
        for (int k0 = 0; k0 < KPAD; k0 += 32) {
            bf16x8 af = *(const bf16x8*)(Arow + k0 + q * 8);
#pragma unroll
            for (int t = 0; t < 10; ++t) {
                bf16x8 bv = *(const bf16x8*)(Wt + (size_t)((t0 + t) * 16 + mr) * KPAD + k0 + q * 8);
                acc[t] = __builtin_amdgcn_mfma_f32_16x16x32_bf16(af, bv, acc[t], 0, 0, 0);
            }
        }
#pragma unroll
        for (int t = 0; t < 10; ++t)
#pragma unroll
            for (int r = 0; r < 4; ++r)
                pe[q * 4 + r][(t0 + t) * 16 + mr] = f2bf(acc[t][r]);
    }
    __syncthreads();

    // ---- phase 2: combine, 8 edges per wave, 1-deep prefetch ----
    const int lc = (lane < 40) ? lane : 39;
    const int h = lc / 5, o = lc - h * 5;
    const int c = h * 40 + o * 8;
    const bool act = (lane < 40);

    float attn_r[8];
#pragma unroll
    for (int j = 0; j < 8; ++j) attn_r[j] = attn[c + j];

    const int row0 = wv * 8;
    int e = e0 + m0 + row0;
    int s = src[e], d = dst[e];
    bf16x8 api = *(const bf16x8*)(Pn + (size_t)s * 640 + c);
    bf16x8 apj = *(const bf16x8*)(Pn + (size_t)d * 640 + 320 + c);

#pragma unroll
    for (int ei = 0; ei < 8; ++ei) {
        bf16x8 napi, napj;
        if (ei < 7) {
            const int ne = e + 1;
            const int ns = src[ne], nd = dst[ne];
            napi = *(const bf16x8*)(Pn + (size_t)ns * 640 + c);
            napj = *(const bf16x8*)(Pn + (size_t)nd * 640 + 320 + c);
        }
        const int row = row0 + ei;
        bf16x8 ape = *(const bf16x8*)(&pe[row][c]);

        float v[8];
        float ehp = 0.f;
#pragma unroll
        for (int j = 0; j < 8; ++j) {
            float x = bf2f((u16)api[j]) + bf2f((u16)apj[j]) + bf2f((u16)ape[j]);
            x = x > 0.f ? x : 0.01f * x;   // leaky_relu(0.01)
            v[j] = x;
            ehp += x * attn_r[j];
        }
        float eh = 0.f;
#pragma unroll
        for (int k = 0; k < 5; ++k) eh += __shfl(ehp, h * 5 + k, 64);
        if (act && o == 0) esc[(size_t)e * 8 + h] = eh;

        if (FSMODE != 0 && e < fsumE) {
#pragma unroll
            for (int m = 4; m >= 1; m >>= 1) {
                const int p = (h ^ m) * 5 + o;
#pragma unroll
                for (int j = 0; j < 8; ++j) v[j] += __shfl(v[j], p, 64);
            }
            if (act && h == 0) {
#pragma unroll
                for (int j = 0; j < 8; ++j) {
                    const int f = o * 8 + j;
                    if (FSMODE == 1) {
                        if (f < 36) ((float*)fsum)[(size_t)e * 36 + f] = v[j];
                    } else {
                        ((u16*)fsum)[(size_t)e * 64 + f] = f2bf(v[j]);
                    }
                }
            }
        }
        if (ei < 7) {
            api = napi;
            apj = napj;
        }
        ++e;
    }
}

// ---------------- CSR build ----------------
__global__ __launch_bounds__(256) void hist_kernel(const int* __restrict__ dst,
                                                   int* __restrict__ cnt, int E) {
    int i = blockIdx.x * 256 + threadIdx.x;
    if (i < E) atomicAdd(&cnt[dst[i]], 1);
}

__global__ __launch_bounds__(1024) void scan_block_kernel(const int* __restrict__ cnt,
                                                          int* __restrict__ excl,
                                                          int* __restrict__ bsum, int N) {
    __shared__ int sd[1024];
    const int tid = threadIdx.x;
    const int i = blockIdx.x * 1024 + tid;
    int v = (i < N) ? cnt[i] : 0;
    sd[tid] = v;
    __syncthreads();
    for (int off = 1; off < 1024; off <<= 1) {
        int t = (tid >= off) ? sd[tid - off] : 0;
        __syncthreads();
        sd[tid] += t;
        __syncthreads();
    }
    if (i < N) excl[i] = sd[tid] - v;
    if (tid == 1023) bsum[blockIdx.x] = sd[1023];
}

__global__ void scan_top_kernel(int* __restrict__ bsum, int nblk) {
    if (threadIdx.x == 0 && blockIdx.x == 0) {
        int run = 0;
        for (int b = 0; b < nblk; ++b) {
            int t = bsum[b];
            bsum[b] = run;
            run += t;
        }
    }
}

__global__ __launch_bounds__(256) void scan_add_kernel(int* __restrict__ row_ptr,
                                                       const int* __restrict__ bsum,
                                                       int N, int E) {
    int i = blockIdx.x * 256 + threadIdx.x;
    if (i < N) row_ptr[i] += bsum[i >> 10];
    if (i == 0) row_ptr[N] = E;
}

// scatter: eidx (edge id) + srcs_csr (source node ids, CSR order)
__global__ __launch_bounds__(256) void scatter_kernel(const int* __restrict__ dst,
                                                      const int* __restrict__ src,
                                                      const int* __restrict__ row_ptr,
                                                      int* __restrict__ cur,
                                                      int* __restrict__ eidx,
                                                      int* __restrict__ srcs, int E) {
    int i = blockIdx.x * 256 + threadIdx.x;
    if (i < E) {
        int d = dst[i];
        int pos = row_ptr[d] + atomicAdd(&cur[d], 1);
        eidx[pos] = i;
        srcs[pos] = src[i];
    }
}

// ---------------- CSR softmax: scores (edge order) -> weights in CSR order ----------------
template <int GH>
__global__ __launch_bounds__(256) void csr_softmax_kernel(
    const int* __restrict__ row_ptr, const int* __restrict__ eidx,
    const float* __restrict__ esc, float* __restrict__ wcsr, int N) {
    constexpr int NS = 64 / GH;
    const int wid = threadIdx.x >> 6;
    const int lane = threadIdx.x & 63;
    const int nid = blockIdx.x * 4 + wid;
    if (nid >= N) return;
    const int r0 = row_ptr[nid], r1 = row_ptr[nid + 1];
    const int h = lane & (GH - 1);
    const int slot = lane / GH;

    float mx = -1e30f;
    for (int i = r0 + slot; i < r1; i += NS)
        mx = fmaxf(mx, esc[(size_t)eidx[i] * GH + h]);
#pragma unroll
    for (int m = GH; m < 64; m <<= 1) mx = fmaxf(mx, __shfl_xor(mx, m, 64));

    float den = 0.f;
    for (int i = r0 + slot; i < r1; i += NS)
        den += expf(esc[(size_t)eidx[i] * GH + h] - mx);
#pragma unroll
    for (int m = GH; m < 64; m <<= 1) den += __shfl_xor(den, m, 64);
    const float rden = 1.f / den;

    for (int i = r0 + slot; i < r1; i += NS)
        wcsr[(size_t)i * GH + h] = expf(esc[(size_t)eidx[i] * GH + h] - mx) * rden;
}

// ---------------- RAW node aggregation: agg[n][h*Fn+f] = sum_e a[e,h]*nf[src_e][f] ----------------
// Gathers RAW node-feature rows (tiny, L2/L3-hot) instead of projected rows.
// Fn: feature count; NFS: nf row stride (elems). Output agg bf16 [N][GH*Fn].
template <int Fn, int GH, int NFS>
__global__ __launch_bounds__(256) void node_agg_raw_kernel(
    const int* __restrict__ row_ptr,
    const int* __restrict__ srcs,     // [E] CSR-ordered source node ids
    const float* __restrict__ wcsr,   // [E, GH] CSR-ordered softmax weights
    const u16* __restrict__ nf,       // [N, NFS] bf16 raw node features
    u16* __restrict__ agg, int N) {
    constexpr int PAIRS = Fn / 2;     // 20 / 46
    const int wid = threadIdx.x >> 6;
    const int lane = threadIdx.x & 63;
    const int nid = blockIdx.x * 4 + wid;
    if (nid >= N) return;
    const int r0 = row_ptr[nid], r1 = row_ptr[nid + 1];
    const int col = 2 * lane;
    const bool act = (lane < PAIRS);

    float a0[GH], a1[GH];
#pragma unroll
    for (int h = 0; h < GH; ++h) { a0[h] = 0.f; a1[h] = 0.f; }

    for (int i = r0; i < r1; i += 4) {
        const u16* prs[4];
        float wv[4][GH];
#pragma unroll
        for (int b = 0; b < 4; ++b) {
            const int ii = (i + b < r1) ? (i + b) : (r1 - 1);
            prs[b] = nf + (size_t)srcs[ii] * NFS;
            const float live = (i + b < r1) ? 1.f : 0.f;
            const float* wp = wcsr + (size_t)ii * GH;
#pragma unroll
            for (int h = 0; h < GH; ++h) wv[b][h] = wp[h] * live;
        }
        if (act) {
            unsigned pv[4];
#pragma unroll
            for (int b = 0; b < 4; ++b) pv[b] = *(const unsigned*)(prs[b] + col);
#pragma unroll
            for (int b = 0; b < 4; ++b) {
                const float lo = bf2f((u16)(pv[b] & 0xFFFFu));
                const float hi = bf2f((u16)(pv[b] >> 16));
#pragma unroll
                for (int h = 0; h < GH; ++h) {
                    a0[h] += wv[b][h] * lo;
                    a1[h] += wv[b][h] * hi;
                }
            }
        }
    }
    if (act) {
        u16* ob = agg + (size_t)nid * (GH * Fn);
#pragma unroll
        for (int h = 0; h < GH; ++h) {
            unsigned pk = (unsigned)f2bf(a0[h]) | ((unsigned)f2bf(a1[h]) << 16);
            *(unsigned*)(ob + h * Fn + col) = pk;
        }
    }
}

// ---------------- readout: cooperative row-major reads + LDS reduce ----------------
__global__ __launch_bounds__(256) void readout_kernel(const u16* __restrict__ nfb,
                                                      const float* __restrict__ y22p,
                                                      const float* __restrict__ Wr1,
                                                      const float* __restrict__ br1,
                                                      const float* __restrict__ Wr2,
                                                      const float* __restrict__ br2,
                                                      float* __restrict__ out) {
    const int b = blockIdx.x;
    const int t = threadIdx.x;
    __shared__ float sA[20][96];
    __shared__ float sB[28][36];
    __shared__ float y[128];
    __shared__ float hh[128];
    __shared__ float red[128];
    // part A: nfb [600][96] bf16 rows, 12 chunk-lanes x 20 row-groups
    if (t < 240) {
        const int cc = t % 12, rg = t / 12;
        float s[8];
#pragma unroll
        for (int j = 0; j < 8; ++j) s[j] = 0.f;
        const u16* base = nfb + (size_t)b * 600 * 96 + cc * 8;
        for (int i = rg; i < 600; i += 20) {
            bf16x8 v = *(const bf16x8*)(base + (size_t)i * 96);
#pragma unroll
            for (int j = 0; j < 8; ++j) s[j] += bf2f((u16)v[j]);
        }
#pragma unroll
        for (int j = 0; j < 8; ++j) sA[rg][cc * 8 + j] = s[j];
    }
    // part B: y22p [1200][36] fp32 rows, 9 float4-chunks x 28 row-groups
    if (t < 252) {
        const int cc = t % 9, rg = t / 9;
        float s0 = 0.f, s1 = 0.f, s2 = 0.f, s3 = 0.f;
        const float* base = y22p + (size_t)b * 1200 * 36 + cc * 4;
        for (int i = rg; i < 1200; i += 28) {
            const float* p = base + (size_t)i * 36;
            s0 += p[0]; s1 += p[1]; s2 += p[2]; s3 += p[3];
        }
        sB[rg][cc * 4 + 0] = s0;
        sB[rg][cc * 4 + 1] = s1;
        sB[rg][cc * 4 + 2] = s2;
        sB[rg][cc * 4 + 3] = s3;
    }
    __syncthreads();
    if (t < 92) {
        float s = 0.f;
        for (int r = 0; r < 20; ++r) s += sA[r][t];
        y[t] = s * (1.f / 600.f);
    } else if (t >= 128 && t < 164) {
        const int f = t - 128;
        float s = 0.f;
        for (int r = 0; r < 28; ++r) s += sB[r][f];
        y[92 + f] = s * (1.f / 1200.f);
    }
    __syncthreads();
    if (t < 128) {
        float s = br1[t];
        for (int c = 0; c < 128; ++c) s += y[c] * Wr1[(size_t)c * 128 + t];
        hh[t] = sigmoidf(s);
    }
    __syncthreads();
    if (t < 128) red[t] = hh[t] * Wr2[t];
    __syncthreads();
    for (int k = 64; k > 0; k >>= 1) {
        if (t < k) red[t] += red[t + k];
        __syncthreads();
    }
    if (t == 0) out[b] = sigmoidf(red[0] + br2[0]);
}

// ---------------- host side ----------------
static inline int cdiv(int a, int b) { return (a + b - 1) / b; }

extern "C" void kernel_launch(void* const* d_in, const int* in_sizes, int n_in,
                              void* d_out, int out_size, void* d_ws, size_t ws_size,
                              hipStream_t stream) {
    const int* gg_src = (const int*)d_in[0];
    const int* gg_dst = (const int*)d_in[1];
    const float* gg_nf = (const float*)d_in[2];
    const float* gg_ef = (const float*)d_in[3];
    const int* lg_src = (const int*)d_in[4];
    const int* lg_dst = (const int*)d_in[5];
    const float* lg_nf = (const float*)d_in[6];
    const float* lg_ef = (const float*)d_in[7];
    const float* W_node1 = (const float*)d_in[8];
    const float* b_node1 = (const float*)d_in[9];
    const float* W_ni1 = (const float*)d_in[10];
    const float* W_nj1 = (const float*)d_in[11];
    const float* W_fij1 = (const float*)d_in[12];
    const float* attn1 = (const float*)d_in[13];
    const float* bias1 = (const float*)d_in[14];
    const float* W_node2a = (const float*)d_in[15];
    const float* b_node2a = (const float*)d_in[16];
    const float* W_ni2a = (const float*)d_in[17];
    const float* W_nj2a = (const float*)d_in[18];
    const float* W_fij2a = (const float*)d_in[19];
    const float* attn2a = (const float*)d_in[20];
    const float* bias2a = (const float*)d_in[21];
    const float* W_node2b = (const float*)d_in[22];
    const float* b_node2b = (const float*)d_in[23];
    const float* W_ni2b = (const float*)d_in[24];
    const float* W_nj2b = (const float*)d_in[25];
    const float* W_fij2b = (const float*)d_in[26];
    const float* attn2b = (const float*)d_in[27];
    const float* bias2b = (const float*)d_in[28];
    const float* Wr1 = (const float*)d_in[29];
    const float* br1 = (const float*)d_in[30];
    const float* Wr2 = (const float*)d_in[31];
    const float* br2 = (const float*)d_in[32];
    float* out = (float*)d_out;

    char* ws = (char*)d_ws;
    size_t off = 0;
    auto take = [&](size_t bytes) {
        size_t o = off;
        off += (bytes + 255) & ~(size_t)255;
        return (void*)(ws + o);
    };
    u16* y2n = (u16*)take((size_t)NG * 40 * 2);          // bf16
    float* y22p = (float*)take((size_t)NG * 36 * 4);
    float* esc = (float*)take((size_t)EG * 8 * 4);
    float* wcsr = (float*)take((size_t)EG * 8 * 4);
    int* gg_row = (int*)take((size_t)(NG + 1) * 4);
    int* gg_eidx = (int*)take((size_t)EG * 4);
    int* gg_srcs = (int*)take((size_t)EG * 4);
    int* gg_cnt = (int*)take((size_t)NG * 4);
    int* lg_row = (int*)take((size_t)(NL + 1) * 4);
    int* lg_eidx = (int*)take((size_t)EL * 4);
    int* lg_srcs = (int*)take((size_t)EL * 4);
    int* lg_cnt = (int*)take((size_t)NL * 4);
    int* bsum = (int*)take((size_t)128 * 4);
    u16* gg_nf_bf = (u16*)take((size_t)NG * 64 * 2);
    u16* gg_ef_bf = (u16*)take((size_t)EG * 32 * 2);
    u16* lg_nf_bf = (u16*)take((size_t)NL * 96 * 2);
    u16* nfa_bf = (u16*)take((size_t)NL * 96 * 2);
    u16* nfb_bf = (u16*)take((size_t)NL * 96 * 2);
    u16* ef_shared = (u16*)take((size_t)EL * 64 * 2);   // ef2a input, then efa fsum
    u16* wt_ninj1 = (u16*)take((size_t)640 * 64 * 2);
    u16* wt_fij1 = (u16*)take((size_t)320 * 32 * 2);
    u16* wt_ninj2a = (u16*)take((size_t)640 * 96 * 2);
    u16* wt_ninj2b = (u16*)take((size_t)640 * 96 * 2);
    u16* wt_fij2a = (u16*)take((size_t)320 * 64 * 2);
    u16* wt_fij2b = (u16*)take((size_t)320 * 64 * 2);
    u16* wt_cat1 = (u16*)take((size_t)64 * 320 * 2);
    u16* wt_cat2a = (u16*)take((size_t)128 * 736 * 2);
    u16* wt_cat2b = (u16*)take((size_t)128 * 736 * 2);
    float* bsum1 = (float*)take((size_t)64 * 4);
    float* bsum2a = (float*)take((size_t)128 * 4);
    float* bsum2b = (float*)take((size_t)128 * 4);
    float* attn_p1 = (float*)take((size_t)320 * 4);
    float* bias_cat1 = (float*)take((size_t)640 * 4);
    float* bias_cat2a = (float*)take((size_t)640 * 4);
    float* bias_cat2b = (float*)take((size_t)640 * 4);
    u16* slab = (u16*)take((size_t)NG * 640 * 2);   // Pn1 / Pn2 / agg slabs

    auto cvt = [&](const float* s, u16* d, int M, int K, int Kpad) {
        convert_pad_kernel<<<cdiv(M * Kpad, 256), 256, 0, stream>>>(s, d, M, K, Kpad);
    };
    auto wtr = [&](const float* W, int ldw, u16* d, int K, int N, int Nalloc, int Kpad) {
        wtrans_kernel<<<cdiv(Nalloc * Kpad, 256), 256, 0, stream>>>(W, ldw, d, K, N, Nalloc, Kpad);
    };
    auto build_csr = [&](const int* dst, const int* src, int* row_ptr, int* eidx, int* srcs,
                         int* cnt, int N, int E) {
        hipMemsetAsync(cnt, 0, (size_t)N * 4, stream);
        hist_kernel<<<cdiv(E, 256), 256, 0, stream>>>(dst, cnt, E);
        int nblk = cdiv(N, 1024);
        scan_block_kernel<<<nblk, 1024, 0, stream>>>(cnt, row_ptr, bsum, N);
        scan_top_kernel<<<1, 64, 0, stream>>>(bsum, nblk);
        scan_add_kernel<<<cdiv(N, 256), 256, 0, stream>>>(row_ptr, bsum, N, E);
        hipMemsetAsync(cnt, 0, (size_t)N * 4, stream);
        scatter_kernel<<<cdiv(E, 256), 256, 0, stream>>>(dst, src, row_ptr, cnt, eidx, srcs, E);
    };

    build_csr(gg_dst, gg_src, gg_row, gg_eidx, gg_srcs, gg_cnt, NG, EG);
    build_csr(lg_dst, lg_src, lg_row, lg_eidx, lg_srcs, lg_cnt, NL, EL);

    // prep: conversions + weight transforms + meta
    cvt(gg_nf, gg_nf_bf, NG, 40, 64);
    cvt(gg_ef, gg_ef_bf, EG, 10, 32);
    cvt(lg_nf, lg_nf_bf, NL, 92, 96);
    wtrans_hp_kernel<<<cdiv(320 * 64, 256), 256, 0, stream>>>(W_ni1, 288, wt_ninj1, 40, 64);
    wtrans_hp_kernel<<<cdiv(320 * 64, 256), 256, 0, stream>>>(W_nj1, 288, wt_ninj1 + 320 * 64, 40, 64);
    wtrans_hp_kernel<<<cdiv(320 * 32, 256), 256, 0, stream>>>(W_fij1, 288, wt_fij1, 10, 32);
    wtr(W_ni2a, 320, wt_ninj2a, 92, 320, 320, 96);
    wtr(W_nj2a, 320, wt_ninj2a + 320 * 96, 92, 320, 320, 96);
    wtr(W_ni2b, 320, wt_ninj2b, 92, 320, 320, 96);
    wtr(W_nj2b, 320, wt_ninj2b + 320 * 96, 92, 320, 320, 96);
    wtr(W_fij2a, 320, wt_fij2a, 40, 320, 320, 64);
    wtr(W_fij2b, 320, wt_fij2b, 40, 320, 320, 64);
    wtrans_cat_kernel<<<cdiv(64 * 320, 256), 256, 0, stream>>>(W_node1, 320, wt_cat1, 40, 40, 64, 320);
    wtrans_cat_kernel<<<cdiv(128 * 736, 256), 256, 0, stream>>>(W_node2a, 736, wt_cat2a, 92, 92, 128, 736);
    wtrans_cat_kernel<<<cdiv(128 * 736, 256), 256, 0, stream>>>(W_node2b, 736, wt_cat2b, 92, 92, 128, 736);
    bias_headsum_kernel<<<1, 256, 0, stream>>>(b_node1, bsum1, 40, 8, 64);
    bias_headsum_kernel<<<1, 256, 0, stream>>>(b_node2a, bsum2a, 92, 8, 128);
    bias_headsum_kernel<<<1, 256, 0, stream>>>(b_node2b, bsum2b, 92, 8, 128);
    meta_kernel<<<cdiv(2240, 256), 256, 0, stream>>>(attn1, bias1, bias2a, bias2b,
                                                     attn_p1, bias_cat1, bias_cat2a, bias_cat2b);

    // ---------------- stage 1 (gg) ----------------
    {
        u16* Pn1 = slab;                                  // [NG][640]
        gemm_bf_kernel<64><<<dim3(NG / 64, 10), 256, 0, stream>>>(
            gg_nf_bf, wt_ninj1, bias_cat1, Pn1, 640, 640);
        pe_edge_kernel<32, 1><<<EG / 16, 128, 0, stream>>>(
            gg_ef_bf, wt_fij1, gg_src, gg_dst, Pn1, attn_p1, esc, y22p, 0, EG, NG);
        csr_softmax_kernel<8><<<NG / 4, 256, 0, stream>>>(gg_row, gg_eidx, esc, wcsr, NG);
        u16* agg1 = slab;   // alias: Pn1 dead; [NG][320]
        node_agg_raw_kernel<40, 8, 64><<<NG / 4, 256, 0, stream>>>(gg_row, gg_srcs, wcsr,
                                                                   gg_nf_bf, agg1, NG);
        gemm_bf_kernel<320><<<dim3(NG / 64, 1), 256, 0, stream>>>(
            agg1, wt_cat1, bsum1, y2n, 40, 40);
    }

    // ef for lg layer 2a
    ef2a_kernel<<<cdiv(EL * 64, 256), 256, 0, stream>>>(lg_ef, y2n, ef_shared);

    // ---------------- stage 2 (lg), two layers ----------------
    for (int layer = 0; layer < 2; ++layer) {
        const bool a = (layer == 0);
        const u16* nf_in = a ? lg_nf_bf : nfa_bf;
        const u16* Wninj = a ? wt_ninj2a : wt_ninj2b;
        const u16* Wfij = a ? wt_fij2a : wt_fij2b;
        const u16* Wcat = a ? wt_cat2a : wt_cat2b;
        const float* bs = a ? bsum2a : bsum2b;
        const float* bcat = a ? bias_cat2a : bias_cat2b;
        const float* at = a ? attn2a : attn2b;
        u16* nf_out = a ? nfa_bf : nfb_bf;

        u16* Pn2 = slab;                                  // [NL][640]
        gemm_bf_kernel<96><<<dim3(NL / 64, 10), 256, 0, stream>>>(nf_in, Wninj, bcat, Pn2, 640, 640);
        if (a)
            pe_edge_kernel<64, 2><<<EL / 16, 128, 0, stream>>>(
                ef_shared, Wfij, lg_src, lg_dst, Pn2, at, esc, ef_shared, 0, EL, EL);
        else
            pe_edge_kernel<64, 0><<<EL / 16, 128, 0, stream>>>(
                ef_shared, Wfij, lg_src, lg_dst, Pn2, at, esc, nullptr, 0, EL, 0);
        csr_softmax_kernel<8><<<NL / 4, 256, 0, stream>>>(lg_row, lg_eidx, esc, wcsr, NL);
        u16* agg2 = slab;   // alias: Pn2 dead; [NL][736]
        node_agg_raw_kernel<92, 8, 96><<<NL / 4, 256, 0, stream>>>(lg_row, lg_srcs, wcsr,
                                                                   nf_in, agg2, NL);
        gemm_bf_kernel<736><<<dim3(NL / 64, 2), 256, 0, stream>>>(
            agg2, Wcat, bs, nf_out, 96, 96);
    }

    // ---------------- readout ----------------
    readout_kernel<<<NB, 256, 0, stream>>>(nfb_bf, y22p, Wr1, br1, Wr2, br2, out);
}

// Round 10
// 908.066 us; speedup vs baseline: 1.2063x; 1.0633x over previous
//
#include <hip/hip_runtime.h>
#include <math.h>

#define NG 76800
#define EG 307200
#define NL 38400
#define EL 153600
#define NB 64
#define NH 8

typedef __attribute__((ext_vector_type(8))) short bf16x8;
typedef __attribute__((ext_vector_type(4))) float f32x4;
typedef unsigned short u16;

__device__ __forceinline__ float sigmoidf(float x) { return 1.f / (1.f + expf(-x)); }
__device__ __forceinline__ u16 f2bf(float x) {
    unsigned u = __float_as_uint(x);
    return (u16)((u + 0x7FFFu + ((u >> 16) & 1u)) >> 16);
}
__device__ __forceinline__ float bf2f(u16 v) { return __uint_as_float(((unsigned)v) << 16); }

// ---------------- fp32 -> padded bf16 [M x Kpad] ----------------
__global__ __launch_bounds__(256) void convert_pad_kernel(const float* __restrict__ src,
                                                          u16* __restrict__ dst,
                                                          int M, int K, int Kpad) {
    int i = blockIdx.x * 256 + threadIdx.x;
    if (i >= M * Kpad) return;
    int m = i / Kpad, k = i - m * Kpad;
    dst[i] = (k < K) ? f2bf(src[(size_t)m * K + k]) : (u16)0;
}

// ---------------- W[K x Nfull] -> bf16 Wt[Nalloc x Kpad] (zero padded) ----------------
__global__ __launch_bounds__(256) void wtrans_kernel(const float* __restrict__ W, int ldw,
                                                     u16* __restrict__ dst,
                                                     int K, int N, int Nalloc, int Kpad) {
    int i = blockIdx.x * 256 + threadIdx.x;
    if (i >= Nalloc * Kpad) return;
    int n = i / Kpad, k = i - n * Kpad;
    dst[i] = (n < N && k < K) ? f2bf(W[(size_t)k * ldw + n]) : (u16)0;
}

// ---------------- head-padded transform: FE 36->40, 8 heads, R=320 rows ----------------
__global__ __launch_bounds__(256) void wtrans_hp_kernel(const float* __restrict__ W, int ldw,
                                                        u16* __restrict__ dst,
                                                        int K, int Kpad) {
    int i = blockIdx.x * 256 + threadIdx.x;
    if (i >= 320 * Kpad) return;
    int n = i / Kpad, k = i - n * Kpad;
    int hh = n / 40, f = n - hh * 40;
    float v = (k < K && f < 36) ? W[(size_t)k * ldw + hh * 36 + f] : 0.f;
    dst[i] = f2bf(v);
}

// ---------------- W_node[Fin][H*Fout] -> Wcat^T bf16 [Nalloc][H*Fin] ----------------
// Wcat[k=h*Fin+f][n] = W[f][h*Fout+n];  dst[n][k] = that (zero pad n>=Fout).
__global__ __launch_bounds__(256) void wtrans_cat_kernel(const float* __restrict__ W, int ldw,
                                                         u16* __restrict__ dst,
                                                         int Fin, int Fout, int Nalloc, int KIN) {
    int i = blockIdx.x * 256 + threadIdx.x;
    if (i >= Nalloc * KIN) return;
    int n = i / KIN, k = i - n * KIN;
    int h = k / Fin, f = k - h * Fin;
    float v = (n < Fout) ? W[(size_t)f * ldw + h * Fout + n] : 0.f;
    dst[i] = f2bf(v);
}

// ---------------- bias head-sum: out[f] = sum_h b[h*Fout+f], zero padded ----------------
__global__ __launch_bounds__(256) void bias_headsum_kernel(const float* __restrict__ b,
                                                           float* __restrict__ outp,
                                                           int Fout, int H, int Npad) {
    int i = blockIdx.x * 256 + threadIdx.x;
    if (i >= Npad) return;
    float s = 0.f;
    if (i < Fout)
        for (int h = 0; h < H; ++h) s += b[h * Fout + i];
    outp[i] = s;
}

// ---------------- meta: padded attn1 + concat biases ----------------
__global__ __launch_bounds__(256) void meta_kernel(const float* __restrict__ attn1,
                                                   const float* __restrict__ bias1,
                                                   const float* __restrict__ b2a,
                                                   const float* __restrict__ b2b,
                                                   float* __restrict__ attn_p1,
                                                   float* __restrict__ bias_cat1,
                                                   float* __restrict__ bias_cat2a,
                                                   float* __restrict__ bias_cat2b) {
    int i = blockIdx.x * 256 + threadIdx.x;
    if (i < 320) {
        int hh = i / 40, f = i - hh * 40;
        attn_p1[i] = (f < 36) ? attn1[hh * 36 + f] : 0.f;
    } else if (i < 960) {
        int j = i - 320;
        float v = 0.f;
        if (j < 320) {
            int hh = j / 40, f = j - hh * 40;
            v = (f < 36) ? bias1[hh * 36 + f] : 0.f;
        }
        bias_cat1[j] = v;
    } else if (i < 1600) {
        int j = i - 960;
        bias_cat2a[j] = (j < 320) ? b2a[j] : 0.f;
    } else if (i < 2240) {
        int j = i - 1600;
        bias_cat2b[j] = (j < 320) ? b2b[j] : 0.f;
    }
}

// ---------------- LDS-free bf16 MFMA GEMM, LDS-staged full-line epilogue ----------------
// Staging tile padded [16][72] to break the q-group 8-way bank conflict.
template <int KPAD>
__global__ __launch_bounds__(256) void gemm_bf_kernel(const u16* __restrict__ A,
                                                      const u16* __restrict__ Wt,
                                                      const float* __restrict__ bias,
                                                      u16* __restrict__ C, int Ncols,
                                                      int Nstride) {
    __shared__ u16 st[4][16 * 72];
    const int m0 = blockIdx.x * 64;
    const int n0 = blockIdx.y * 64;
    const int wv = threadIdx.x >> 6;
    const int lane = threadIdx.x & 63;
    const int q = lane >> 4;
    const int mr = lane & 15;

    const u16* Arow = A + (size_t)(m0 + wv * 16 + mr) * KPAD;
    f32x4 acc[4];
#pragma unroll
    for (int t = 0; t < 4; ++t) acc[t] = (f32x4){0.f, 0.f, 0.f, 0.f};

#pragma unroll
    for (int k0 = 0; k0 < KPAD; k0 += 32) {
        bf16x8 af = *(const bf16x8*)(Arow + k0 + q * 8);
#pragma unroll
        for (int t = 0; t < 4; ++t) {
            bf16x8 bv = *(const bf16x8*)(Wt + (size_t)(n0 + t * 16 + mr) * KPAD + k0 + q * 8);
            acc[t] = __builtin_amdgcn_mfma_f32_16x16x32_bf16(af, bv, acc[t], 0, 0, 0);
        }
    }

    u16* myst = st[wv];
#pragma unroll
    for (int t = 0; t < 4; ++t) {
        const int colme = n0 + t * 16 + mr;
        const float bb = (bias && colme < Ncols) ? bias[colme] : 0.f;
#pragma unroll
        for (int r = 0; r < 4; ++r)
            myst[(q * 4 + r) * 72 + t * 16 + mr] = f2bf(acc[t][r] + bb);
    }
    // wave-private region: same-wave LDS ordering via lgkmcnt, no barrier needed
    const int rrow = lane >> 3;        // 0..7
    const int rcol = (lane & 7) * 8;   // 0,8,..,56
    bf16x8 v0 = *(const bf16x8*)(myst + rrow * 72 + rcol);
    bf16x8 v1 = *(const bf16x8*)(myst + (rrow + 8) * 72 + rcol);
    const int gcol = n0 + rcol;
    if (gcol < Ncols) {
        const int grow = m0 + wv * 16 + rrow;
        *(bf16x8*)(C + (size_t)grow * Nstride + gcol) = v0;
        *(bf16x8*)(C + (size_t)(grow + 8) * Nstride + gcol) = v1;
    }
}

// ---------------- ef2a = bf16(lg_ef + repeat(y2n,2)), padded to 64 ----------------
__global__ __launch_bounds__(256) void ef2a_kernel(const float* __restrict__ lg_ef,
                                                   const u16* __restrict__ y2n,
                                                   u16* __restrict__ dst) {
    int i = blockIdx.x * 256 + threadIdx.x;
    if (i >= EL * 64) return;
    int e = i >> 6, c = i & 63;
    dst[i] = (c < 40) ? f2bf(lg_ef[(size_t)e * 40 + c] + bf2f(y2n[(size_t)(e >> 1) * 40 + c]))
                      : (u16)0;
}

// ---------------- FUSED: edge-projection GEMM (-> LDS) + edge combine ----------------
// Block = 16 consecutive edges, 128 threads (2 waves).
// Phase 1: Pe tile [16][320] via MFMA into LDS (wave wv: col half wv*160).
// Phase 2: 8 edges/wave with 1-deep prefetch (measured sweet spot, r7).
// FSMODE: 0 none; 1 fp32 out stride 36 (f<36, e<fsumE); 2 bf16 out stride 64.
// NOTE (FSMODE 2): fsum may alias A (ef_shared): block reads only its own A
// rows in phase 1, writes same rows in phase 2, barrier between; disjoint.
template <int KPAD, int FSMODE>
__global__ __launch_bounds__(128) void pe_edge_kernel(
    const u16* __restrict__ A,        // [CH][KPAD] edge features
    const u16* __restrict__ Wt,       // [320][KPAD]
    const int* __restrict__ src, const int* __restrict__ dst,
    const u16* __restrict__ Pn,       // [N][640]
    const float* __restrict__ attn,   // [320]
    float* __restrict__ esc,          // [E][8]
    void* __restrict__ fsum,
    int e0, int CH, int fsumE) {
    __shared__ u16 pe[16][328];       // padded row pitch 656B
    const int wv = threadIdx.x >> 6;  // 0..1
    const int lane = threadIdx.x & 63;
    const int q = lane >> 4;
    const int mr = lane & 15;
    const int m0 = blockIdx.x * 16;

    // ---- phase 1: GEMM into LDS ----
    {
        const int t0 = wv * 10;
        const u16* Arow = A + (size_t)(m0 + mr) * KPAD;
        f32x4 acc[10];
#pragma unroll
        for (int t = 0; t < 10; ++t) acc[t] = (f32x4){0.f, 0.f, 0.f, 0.f};
#pragma unroll
        for (int k0 = 0; k0 < KPAD; k0 += 32) {
            bf16x8 af = *(const bf16x8*)(Arow + k0 + q * 8);
#pragma unroll
            for (int t = 0; t < 10; ++t) {
                bf16x8 bv = *(const bf16x8*)(Wt + (size_t)((t0 + t) * 16 + mr) * KPAD + k0 + q * 8);
                acc[t] = __builtin_amdgcn_mfma_f32_16x16x32_bf16(af, bv, acc[t], 0, 0, 0);
            }
        }
#pragma unroll
        for (int t = 0; t < 10; ++t)
#pragma unroll
            for (int r = 0; r < 4; ++r)
                pe[q * 4 + r][(t0 + t) * 16 + mr] = f2bf(acc[t][r]);
    }
    __syncthreads();

    // ---- phase 2: combine, 8 edges per wave, 1-deep prefetch ----
    const int lc = (lane < 40) ? lane : 39;
    const int h = lc / 5, o = lc - h * 5;
    const int c = h * 40 + o * 8;
    const bool act = (lane < 40);

    float attn_r[8];
#pragma unroll
    for (int j = 0; j < 8; ++j) attn_r[j] = attn[c + j];

    const int row0 = wv * 8;
    int e = e0 + m0 + row0;
    int s = src[e], d = dst[e];
    bf16x8 api = *(const bf16x8*)(Pn + (size_t)s * 640 + c);
    bf16x8 apj = *(const bf16x8*)(Pn + (size_t)d * 640 + 320 + c);

#pragma unroll
    for (int ei = 0; ei < 8; ++ei) {
        bf16x8 napi, napj;
        if (ei < 7) {
            const int ne = e + 1;
            const int ns = src[ne], nd = dst[ne];
            napi = *(const bf16x8*)(Pn + (size_t)ns * 640 + c);
            napj = *(const bf16x8*)(Pn + (size_t)nd * 640 + 320 + c);
        }
        const int row = row0 + ei;
        bf16x8 ape = *(const bf16x8*)(&pe[row][c]);

        float v[8];
        float ehp = 0.f;
#pragma unroll
        for (int j = 0; j < 8; ++j) {
            float x = bf2f((u16)api[j]) + bf2f((u16)apj[j]) + bf2f((u16)ape[j]);
            x = x > 0.f ? x : 0.01f * x;   // leaky_relu(0.01)
            v[j] = x;
            ehp += x * attn_r[j];
        }
        float eh = 0.f;
#pragma unroll
        for (int k = 0; k < 5; ++k) eh += __shfl(ehp, h * 5 + k, 64);
        if (act && o == 0) esc[(size_t)e * 8 + h] = eh;

        if (FSMODE != 0 && e < fsumE) {
#pragma unroll
            for (int m = 4; m >= 1; m >>= 1) {
                const int p = (h ^ m) * 5 + o;
#pragma unroll
                for (int j = 0; j < 8; ++j) v[j] += __shfl(v[j], p, 64);
            }
            if (act && h == 0) {
#pragma unroll
                for (int j = 0; j < 8; ++j) {
                    const int f = o * 8 + j;
                    if (FSMODE == 1) {
                        if (f < 36) ((float*)fsum)[(size_t)e * 36 + f] = v[j];
                    } else {
                        ((u16*)fsum)[(size_t)e * 64 + f] = f2bf(v[j]);
                    }
                }
            }
        }
        if (ei < 7) {
            api = napi;
            apj = napj;
        }
        ++e;
    }
}

// ---------------- CSR build ----------------
__global__ __launch_bounds__(256) void hist_kernel(const int* __restrict__ dst,
                                                   int* __restrict__ cnt, int E) {
    int i = blockIdx.x * 256 + threadIdx.x;
    if (i < E) atomicAdd(&cnt[dst[i]], 1);
}

__global__ __launch_bounds__(1024) void scan_block_kernel(const int* __restrict__ cnt,
                                                          int* __restrict__ excl,
                                                          int* __restrict__ bsum, int N) {
    __shared__ int sd[1024];
    const int tid = threadIdx.x;
    const int i = blockIdx.x * 1024 + tid;
    int v = (i < N) ? cnt[i] : 0;
    sd[tid] = v;
    __syncthreads();
    for (int off = 1; off < 1024; off <<= 1) {
        int t = (tid >= off) ? sd[tid - off] : 0;
        __syncthreads();
        sd[tid] += t;
        __syncthreads();
    }
    if (i < N) excl[i] = sd[tid] - v;
    if (tid == 1023) bsum[blockIdx.x] = sd[1023];
}

__global__ void scan_top_kernel(int* __restrict__ bsum, int nblk) {
    if (threadIdx.x == 0 && blockIdx.x == 0) {
        int run = 0;
        for (int b = 0; b < nblk; ++b) {
            int t = bsum[b];
            bsum[b] = run;
            run += t;
        }
    }
}

__global__ __launch_bounds__(256) void scan_add_kernel(int* __restrict__ row_ptr,
                                                       const int* __restrict__ bsum,
                                                       int N, int E) {
    int i = blockIdx.x * 256 + threadIdx.x;
    if (i < N) row_ptr[i] += bsum[i >> 10];
    if (i == 0) row_ptr[N] = E;
}

// scatter: eidx (edge id) + srcs_csr (source node ids, CSR order)
__global__ __launch_bounds__(256) void scatter_kernel(const int* __restrict__ dst,
                                                      const int* __restrict__ src,
                                                      const int* __restrict__ row_ptr,
                                                      int* __restrict__ cur,
                                                      int* __restrict__ eidx,
                                                      int* __restrict__ srcs, int E) {
    int i = blockIdx.x * 256 + threadIdx.x;
    if (i < E) {
        int d = dst[i];
        int pos = row_ptr[d] + atomicAdd(&cur[d], 1);
        eidx[pos] = i;
        srcs[pos] = src[i];
    }
}

// ---------------- CSR softmax: scores (edge order) -> weights in CSR order ----------------
template <int GH>
__global__ __launch_bounds__(256) void csr_softmax_kernel(
    const int* __restrict__ row_ptr, const int* __restrict__ eidx,
    const float* __restrict__ esc, float* __restrict__ wcsr, int N) {
    constexpr int NS = 64 / GH;
    const int wid = threadIdx.x >> 6;
    const int lane = threadIdx.x & 63;
    const int nid = blockIdx.x * 4 + wid;
    if (nid >= N) return;
    const int r0 = row_ptr[nid], r1 = row_ptr[nid + 1];
    const int h = lane & (GH - 1);
    const int slot = lane / GH;

    float mx = -1e30f;
    for (int i = r0 + slot; i < r1; i += NS)
        mx = fmaxf(mx, esc[(size_t)eidx[i] * GH + h]);
#pragma unroll
    for (int m = GH; m < 64; m <<= 1) mx = fmaxf(mx, __shfl_xor(mx, m, 64));

    float den = 0.f;
    for (int i = r0 + slot; i < r1; i += NS)
        den += expf(esc[(size_t)eidx[i] * GH + h] - mx);
#pragma unroll
    for (int m = GH; m < 64; m <<= 1) den += __shfl_xor(den, m, 64);
    const float rden = 1.f / den;

    for (int i = r0 + slot; i < r1; i += NS)
        wcsr[(size_t)i * GH + h] = expf(esc[(size_t)eidx[i] * GH + h] - mx) * rden;
}

// ---------------- FUSED: raw node aggregation (16 nodes -> LDS) + Wcat GEMM ----------------
// Block = 256 threads (4 waves), 16 nodes. Phase 1: wave wv aggregates nodes
// wv*4..+4 sequentially into LDS tile[16][KIN+8] (agg[n][h*Fn+f] = sum_e
// a[e,h]*nf[src_e][f]; raw rows are L2/L3-hot). Phase 2: 16 x NOUT GEMM,
// A = LDS tile (ds_read_b128, 2-way-conflict-free pitches 656/1488B),
// B = Wcat [NTILES*16][KIN] from global (L2-hot), bias = bsum (head-summed,
// valid since softmax weights sum to 1 per head). Wave w takes N-tiles
// {w, w+4}. Output staged in LDS, stored as full coalesced rows.
template <int Fn, int GH, int NFS, int KIN, int NOUT, int NTILES>
__global__ __launch_bounds__(256) void node_agg_gemm_kernel(
    const int* __restrict__ row_ptr,
    const int* __restrict__ srcs,     // [E] CSR-ordered source node ids
    const float* __restrict__ wcsr,   // [E, GH] CSR-ordered softmax weights
    const u16* __restrict__ nf,       // [N, NFS] bf16 raw node features
    const u16* __restrict__ Wcat,     // [>=NTILES*16][KIN] bf16
    const float* __restrict__ bsum,   // [>=NTILES*16] fp32 (zero padded)
    u16* __restrict__ outp,           // [N][NOUT] bf16
    int N) {
    constexpr int PAIRS = Fn / 2;     // 20 / 46
    constexpr int KINP = KIN + 8;     // pad 16B: stagger row banks
    __shared__ u16 tile[16][KINP];
    __shared__ u16 ot[16][NTILES * 16];
    const int wv = threadIdx.x >> 6;
    const int lane = threadIdx.x & 63;
    const int q = lane >> 4;
    const int mr = lane & 15;
    const int nblk = blockIdx.x * 16;

    // ---- phase 1: aggregate 4 nodes per wave ----
    {
        const int col = 2 * lane;
        const bool act = (lane < PAIRS);
#pragma unroll
        for (int nn = 0; nn < 4; ++nn) {
            const int nid = nblk + wv * 4 + nn;
            const int r0 = row_ptr[nid], r1 = row_ptr[nid + 1];
            float a0[GH], a1[GH];
#pragma unroll
            for (int h = 0; h < GH; ++h) { a0[h] = 0.f; a1[h] = 0.f; }
            for (int i = r0; i < r1; i += 4) {
                const u16* prs[4];
                float wvv[4][GH];
#pragma unroll
                for (int b = 0; b < 4; ++b) {
                    const int ii = (i + b < r1) ? (i + b) : (r1 - 1);
                    prs[b] = nf + (size_t)srcs[ii] * NFS;
                    const float live = (i + b < r1) ? 1.f : 0.f;
                    const float* wp = wcsr + (size_t)ii * GH;
#pragma unroll
                    for (int h = 0; h < GH; ++h) wvv[b][h] = wp[h] * live;
                }
                if (act) {
                    unsigned pv[4];
#pragma unroll
                    for (int b = 0; b < 4; ++b) pv[b] = *(const unsigned*)(prs[b] + col);
#pragma unroll
                    for (int b = 0; b < 4; ++b) {
                        const float lo = bf2f((u16)(pv[b] & 0xFFFFu));
                        const float hi = bf2f((u16)(pv[b] >> 16));
#pragma unroll
                        for (int h = 0; h < GH; ++h) {
                            a0[h] += wvv[b][h] * lo;
                            a1[h] += wvv[b][h] * hi;
                        }
                    }
                }
            }
            if (act) {
                u16* ob = tile[wv * 4 + nn];
#pragma unroll
                for (int h = 0; h < GH; ++h) {
                    unsigned pk = (unsigned)f2bf(a0[h]) | ((unsigned)f2bf(a1[h]) << 16);
                    *(unsigned*)(ob + h * Fn + col) = pk;
                }
            }
        }
    }
    __syncthreads();

    // ---- phase 2: 16 x NOUT GEMM from LDS tile ----
    {
        const int t0 = wv;
        const int t1 = wv + 4;
        f32x4 acc0 = (f32x4){0.f, 0.f, 0.f, 0.f};
        f32x4 acc1 = (f32x4){0.f, 0.f, 0.f, 0.f};
#pragma unroll
        for (int k0 = 0; k0 < KIN; k0 += 32) {
            bf16x8 af = *(const bf16x8*)(&tile[mr][k0 + q * 8]);
            if (t0 < NTILES) {
                bf16x8 bv = *(const bf16x8*)(Wcat + (size_t)(t0 * 16 + mr) * KIN + k0 + q * 8);
                acc0 = __builtin_amdgcn_mfma_f32_16x16x32_bf16(af, bv, acc0, 0, 0, 0);
            }
            if (t1 < NTILES) {
                bf16x8 bv = *(const bf16x8*)(Wcat + (size_t)(t1 * 16 + mr) * KIN + k0 + q * 8);
                acc1 = __builtin_amdgcn_mfma_f32_16x16x32_bf16(af, bv, acc1, 0, 0, 0);
            }
        }
        if (t0 < NTILES) {
            const float bb = bsum[t0 * 16 + mr];
#pragma unroll
            for (int r = 0; r < 4; ++r) ot[q * 4 + r][t0 * 16 + mr] = f2bf(acc0[r] + bb);
        }
        if (t1 < NTILES) {
            const float bb = bsum[t1 * 16 + mr];
#pragma unroll
            for (int r = 0; r < 4; ++r) ot[q * 4 + r][t1 * 16 + mr] = f2bf(acc1[r] + bb);
        }
    }
    __syncthreads();

    // ---- store: full rows, coalesced dword writes ----
    constexpr int DW = NOUT / 2;
    for (int idx = threadIdx.x; idx < 16 * DW; idx += 256) {
        const int row = idx / DW, c2 = idx - row * DW;
        unsigned pk = *(const unsigned*)(&ot[row][c2 * 2]);
        *(unsigned*)(outp + (size_t)(nblk + row) * NOUT + c2 * 2) = pk;
    }
}

// ---------------- readout: cooperative row-major reads + LDS reduce ----------------
__global__ __launch_bounds__(256) void readout_kernel(const u16* __restrict__ nfb,
                                                      const float* __restrict__ y22p,
                                                      const float* __restrict__ Wr1,
                                                      const float* __restrict__ br1,
                                                      const float* __restrict__ Wr2,
                                                      const float* __restrict__ br2,
                                                      float* __restrict__ out) {
    const int b = blockIdx.x;
    const int t = threadIdx.x;
    __shared__ float sA[20][96];
    __shared__ float sB[28][36];
    __shared__ float y[128];
    __shared__ float hh[128];
    __shared__ float red[128];
    // part A: nfb [600][96] bf16 rows, 12 chunk-lanes x 20 row-groups
    if (t < 240) {
        const int cc = t % 12, rg = t / 12;
        float s[8];
#pragma unroll
        for (int j = 0; j < 8; ++j) s[j] = 0.f;
        const u16* base = nfb + (size_t)b * 600 * 96 + cc * 8;
        for (int i = rg; i < 600; i += 20) {
            bf16x8 v = *(const bf16x8*)(base + (size_t)i * 96);
#pragma unroll
            for (int j = 0; j < 8; ++j) s[j] += bf2f((u16)v[j]);
        }
#pragma unroll
        for (int j = 0; j < 8; ++j) sA[rg][cc * 8 + j] = s[j];
    }
    // part B: y22p [1200][36] fp32 rows, 9 float4-chunks x 28 row-groups
    if (t < 252) {
        const int cc = t % 9, rg = t / 9;
        float s0 = 0.f, s1 = 0.f, s2 = 0.f, s3 = 0.f;
        const float* base = y22p + (size_t)b * 1200 * 36 + cc * 4;
        for (int i = rg; i < 1200; i += 28) {
            const float* p = base + (size_t)i * 36;
            s0 += p[0]; s1 += p[1]; s2 += p[2]; s3 += p[3];
        }
        sB[rg][cc * 4 + 0] = s0;
        sB[rg][cc * 4 + 1] = s1;
        sB[rg][cc * 4 + 2] = s2;
        sB[rg][cc * 4 + 3] = s3;
    }
    __syncthreads();
    if (t < 92) {
        float s = 0.f;
        for (int r = 0; r < 20; ++r) s += sA[r][t];
        y[t] = s * (1.f / 600.f);
    } else if (t >= 128 && t < 164) {
        const int f = t - 128;
        float s = 0.f;
        for (int r = 0; r < 28; ++r) s += sB[r][f];
        y[92 + f] = s * (1.f / 1200.f);
    }
    __syncthreads();
    if (t < 128) {
        float s = br1[t];
        for (int c = 0; c < 128; ++c) s += y[c] * Wr1[(size_t)c * 128 + t];
        hh[t] = sigmoidf(s);
    }
    __syncthreads();
    if (t < 128) red[t] = hh[t] * Wr2[t];
    __syncthreads();
    for (int k = 64; k > 0; k >>= 1) {
        if (t < k) red[t] += red[t + k];
        __syncthreads();
    }
    if (t == 0) out[b] = sigmoidf(red[0] + br2[0]);
}

// ---------------- host side ----------------
static inline int cdiv(int a, int b) { return (a + b - 1) / b; }

extern "C" void kernel_launch(void* const* d_in, const int* in_sizes, int n_in,
                              void* d_out, int out_size, void* d_ws, size_t ws_size,
                              hipStream_t stream) {
    const int* gg_src = (const int*)d_in[0];
    const int* gg_dst = (const int*)d_in[1];
    const float* gg_nf = (const float*)d_in[2];
    const float* gg_ef = (const float*)d_in[3];
    const int* lg_src = (const int*)d_in[4];
    const int* lg_dst = (const int*)d_in[5];
    const float* lg_nf = (const float*)d_in[6];
    const float* lg_ef = (const float*)d_in[7];
    const float* W_node1 = (const float*)d_in[8];
    const float* b_node1 = (const float*)d_in[9];
    const float* W_ni1 = (const float*)d_in[10];
    const float* W_nj1 = (const float*)d_in[11];
    const float* W_fij1 = (const float*)d_in[12];
    const float* attn1 = (const float*)d_in[13];
    const float* bias1 = (const float*)d_in[14];
    const float* W_node2a = (const float*)d_in[15];
    const float* b_node2a = (const float*)d_in[16];
    const float* W_ni2a = (const float*)d_in[17];
    const float* W_nj2a = (const float*)d_in[18];
    const float* W_fij2a = (const float*)d_in[19];
    const float* attn2a = (const float*)d_in[20];
    const float* bias2a = (const float*)d_in[21];
    const float* W_node2b = (const float*)d_in[22];
    const float* b_node2b = (const float*)d_in[23];
    const float* W_ni2b = (const float*)d_in[24];
    const float* W_nj2b = (const float*)d_in[25];
    const float* W_fij2b = (const float*)d_in[26];
    const float* attn2b = (const float*)d_in[27];
    const float* bias2b = (const float*)d_in[28];
    const float* Wr1 = (const float*)d_in[29];
    const float* br1 = (const float*)d_in[30];
    const float* Wr2 = (const float*)d_in[31];
    const float* br2 = (const float*)d_in[32];
    float* out = (float*)d_out;

    char* ws = (char*)d_ws;
    size_t off = 0;
    auto take = [&](size_t bytes) {
        size_t o = off;
        off += (bytes + 255) & ~(size_t)255;
        return (void*)(ws + o);
    };
    u16* y2n = (u16*)take((size_t)NG * 40 * 2);          // bf16
    float* y22p = (float*)take((size_t)NG * 36 * 4);
    float* esc = (float*)take((size_t)EG * 8 * 4);
    float* wcsr = (float*)take((size_t)EG * 8 * 4);
    int* gg_row = (int*)take((size_t)(NG + 1) * 4);
    int* gg_eidx = (int*)take((size_t)EG * 4);
    int* gg_srcs = (int*)take((size_t)EG * 4);
    int* gg_cnt = (int*)take((size_t)NG * 4);
    int* lg_row = (int*)take((size_t)(NL + 1) * 4);
    int* lg_eidx = (int*)take((size_t)EL * 4);
    int* lg_srcs = (int*)take((size_t)EL * 4);
    int* lg_cnt = (int*)take((size_t)NL * 4);
    int* bsum = (int*)take((size_t)128 * 4);
    u16* gg_nf_bf = (u16*)take((size_t)NG * 64 * 2);
    u16* gg_ef_bf = (u16*)take((size_t)EG * 32 * 2);
    u16* lg_nf_bf = (u16*)take((size_t)NL * 96 * 2);
    u16* nfa_bf = (u16*)take((size_t)NL * 96 * 2);
    u16* nfb_bf = (u16*)take((size_t)NL * 96 * 2);
    u16* ef_shared = (u16*)take((size_t)EL * 64 * 2);   // ef2a input, then efa fsum
    u16* wt_ninj1 = (u16*)take((size_t)640 * 64 * 2);
    u16* wt_fij1 = (u16*)take((size_t)320 * 32 * 2);
    u16* wt_ninj2a = (u16*)take((size_t)640 * 96 * 2);
    u16* wt_ninj2b = (u16*)take((size_t)640 * 96 * 2);
    u16* wt_fij2a = (u16*)take((size_t)320 * 64 * 2);
    u16* wt_fij2b = (u16*)take((size_t)320 * 64 * 2);
    u16* wt_cat1 = (u16*)take((size_t)64 * 320 * 2);
    u16* wt_cat2a = (u16*)take((size_t)128 * 736 * 2);
    u16* wt_cat2b = (u16*)take((size_t)128 * 736 * 2);
    float* bsum1 = (float*)take((size_t)64 * 4);
    float* bsum2a = (float*)take((size_t)128 * 4);
    float* bsum2b = (float*)take((size_t)128 * 4);
    float* attn_p1 = (float*)take((size_t)320 * 4);
    float* bias_cat1 = (float*)take((size_t)640 * 4);
    float* bias_cat2a = (float*)take((size_t)640 * 4);
    float* bias_cat2b = (float*)take((size_t)640 * 4);
    u16* slab = (u16*)take((size_t)NG * 640 * 2);   // Pn1 / Pn2 slabs

    auto cvt = [&](const float* s, u16* d, int M, int K, int Kpad) {
        convert_pad_kernel<<<cdiv(M * Kpad, 256), 256, 0, stream>>>(s, d, M, K, Kpad);
    };
    auto wtr = [&](const float* W, int ldw, u16* d, int K, int N, int Nalloc, int Kpad) {
        wtrans_kernel<<<cdiv(Nalloc * Kpad, 256), 256, 0, stream>>>(W, ldw, d, K, N, Nalloc, Kpad);
    };
    auto build_csr = [&](const int* dst, const int* src, int* row_ptr, int* eidx, int* srcs,
                         int* cnt, int N, int E) {
        hipMemsetAsync(cnt, 0, (size_t)N * 4, stream);
        hist_kernel<<<cdiv(E, 256), 256, 0, stream>>>(dst, cnt, E);
        int nblk = cdiv(N, 1024);
        scan_block_kernel<<<nblk, 1024, 0, stream>>>(cnt, row_ptr, bsum, N);
        scan_top_kernel<<<1, 64, 0, stream>>>(bsum, nblk);
        scan_add_kernel<<<cdiv(N, 256), 256, 0, stream>>>(row_ptr, bsum, N, E);
        hipMemsetAsync(cnt, 0, (size_t)N * 4, stream);
        scatter_kernel<<<cdiv(E, 256), 256, 0, stream>>>(dst, src, row_ptr, cnt, eidx, srcs, E);
    };

    build_csr(gg_dst, gg_src, gg_row, gg_eidx, gg_srcs, gg_cnt, NG, EG);
    build_csr(lg_dst, lg_src, lg_row, lg_eidx, lg_srcs, lg_cnt, NL, EL);

    // prep: conversions + weight transforms + meta
    cvt(gg_nf, gg_nf_bf, NG, 40, 64);
    cvt(gg_ef, gg_ef_bf, EG, 10, 32);
    cvt(lg_nf, lg_nf_bf, NL, 92, 96);
    wtrans_hp_kernel<<<cdiv(320 * 64, 256), 256, 0, stream>>>(W_ni1, 288, wt_ninj1, 40, 64);
    wtrans_hp_kernel<<<cdiv(320 * 64, 256), 256, 0, stream>>>(W_nj1, 288, wt_ninj1 + 320 * 64, 40, 64);
    wtrans_hp_kernel<<<cdiv(320 * 32, 256), 256, 0, stream>>>(W_fij1, 288, wt_fij1, 10, 32);
    wtr(W_ni2a, 320, wt_ninj2a, 92, 320, 320, 96);
    wtr(W_nj2a, 320, wt_ninj2a + 320 * 96, 92, 320, 320, 96);
    wtr(W_ni2b, 320, wt_ninj2b, 92, 320, 320, 96);
    wtr(W_nj2b, 320, wt_ninj2b + 320 * 96, 92, 320, 320, 96);
    wtr(W_fij2a, 320, wt_fij2a, 40, 320, 320, 64);
    wtr(W_fij2b, 320, wt_fij2b, 40, 320, 320, 64);
    wtrans_cat_kernel<<<cdiv(64 * 320, 256), 256, 0, stream>>>(W_node1, 320, wt_cat1, 40, 40, 64, 320);
    wtrans_cat_kernel<<<cdiv(128 * 736, 256), 256, 0, stream>>>(W_node2a, 736, wt_cat2a, 92, 92, 128, 736);
    wtrans_cat_kernel<<<cdiv(128 * 736, 256), 256, 0, stream>>>(W_node2b, 736, wt_cat2b, 92, 92, 128, 736);
    bias_headsum_kernel<<<1, 256, 0, stream>>>(b_node1, bsum1, 40, 8, 64);
    bias_headsum_kernel<<<1, 256, 0, stream>>>(b_node2a, bsum2a, 92, 8, 128);
    bias_headsum_kernel<<<1, 256, 0, stream>>>(b_node2b, bsum2b, 92, 8, 128);
    meta_kernel<<<cdiv(2240, 256), 256, 0, stream>>>(attn1, bias1, bias2a, bias2b,
                                                     attn_p1, bias_cat1, bias_cat2a, bias_cat2b);

    // ---------------- stage 1 (gg) ----------------
    {
        u16* Pn1 = slab;                                  // [NG][640]
        gemm_bf_kernel<64><<<dim3(NG / 64, 10), 256, 0, stream>>>(
            gg_nf_bf, wt_ninj1, bias_cat1, Pn1, 640, 640);
        pe_edge_kernel<32, 1><<<EG / 16, 128, 0, stream>>>(
            gg_ef_bf, wt_fij1, gg_src, gg_dst, Pn1, attn_p1, esc, y22p, 0, EG, NG);
        csr_softmax_kernel<8><<<NG / 4, 256, 0, stream>>>(gg_row, gg_eidx, esc, wcsr, NG);
        node_agg_gemm_kernel<40, 8, 64, 320, 40, 3><<<NG / 16, 256, 0, stream>>>(
            gg_row, gg_srcs, wcsr, gg_nf_bf, wt_cat1, bsum1, y2n, NG);
    }

    // ef for lg layer 2a
    ef2a_kernel<<<cdiv(EL * 64, 256), 256, 0, stream>>>(lg_ef, y2n, ef_shared);

    // ---------------- stage 2 (lg), two layers ----------------
    for (int layer = 0; layer < 2; ++layer) {
        const bool a = (layer == 0);
        const u16* nf_in = a ? lg_nf_bf : nfa_bf;
        const u16* Wninj = a ? wt_ninj2a : wt_ninj2b;
        const u16* Wfij = a ? wt_fij2a : wt_fij2b;
        const u16* Wcat = a ? wt_cat2a : wt_cat2b;
        const float* bs = a ? bsum2a : bsum2b;
        const float* bcat = a ? bias_cat2a : bias_cat2b;
        const float* at = a ? attn2a : attn2b;
        u16* nf_out = a ? nfa_bf : nfb_bf;

        u16* Pn2 = slab;                                  // [NL][640]
        gemm_bf_kernel<96><<<dim3(NL / 64, 10), 256, 0, stream>>>(nf_in, Wninj, bcat, Pn2, 640, 640);
        if (a)
            pe_edge_kernel<64, 2><<<EL / 16, 128, 0, stream>>>(
                ef_shared, Wfij, lg_src, lg_dst, Pn2, at, esc, ef_shared, 0, EL, EL);
        else
            pe_edge_kernel<64, 0><<<EL / 16, 128, 0, stream>>>(
                ef_shared, Wfij, lg_src, lg_dst, Pn2, at, esc, nullptr, 0, EL, 0);
        csr_softmax_kernel<8><<<NL / 4, 256, 0, stream>>>(lg_row, lg_eidx, esc, wcsr, NL);
        node_agg_gemm_kernel<92, 8, 96, 736, 96, 6><<<NL / 16, 256, 0, stream>>>(
            lg_row, lg_srcs, wcsr, nf_in, Wcat, bs, nf_out, NL);
    }

    // ---------------- readout ----------------
    readout_kernel<<<NB, 256, 0, stream>>>(nfb_bf, y22p, Wr1, br1, Wr2, br2, out);
}

// Round 11
// 897.601 us; speedup vs baseline: 1.2203x; 1.0117x over previous
//
#include <hip/hip_runtime.h>
#include <math.h>

#define NG 76800
#define EG 307200
#define NL 38400
#define EL 153600
#define NB 64
#define NH 8

typedef __attribute__((ext_vector_type(8))) short bf16x8;
typedef __attribute__((ext_vector_type(4))) float f32x4;
typedef unsigned short u16;

__device__ __forceinline__ float sigmoidf(float x) { return 1.f / (1.f + expf(-x)); }
__device__ __forceinline__ u16 f2bf(float x) {
    unsigned u = __float_as_uint(x);
    return (u16)((u + 0x7FFFu + ((u >> 16) & 1u)) >> 16);
}
__device__ __forceinline__ float bf2f(u16 v) { return __uint_as_float(((unsigned)v) << 16); }

// ---------------- fp32 -> padded bf16 [M x Kpad] ----------------
__global__ __launch_bounds__(256) void convert_pad_kernel(const float* __restrict__ src,
                                                          u16* __restrict__ dst,
                                                          int M, int K, int Kpad) {
    int i = blockIdx.x * 256 + threadIdx.x;
    if (i >= M * Kpad) return;
    int m = i / Kpad, k = i - m * Kpad;
    dst[i] = (k < K) ? f2bf(src[(size_t)m * K + k]) : (u16)0;
}

// ---------------- W[K x Nfull] -> bf16 Wt[Nalloc x Kpad] (zero padded) ----------------
__global__ __launch_bounds__(256) void wtrans_kernel(const float* __restrict__ W, int ldw,
                                                     u16* __restrict__ dst,
                                                     int K, int N, int Nalloc, int Kpad) {
    int i = blockIdx.x * 256 + threadIdx.x;
    if (i >= Nalloc * Kpad) return;
    int n = i / Kpad, k = i - n * Kpad;
    dst[i] = (n < N && k < K) ? f2bf(W[(size_t)k * ldw + n]) : (u16)0;
}

// ---------------- head-padded transform: FE 36->40, 8 heads, R=320 rows ----------------
__global__ __launch_bounds__(256) void wtrans_hp_kernel(const float* __restrict__ W, int ldw,
                                                        u16* __restrict__ dst,
                                                        int K, int Kpad) {
    int i = blockIdx.x * 256 + threadIdx.x;
    if (i >= 320 * Kpad) return;
    int n = i / Kpad, k = i - n * Kpad;
    int hh = n / 40, f = n - hh * 40;
    float v = (k < K && f < 36) ? W[(size_t)k * ldw + hh * 36 + f] : 0.f;
    dst[i] = f2bf(v);
}

// ---------------- W_node[Fin][H*Fout] -> Wcat^T bf16 [Nalloc][H*Fin] ----------------
// Wcat[k=h*Fin+f][n] = W[f][h*Fout+n];  dst[n][k] = that (zero pad n>=Fout).
__global__ __launch_bounds__(256) void wtrans_cat_kernel(const float* __restrict__ W, int ldw,
                                                         u16* __restrict__ dst,
                                                         int Fin, int Fout, int Nalloc, int KIN) {
    int i = blockIdx.x * 256 + threadIdx.x;
    if (i >= Nalloc * KIN) return;
    int n = i / KIN, k = i - n * KIN;
    int h = k / Fin, f = k - h * Fin;
    float v = (n < Fout) ? W[(size_t)f * ldw + h * Fout + n] : 0.f;
    dst[i] = f2bf(v);
}

// ---------------- bias head-sum: out[f] = sum_h b[h*Fout+f], zero padded ----------------
__global__ __launch_bounds__(256) void bias_headsum_kernel(const float* __restrict__ b,
                                                           float* __restrict__ outp,
                                                           int Fout, int H, int Npad) {
    int i = blockIdx.x * 256 + threadIdx.x;
    if (i >= Npad) return;
    float s = 0.f;
    if (i < Fout)
        for (int h = 0; h < H; ++h) s += b[h * Fout + i];
    outp[i] = s;
}

// ---------------- meta: padded attn1 + concat biases ----------------
__global__ __launch_bounds__(256) void meta_kernel(const float* __restrict__ attn1,
                                                   const float* __restrict__ bias1,
                                                   const float* __restrict__ b2a,
                                                   const float* __restrict__ b2b,
                                                   float* __restrict__ attn_p1,
                                                   float* __restrict__ bias_cat1,
                                                   float* __restrict__ bias_cat2a,
                                                   float* __restrict__ bias_cat2b) {
    int i = blockIdx.x * 256 + threadIdx.x;
    if (i < 320) {
        int hh = i / 40, f = i - hh * 40;
        attn_p1[i] = (f < 36) ? attn1[hh * 36 + f] : 0.f;
    } else if (i < 960) {
        int j = i - 320;
        float v = 0.f;
        if (j < 320) {
            int hh = j / 40, f = j - hh * 40;
            v = (f < 36) ? bias1[hh * 36 + f] : 0.f;
        }
        bias_cat1[j] = v;
    } else if (i < 1600) {
        int j = i - 960;
        bias_cat2a[j] = (j < 320) ? b2a[j] : 0.f;
    } else if (i < 2240) {
        int j = i - 1600;
        bias_cat2b[j] = (j < 320) ? b2b[j] : 0.f;
    }
}

// ---------------- row-strip bf16 MFMA GEMM, LDS-staged full-line epilogue ----------------
// Each block owns a 64-row strip; A-fragments loaded ONCE into registers, then
// the block loops over `ytiles` consecutive 64-col output tiles (B rows L2-hot,
// long store stream). Grid: (M/64, NYT/ytiles). Staging tile [16][72] padded.
template <int KPAD>
__global__ __launch_bounds__(256) void gemm_bf_kernel(const u16* __restrict__ A,
                                                      const u16* __restrict__ Wt,
                                                      const float* __restrict__ bias,
                                                      u16* __restrict__ C, int Ncols,
                                                      int Nstride, int ytiles) {
    __shared__ u16 st[4][16 * 72];
    const int m0 = blockIdx.x * 64;
    const int wv = threadIdx.x >> 6;
    const int lane = threadIdx.x & 63;
    const int q = lane >> 4;
    const int mr = lane & 15;
    constexpr int KS = KPAD / 32;

    const u16* Arow = A + (size_t)(m0 + wv * 16 + mr) * KPAD;
    bf16x8 af[KS];
#pragma unroll
    for (int k = 0; k < KS; ++k) af[k] = *(const bf16x8*)(Arow + k * 32 + q * 8);

    u16* myst = st[wv];
    const int rrow = lane >> 3;        // 0..7
    const int rcol = (lane & 7) * 8;   // 0,8,..,56
    const int yend = blockIdx.y * ytiles + ytiles;

    for (int yt = blockIdx.y * ytiles; yt < yend; ++yt) {
        const int n0 = yt * 64;
        f32x4 acc[4];
#pragma unroll
        for (int t = 0; t < 4; ++t) acc[t] = (f32x4){0.f, 0.f, 0.f, 0.f};
#pragma unroll
        for (int k = 0; k < KS; ++k)
#pragma unroll
            for (int t = 0; t < 4; ++t) {
                bf16x8 bv = *(const bf16x8*)(Wt + (size_t)(n0 + t * 16 + mr) * KPAD + k * 32 + q * 8);
                acc[t] = __builtin_amdgcn_mfma_f32_16x16x32_bf16(af[k], bv, acc[t], 0, 0, 0);
            }
#pragma unroll
        for (int t = 0; t < 4; ++t) {
            const int colme = n0 + t * 16 + mr;
            const float bb = (bias && colme < Ncols) ? bias[colme] : 0.f;
#pragma unroll
            for (int r = 0; r < 4; ++r)
                myst[(q * 4 + r) * 72 + t * 16 + mr] = f2bf(acc[t][r] + bb);
        }
        // wave-private region; per-wave DS ops are in-order, no barrier needed
        bf16x8 v0 = *(const bf16x8*)(myst + rrow * 72 + rcol);
        bf16x8 v1 = *(const bf16x8*)(myst + (rrow + 8) * 72 + rcol);
        const int gcol = n0 + rcol;
        if (gcol < Ncols) {
            const int grow = m0 + wv * 16 + rrow;
            *(bf16x8*)(C + (size_t)grow * Nstride + gcol) = v0;
            *(bf16x8*)(C + (size_t)(grow + 8) * Nstride + gcol) = v1;
        }
    }
}

// ---------------- ef2a = bf16(lg_ef + repeat(y2n,2)), padded to 64 ----------------
__global__ __launch_bounds__(256) void ef2a_kernel(const float* __restrict__ lg_ef,
                                                   const u16* __restrict__ y2n,
                                                   u16* __restrict__ dst) {
    int i = blockIdx.x * 256 + threadIdx.x;
    if (i >= EL * 64) return;
    int e = i >> 6, c = i & 63;
    dst[i] = (c < 40) ? f2bf(lg_ef[(size_t)e * 40 + c] + bf2f(y2n[(size_t)(e >> 1) * 40 + c]))
                      : (u16)0;
}

// ---------------- FUSED: edge-projection GEMM (-> LDS) + edge combine ----------------
// Block = 16 consecutive edges, 128 threads (2 waves).
// Phase 1: Pe tile [16][320] via MFMA into LDS (wave wv: col half wv*160).
// Phase 2: 8 edges/wave with 1-deep prefetch (measured sweet spot, r7).
// FSMODE: 0 none; 1 fp32 out stride 36 (f<36, e<fsumE); 2 bf16 out stride 64.
// NOTE (FSMODE 2): fsum may alias A (ef_shared): block reads only its own A
// rows in phase 1, writes same rows in phase 2, barrier between; disjoint.
template <int KPAD, int FSMODE>
__global__ __launch_bounds__(128) void pe_edge_kernel(
    const u16* __restrict__ A,        // [CH][KPAD] edge features
    const u16* __restrict__ Wt,       // [320][KPAD]
    const int* __restrict__ src, const int* __restrict__ dst,
    const u16* __restrict__ Pn,       // [N][640]
    const float* __restrict__ attn,   // [320]
    float* __restrict__ esc,          // [E][8]
    void* __restrict__ fsum,
    int e0, int CH, int fsumE) {
    __shared__ u16 pe[16][328];       // padded row pitch 656B
    const int wv = threadIdx.x >> 6;  // 0..1
    const int lane = threadIdx.x & 63;
    const int q = lane >> 4;
    const int mr = lane & 15;
    const int m0 = blockIdx.x * 16;

    // ---- phase 1: GEMM into LDS ----
    {
        const int t0 = wv * 10;
        const u16* Arow = A + (size_t)(m0 + mr) * KPAD;
        f32x4 acc[10];
#pragma unroll
        for (int t = 0; t < 10; ++t) acc[t] = (f32x4){0.f, 0.f, 0.f, 0.f};
#pragma unroll
        for (int k0 = 0; k0 < KPAD; k0 += 32) {
            bf16x8 af = *(const bf16x8*)(Arow + k0 + q * 8);
#pragma unroll
            for (int t = 0; t < 10; ++t) {
                bf16x8 bv = *(const bf16x8*)(Wt + (size_t)((t0 + t) * 16 + mr) * KPAD + k0 + q * 8);
                acc[t] = __builtin_amdgcn_mfma_f32_16x16x32_bf16(af, bv, acc[t], 0, 0, 0);
            }
        }
#pragma unroll
        for (int t = 0; t < 10; ++t)
#pragma unroll
            for (int r = 0; r < 4; ++r)
                pe[q * 4 + r][(t0 + t) * 16 + mr] = f2bf(acc[t][r]);
    }
    __syncthreads();

    // ---- phase 2: combine, 8 edges per wave, 1-deep prefetch ----
    const int lc = (lane < 40) ? lane : 39;
    const int h = lc / 5, o = lc - h * 5;
    const int c = h * 40 + o * 8;
    const bool act = (lane < 40);

    float attn_r[8];
#pragma unroll
    for (int j = 0; j < 8; ++j) attn_r[j] = attn[c + j];

    const int row0 = wv * 8;
    int e = e0 + m0 + row0;
    int s = src[e], d = dst[e];
    bf16x8 api = *(const bf16x8*)(Pn + (size_t)s * 640 + c);
    bf16x8 apj = *(const bf16x8*)(Pn + (size_t)d * 640 + 320 + c);

#pragma unroll
    for (int ei = 0; ei < 8; ++ei) {
        bf16x8 napi, napj;
        if (ei < 7) {
            const int ne = e + 1;
            const int ns = src[ne], nd = dst[ne];
            napi = *(const bf16x8*)(Pn + (size_t)ns * 640 + c);
            napj = *(const bf16x8*)(Pn + (size_t)nd * 640 + 320 + c);
        }
        const int row = row0 + ei;
        bf16x8 ape = *(const bf16x8*)(&pe[row][c]);

        float v[8];
        float ehp = 0.f;
#pragma unroll
        for (int j = 0; j < 8; ++j) {
            float x = bf2f((u16)api[j]) + bf2f((u16)apj[j]) + bf2f((u16)ape[j]);
            x = x > 0.f ? x : 0.01f * x;   // leaky_relu(0.01)
            v[j] = x;
            ehp += x * attn_r[j];
        }
        float eh = 0.f;
#pragma unroll
        for (int k = 0; k < 5; ++k) eh += __shfl(ehp, h * 5 + k, 64);
        if (act && o == 0) esc[(size_t)e * 8 + h] = eh;

        if (FSMODE != 0 && e < fsumE) {
#pragma unroll
            for (int m = 4; m >= 1; m >>= 1) {
                const int p = (h ^ m) * 5 + o;
#pragma unroll
                for (int j = 0; j < 8; ++j) v[j] += __shfl(v[j], p, 64);
            }
            if (act && h == 0) {
#pragma unroll
                for (int j = 0; j < 8; ++j) {
                    const int f = o * 8 + j;
                    if (FSMODE == 1) {
                        if (f < 36) ((float*)fsum)[(size_t)e * 36 + f] = v[j];
                    } else {
                        ((u16*)fsum)[(size_t)e * 64 + f] = f2bf(v[j]);
                    }
                }
            }
        }
        if (ei < 7) {
            api = napi;
            apj = napj;
        }
        ++e;
    }
}

// ---------------- CSR build ----------------
__global__ __launch_bounds__(256) void hist_kernel(const int* __restrict__ dst,
                                                   int* __restrict__ cnt, int E) {
    int i = blockIdx.x * 256 + threadIdx.x;
    if (i < E) atomicAdd(&cnt[dst[i]], 1);
}

__global__ __launch_bounds__(1024) void scan_block_kernel(const int* __restrict__ cnt,
                                                          int* __restrict__ excl,
                                                          int* __restrict__ bsum, int N) {
    __shared__ int sd[1024];
    const int tid = threadIdx.x;
    const int i = blockIdx.x * 1024 + tid;
    int v = (i < N) ? cnt[i] : 0;
    sd[tid] = v;
    __syncthreads();
    for (int off = 1; off < 1024; off <<= 1) {
        int t = (tid >= off) ? sd[tid - off] : 0;
        __syncthreads();
        sd[tid] += t;
        __syncthreads();
    }
    if (i < N) excl[i] = sd[tid] - v;
    if (tid == 1023) bsum[blockIdx.x] = sd[1023];
}

__global__ void scan_top_kernel(int* __restrict__ bsum, int nblk) {
    if (threadIdx.x == 0 && blockIdx.x == 0) {
        int run = 0;
        for (int b = 0; b < nblk; ++b) {
            int t = bsum[b];
            bsum[b] = run;
            run += t;
        }
    }
}

__global__ __launch_bounds__(256) void scan_add_kernel(int* __restrict__ row_ptr,
                                                       const int* __restrict__ bsum,
                                                       int N, int E) {
    int i = blockIdx.x * 256 + threadIdx.x;
    if (i < N) row_ptr[i] += bsum[i >> 10];
    if (i == 0) row_ptr[N] = E;
}

// scatter: eidx (edge id) + srcs_csr (source node ids, CSR order)
__global__ __launch_bounds__(256) void scatter_kernel(const int* __restrict__ dst,
                                                      const int* __restrict__ src,
                                                      const int* __restrict__ row_ptr,
                                                      int* __restrict__ cur,
                                                      int* __restrict__ eidx,
                                                      int* __restrict__ srcs, int E) {
    int i = blockIdx.x * 256 + threadIdx.x;
    if (i < E) {
        int d = dst[i];
        int pos = row_ptr[d] + atomicAdd(&cur[d], 1);
        eidx[pos] = i;
        srcs[pos] = src[i];
    }
}

// ---------------- CSR softmax: scores (edge order) -> weights in CSR order ----------------
template <int GH>
__global__ __launch_bounds__(256) void csr_softmax_kernel(
    const int* __restrict__ row_ptr, const int* __restrict__ eidx,
    const float* __restrict__ esc, float* __restrict__ wcsr, int N) {
    constexpr int NS = 64 / GH;
    const int wid = threadIdx.x >> 6;
    const int lane = threadIdx.x & 63;
    const int nid = blockIdx.x * 4 + wid;
    if (nid >= N) return;
    const int r0 = row_ptr[nid], r1 = row_ptr[nid + 1];
    const int h = lane & (GH - 1);
    const int slot = lane / GH;

    float mx = -1e30f;
    for (int i = r0 + slot; i < r1; i += NS)
        mx = fmaxf(mx, esc[(size_t)eidx[i] * GH + h]);
#pragma unroll
    for (int m = GH; m < 64; m <<= 1) mx = fmaxf(mx, __shfl_xor(mx, m, 64));

    float den = 0.f;
    for (int i = r0 + slot; i < r1; i += NS)
        den += expf(esc[(size_t)eidx[i] * GH + h] - mx);
#pragma unroll
    for (int m = GH; m < 64; m <<= 1) den += __shfl_xor(den, m, 64);
    const float rden = 1.f / den;

    for (int i = r0 + slot; i < r1; i += NS)
        wcsr[(size_t)i * GH + h] = expf(esc[(size_t)eidx[i] * GH + h] - mx) * rden;
}

// ---------------- FUSED: raw node aggregation (16 nodes -> LDS) + Wcat GEMM ----------------
// Block = 256 threads (4 waves), 16 nodes. Phase 1: wave wv aggregates nodes
// wv*4..+4 sequentially into LDS tile[16][KIN+8] (agg[n][h*Fn+f] = sum_e
// a[e,h]*nf[src_e][f]; raw rows are L2/L3-hot). Phase 2: 16 x NOUT GEMM,
// A = LDS tile, B = Wcat from global (L2-hot), bias = bsum (head-summed,
// valid since softmax weights sum to 1 per head). Wave w takes N-tiles
// {w, w+4}. Output staged in LDS, stored as full coalesced rows.
template <int Fn, int GH, int NFS, int KIN, int NOUT, int NTILES>
__global__ __launch_bounds__(256) void node_agg_gemm_kernel(
    const int* __restrict__ row_ptr,
    const int* __restrict__ srcs,     // [E] CSR-ordered source node ids
    const float* __restrict__ wcsr,   // [E, GH] CSR-ordered softmax weights
    const u16* __restrict__ nf,       // [N, NFS] bf16 raw node features
    const u16* __restrict__ Wcat,     // [>=NTILES*16][KIN] bf16
    const float* __restrict__ bsum,   // [>=NTILES*16] fp32 (zero padded)
    u16* __restrict__ outp,           // [N][NOUT] bf16
    int N) {
    constexpr int PAIRS = Fn / 2;     // 20 / 46
    constexpr int KINP = KIN + 8;     // pad 16B: stagger row banks
    __shared__ u16 tile[16][KINP];
    __shared__ u16 ot[16][NTILES * 16];
    const int wv = threadIdx.x >> 6;
    const int lane = threadIdx.x & 63;
    const int q = lane >> 4;
    const int mr = lane & 15;
    const int nblk = blockIdx.x * 16;

    // ---- phase 1: aggregate 4 nodes per wave ----
    {
        const int col = 2 * lane;
        const bool act = (lane < PAIRS);
#pragma unroll
        for (int nn = 0; nn < 4; ++nn) {
            const int nid = nblk + wv * 4 + nn;
            const int r0 = row_ptr[nid], r1 = row_ptr[nid + 1];
            float a0[GH], a1[GH];
#pragma unroll
            for (int h = 0; h < GH; ++h) { a0[h] = 0.f; a1[h] = 0.f; }
            for (int i = r0; i < r1; i += 4) {
                const u16* prs[4];
                float wvv[4][GH];
#pragma unroll
                for (int b = 0; b < 4; ++b) {
                    const int ii = (i + b < r1) ? (i + b) : (r1 - 1);
                    prs[b] = nf + (size_t)srcs[ii] * NFS;
                    const float live = (i + b < r1) ? 1.f : 0.f;
                    const float* wp = wcsr + (size_t)ii * GH;
#pragma unroll
                    for (int h = 0; h < GH; ++h) wvv[b][h] = wp[h] * live;
                }
                if (act) {
                    unsigned pv[4];
#pragma unroll
                    for (int b = 0; b < 4; ++b) pv[b] = *(const unsigned*)(prs[b] + col);
#pragma unroll
                    for (int b = 0; b < 4; ++b) {
                        const float lo = bf2f((u16)(pv[b] & 0xFFFFu));
                        const float hi = bf2f((u16)(pv[b] >> 16));
#pragma unroll
                        for (int h = 0; h < GH; ++h) {
                            a0[h] += wvv[b][h] * lo;
                            a1[h] += wvv[b][h] * hi;
                        }
                    }
                }
            }
            if (act) {
                u16* ob = tile[wv * 4 + nn];
#pragma unroll
                for (int h = 0; h < GH; ++h) {
                    unsigned pk = (unsigned)f2bf(a0[h]) | ((unsigned)f2bf(a1[h]) << 16);
                    *(unsigned*)(ob + h * Fn + col) = pk;
                }
            }
        }
    }
    __syncthreads();

    // ---- phase 2: 16 x NOUT GEMM from LDS tile ----
    {
        const int t0 = wv;
        const int t1 = wv + 4;
        f32x4 acc0 = (f32x4){0.f, 0.f, 0.f, 0.f};
        f32x4 acc1 = (f32x4){0.f, 0.f, 0.f, 0.f};
#pragma unroll
        for (int k0 = 0; k0 < KIN; k0 += 32) {
            bf16x8 af = *(const bf16x8*)(&tile[mr][k0 + q * 8]);
            if (t0 < NTILES) {
                bf16x8 bv = *(const bf16x8*)(Wcat + (size_t)(t0 * 16 + mr) * KIN + k0 + q * 8);
                acc0 = __builtin_amdgcn_mfma_f32_16x16x32_bf16(af, bv, acc0, 0, 0, 0);
            }
            if (t1 < NTILES) {
                bf16x8 bv = *(const bf16x8*)(Wcat + (size_t)(t1 * 16 + mr) * KIN + k0 + q * 8);
                acc1 = __builtin_amdgcn_mfma_f32_16x16x32_bf16(af, bv, acc1, 0, 0, 0);
            }
        }
        if (t0 < NTILES) {
            const float bb = bsum[t0 * 16 + mr];
#pragma unroll
            for (int r = 0; r < 4; ++r) ot[q * 4 + r][t0 * 16 + mr] = f2bf(acc0[r] + bb);
        }
        if (t1 < NTILES) {
            const float bb = bsum[t1 * 16 + mr];
#pragma unroll
            for (int r = 0; r < 4; ++r) ot[q * 4 + r][t1 * 16 + mr] = f2bf(acc1[r] + bb);
        }
    }
    __syncthreads();

    // ---- store: full rows, coalesced dword writes ----
    constexpr int DW = NOUT / 2;
    for (int idx = threadIdx.x; idx < 16 * DW; idx += 256) {
        const int row = idx / DW, c2 = idx - row * DW;
        unsigned pk = *(const unsigned*)(&ot[row][c2 * 2]);
        *(unsigned*)(outp + (size_t)(nblk + row) * NOUT + c2 * 2) = pk;
    }
}

// ---------------- readout: cooperative row-major reads + LDS reduce ----------------
__global__ __launch_bounds__(256) void readout_kernel(const u16* __restrict__ nfb,
                                                      const float* __restrict__ y22p,
                                                      const float* __restrict__ Wr1,
                                                      const float* __restrict__ br1,
                                                      const float* __restrict__ Wr2,
                                                      const float* __restrict__ br2,
                                                      float* __restrict__ out) {
    const int b = blockIdx.x;
    const int t = threadIdx.x;
    __shared__ float sA[20][96];
    __shared__ float sB[28][36];
    __shared__ float y[128];
    __shared__ float hh[128];
    __shared__ float red[128];
    // part A: nfb [600][96] bf16 rows, 12 chunk-lanes x 20 row-groups
    if (t < 240) {
        const int cc = t % 12, rg = t / 12;
        float s[8];
#pragma unroll
        for (int j = 0; j < 8; ++j) s[j] = 0.f;
        const u16* base = nfb + (size_t)b * 600 * 96 + cc * 8;
        for (int i = rg; i < 600; i += 20) {
            bf16x8 v = *(const bf16x8*)(base + (size_t)i * 96);
#pragma unroll
            for (int j = 0; j < 8; ++j) s[j] += bf2f((u16)v[j]);
        }
#pragma unroll
        for (int j = 0; j < 8; ++j) sA[rg][cc * 8 + j] = s[j];
    }
    // part B: y22p [1200][36] fp32 rows, 9 float4-chunks x 28 row-groups
    if (t < 252) {
        const int cc = t % 9, rg = t / 9;
        float s0 = 0.f, s1 = 0.f, s2 = 0.f, s3 = 0.f;
        const float* base = y22p + (size_t)b * 1200 * 36 + cc * 4;
        for (int i = rg; i < 1200; i += 28) {
            const float* p = base + (size_t)i * 36;
            s0 += p[0]; s1 += p[1]; s2 += p[2]; s3 += p[3];
        }
        sB[rg][cc * 4 + 0] = s0;
        sB[rg][cc * 4 + 1] = s1;
        sB[rg][cc * 4 + 2] = s2;
        sB[rg][cc * 4 + 3] = s3;
    }
    __syncthreads();
    if (t < 92) {
        float s = 0.f;
        for (int r = 0; r < 20; ++r) s += sA[r][t];
        y[t] = s * (1.f / 600.f);
    } else if (t >= 128 && t < 164) {
        const int f = t - 128;
        float s = 0.f;
        for (int r = 0; r < 28; ++r) s += sB[r][f];
        y[92 + f] = s * (1.f / 1200.f);
    }
    __syncthreads();
    if (t < 128) {
        float s = br1[t];
        for (int c = 0; c < 128; ++c) s += y[c] * Wr1[(size_t)c * 128 + t];
        hh[t] = sigmoidf(s);
    }
    __syncthreads();
    if (t < 128) red[t] = hh[t] * Wr2[t];
    __syncthreads();
    for (int k = 64; k > 0; k >>= 1) {
        if (t < k) red[t] += red[t + k];
        __syncthreads();
    }
    if (t == 0) out[b] = sigmoidf(red[0] + br2[0]);
}

// ---------------- host side ----------------
static inline int cdiv(int a, int b) { return (a + b - 1) / b; }

extern "C" void kernel_launch(void* const* d_in, const int* in_sizes, int n_in,
                              void* d_out, int out_size, void* d_ws, size_t ws_size,
                              hipStream_t stream) {
    const int* gg_src = (const int*)d_in[0];
    const int* gg_dst = (const int*)d_in[1];
    const float* gg_nf = (const float*)d_in[2];
    const float* gg_ef = (const float*)d_in[3];
    const int* lg_src = (const int*)d_in[4];
    const int* lg_dst = (const int*)d_in[5];
    const float* lg_nf = (const float*)d_in[6];
    const float* lg_ef = (const float*)d_in[7];
    const float* W_node1 = (const float*)d_in[8];
    const float* b_node1 = (const float*)d_in[9];
    const float* W_ni1 = (const float*)d_in[10];
    const float* W_nj1 = (const float*)d_in[11];
    const float* W_fij1 = (const float*)d_in[12];
    const float* attn1 = (const float*)d_in[13];
    const float* bias1 = (const float*)d_in[14];
    const float* W_node2a = (const float*)d_in[15];
    const float* b_node2a = (const float*)d_in[16];
    const float* W_ni2a = (const float*)d_in[17];
    const float* W_nj2a = (const float*)d_in[18];
    const float* W_fij2a = (const float*)d_in[19];
    const float* attn2a = (const float*)d_in[20];
    const float* bias2a = (const float*)d_in[21];
    const float* W_node2b = (const float*)d_in[22];
    const float* b_node2b = (const float*)d_in[23];
    const float* W_ni2b = (const float*)d_in[24];
    const float* W_nj2b = (const float*)d_in[25];
    const float* W_fij2b = (const float*)d_in[26];
    const float* attn2b = (const float*)d_in[27];
    const float* bias2b = (const float*)d_in[28];
    const float* Wr1 = (const float*)d_in[29];
    const float* br1 = (const float*)d_in[30];
    const float* Wr2 = (const float*)d_in[31];
    const float* br2 = (const float*)d_in[32];
    float* out = (float*)d_out;

    char* ws = (char*)d_ws;
    size_t off = 0;
    auto take = [&](size_t bytes) {
        size_t o = off;
        off += (bytes + 255) & ~(size_t)255;
        return (void*)(ws + o);
    };
    u16* y2n = (u16*)take((size_t)NG * 40 * 2);          // bf16
    float* y22p = (float*)take((size_t)NG * 36 * 4);
    float* esc = (float*)take((size_t)EG * 8 * 4);
    float* wcsr = (float*)take((size_t)EG * 8 * 4);
    int* gg_row = (int*)take((size_t)(NG + 1) * 4);
    int* gg_eidx = (int*)take((size_t)EG * 4);
    int* gg_srcs = (int*)take((size_t)EG * 4);
    int* gg_cnt = (int*)take((size_t)NG * 4);
    int* lg_row = (int*)take((size_t)(NL + 1) * 4);
    int* lg_eidx = (int*)take((size_t)EL * 4);
    int* lg_srcs = (int*)take((size_t)EL * 4);
    int* lg_cnt = (int*)take((size_t)NL * 4);
    int* bsum = (int*)take((size_t)128 * 4);
    u16* gg_nf_bf = (u16*)take((size_t)NG * 64 * 2);
    u16* gg_ef_bf = (u16*)take((size_t)EG * 32 * 2);
    u16* lg_nf_bf = (u16*)take((size_t)NL * 96 * 2);
    u16* nfa_bf = (u16*)take((size_t)NL * 96 * 2);
    u16* nfb_bf = (u16*)take((size_t)NL * 96 * 2);
    u16* ef_shared = (u16*)take((size_t)EL * 64 * 2);   // ef2a input, then efa fsum
    u16* wt_ninj1 = (u16*)take((size_t)640 * 64 * 2);
    u16* wt_fij1 = (u16*)take((size_t)320 * 32 * 2);
    u16* wt_ninj2a = (u16*)take((size_t)640 * 96 * 2);
    u16* wt_ninj2b = (u16*)take((size_t)640 * 96 * 2);
    u16* wt_fij2a = (u16*)take((size_t)320 * 64 * 2);
    u16* wt_fij2b = (u16*)take((size_t)320 * 64 * 2);
    u16* wt_cat1 = (u16*)take((size_t)64 * 320 * 2);
    u16* wt_cat2a = (u16*)take((size_t)128 * 736 * 2);
    u16* wt_cat2b = (u16*)take((size_t)128 * 736 * 2);
    float* bsum1 = (float*)take((size_t)64 * 4);
    float* bsum2a = (float*)take((size_t)128 * 4);
    float* bsum2b = (float*)take((size_t)128 * 4);
    float* attn_p1 = (float*)take((size_t)320 * 4);
    float* bias_cat1 = (float*)take((size_t)640 * 4);
    float* bias_cat2a = (float*)take((size_t)640 * 4);
    float* bias_cat2b = (float*)take((size_t)640 * 4);
    u16* slab = (u16*)take((size_t)NG * 640 * 2);   // Pn1 / Pn2 slabs

    auto cvt = [&](const float* s, u16* d, int M, int K, int Kpad) {
        convert_pad_kernel<<<cdiv(M * Kpad, 256), 256, 0, stream>>>(s, d, M, K, Kpad);
    };
    auto wtr = [&](const float* W, int ldw, u16* d, int K, int N, int Nalloc, int Kpad) {
        wtrans_kernel<<<cdiv(Nalloc * Kpad, 256), 256, 0, stream>>>(W, ldw, d, K, N, Nalloc, Kpad);
    };
    auto build_csr = [&](const int* dst, const int* src, int* row_ptr, int* eidx, int* srcs,
                         int* cnt, int N, int E) {
        hipMemsetAsync(cnt, 0, (size_t)N * 4, stream);
        hist_kernel<<<cdiv(E, 256), 256, 0, stream>>>(dst, cnt, E);
        int nblk = cdiv(N, 1024);
        scan_block_kernel<<<nblk, 1024, 0, stream>>>(cnt, row_ptr, bsum, N);
        scan_top_kernel<<<1, 64, 0, stream>>>(bsum, nblk);
        scan_add_kernel<<<cdiv(N, 256), 256, 0, stream>>>(row_ptr, bsum, N, E);
        hipMemsetAsync(cnt, 0, (size_t)N * 4, stream);
        scatter_kernel<<<cdiv(E, 256), 256, 0, stream>>>(dst, src, row_ptr, cnt, eidx, srcs, E);
    };

    build_csr(gg_dst, gg_src, gg_row, gg_eidx, gg_srcs, gg_cnt, NG, EG);
    build_csr(lg_dst, lg_src, lg_row, lg_eidx, lg_srcs, lg_cnt, NL, EL);

    // prep: conversions + weight transforms + meta
    cvt(gg_nf, gg_nf_bf, NG, 40, 64);
    cvt(gg_ef, gg_ef_bf, EG, 10, 32);
    cvt(lg_nf, lg_nf_bf, NL, 92, 96);
    wtrans_hp_kernel<<<cdiv(320 * 64, 256), 256, 0, stream>>>(W_ni1, 288, wt_ninj1, 40, 64);
    wtrans_hp_kernel<<<cdiv(320 * 64, 256), 256, 0, stream>>>(W_nj1, 288, wt_ninj1 + 320 * 64, 40, 64);
    wtrans_hp_kernel<<<cdiv(320 * 32, 256), 256, 0, stream>>>(W_fij1, 288, wt_fij1, 10, 32);
    wtr(W_ni2a, 320, wt_ninj2a, 92, 320, 320, 96);
    wtr(W_nj2a, 320, wt_ninj2a + 320 * 96, 92, 320, 320, 96);
    wtr(W_ni2b, 320, wt_ninj2b, 92, 320, 320, 96);
    wtr(W_nj2b, 320, wt_ninj2b + 320 * 96, 92, 320, 320, 96);
    wtr(W_fij2a, 320, wt_fij2a, 40, 320, 320, 64);
    wtr(W_fij2b, 320, wt_fij2b, 40, 320, 320, 64);
    wtrans_cat_kernel<<<cdiv(64 * 320, 256), 256, 0, stream>>>(W_node1, 320, wt_cat1, 40, 40, 64, 320);
    wtrans_cat_kernel<<<cdiv(128 * 736, 256), 256, 0, stream>>>(W_node2a, 736, wt_cat2a, 92, 92, 128, 736);
    wtrans_cat_kernel<<<cdiv(128 * 736, 256), 256, 0, stream>>>(W_node2b, 736, wt_cat2b, 92, 92, 128, 736);
    bias_headsum_kernel<<<1, 256, 0, stream>>>(b_node1, bsum1, 40, 8, 64);
    bias_headsum_kernel<<<1, 256, 0, stream>>>(b_node2a, bsum2a, 92, 8, 128);
    bias_headsum_kernel<<<1, 256, 0, stream>>>(b_node2b, bsum2b, 92, 8, 128);
    meta_kernel<<<cdiv(2240, 256), 256, 0, stream>>>(attn1, bias1, bias2a, bias2b,
                                                     attn_p1, bias_cat1, bias_cat2a, bias_cat2b);

    // ---------------- stage 1 (gg) ----------------
    {
        u16* Pn1 = slab;                                  // [NG][640]
        gemm_bf_kernel<64><<<dim3(NG / 64, 2), 256, 0, stream>>>(
            gg_nf_bf, wt_ninj1, bias_cat1, Pn1, 640, 640, 5);
        pe_edge_kernel<32, 1><<<EG / 16, 128, 0, stream>>>(
            gg_ef_bf, wt_fij1, gg_src, gg_dst, Pn1, attn_p1, esc, y22p, 0, EG, NG);
        csr_softmax_kernel<8><<<NG / 4, 256, 0, stream>>>(gg_row, gg_eidx, esc, wcsr, NG);
        node_agg_gemm_kernel<40, 8, 64, 320, 40, 3><<<NG / 16, 256, 0, stream>>>(
            gg_row, gg_srcs, wcsr, gg_nf_bf, wt_cat1, bsum1, y2n, NG);
    }

    // ef for lg layer 2a
    ef2a_kernel<<<cdiv(EL * 64, 256), 256, 0, stream>>>(lg_ef, y2n, ef_shared);

    // ---------------- stage 2 (lg), two layers ----------------
    for (int layer = 0; layer < 2; ++layer) {
        const bool a = (layer == 0);
        const u16* nf_in = a ? lg_nf_bf : nfa_bf;
        const u16* Wninj = a ? wt_ninj2a : wt_ninj2b;
        const u16* Wfij = a ? wt_fij2a : wt_fij2b;
        const u16* Wcat = a ? wt_cat2a : wt_cat2b;
        const float* bs = a ? bsum2a : bsum2b;
        const float* bcat = a ? bias_cat2a : bias_cat2b;
        const float* at = a ? attn2a : attn2b;
        u16* nf_out = a ? nfa_bf : nfb_bf;

        u16* Pn2 = slab;                                  // [NL][640]
        gemm_bf_kernel<96><<<dim3(NL / 64, 5), 256, 0, stream>>>(
            nf_in, Wninj, bcat, Pn2, 640, 640, 2);
        if (a)
            pe_edge_kernel<64, 2><<<EL / 16, 128, 0, stream>>>(
                ef_shared, Wfij, lg_src, lg_dst, Pn2, at, esc, ef_shared, 0, EL, EL);
        else
            pe_edge_kernel<64, 0><<<EL / 16, 128, 0, stream>>>(
                ef_shared, Wfij, lg_src, lg_dst, Pn2, at, esc, nullptr, 0, EL, 0);
        csr_softmax_kernel<8><<<NL / 4, 256, 0, stream>>>(lg_row, lg_eidx, esc, wcsr, NL);
        node_agg_gemm_kernel<92, 8, 96, 736, 96, 6><<<NL / 16, 256, 0, stream>>>(
            lg_row, lg_srcs, wcsr, nf_in, Wcat, bs, nf_out, NL);
    }

    // ---------------- readout ----------------
    readout_kernel<<<NB, 256, 0, stream>>>(nfb_bf, y22p, Wr1, br1, Wr2, br2, out);
}

// Round 12
// 824.262 us; speedup vs baseline: 1.3289x; 1.0890x over previous
//
#include <hip/hip_runtime.h>
#include <math.h>

#define NG 76800
#define EG 307200
#define NL 38400
#define EL 153600
#define NB 64
#define NH 8

typedef __attribute__((ext_vector_type(8))) short bf16x8;
typedef __attribute__((ext_vector_type(4))) float f32x4;
typedef unsigned short u16;

__device__ __forceinline__ float sigmoidf(float x) { return 1.f / (1.f + expf(-x)); }
__device__ __forceinline__ u16 f2bf(float x) {
    unsigned u = __float_as_uint(x);
    return (u16)((u + 0x7FFFu + ((u >> 16) & 1u)) >> 16);
}
__device__ __forceinline__ float bf2f(u16 v) { return __uint_as_float(((unsigned)v) << 16); }

// ---------------- mega prep: all conversions + weight transforms + meta ----------------
__device__ __forceinline__ void cvt_one(const float* src, u16* dst, int j, int K, int Kpad) {
    int m = j / Kpad, k = j - m * Kpad;
    dst[j] = (k < K) ? f2bf(src[(size_t)m * K + k]) : (u16)0;
}
__device__ __forceinline__ void wtr_one(const float* W, int ldw, u16* dst, int j, int K, int Kpad) {
    int n = j / Kpad, k = j - n * Kpad;
    dst[j] = (k < K) ? f2bf(W[(size_t)k * ldw + n]) : (u16)0;
}
__device__ __forceinline__ void whp_one(const float* W, int ldw, u16* dst, int j, int K, int Kpad) {
    int n = j / Kpad, k = j - n * Kpad;
    int hh = n / 40, f = n - hh * 40;
    float v = (k < K && f < 36) ? W[(size_t)k * ldw + hh * 36 + f] : 0.f;
    dst[j] = f2bf(v);
}
__device__ __forceinline__ void wcat_one(const float* W, int ldw, u16* dst, int j,
                                         int Fin, int Fout, int KIN) {
    int n = j / KIN, k = j - n * KIN;
    int h = k / Fin, f = k - h * Fin;
    float v = (n < Fout) ? W[(size_t)f * ldw + h * Fout + n] : 0.f;
    dst[j] = f2bf(v);
}
__device__ __forceinline__ void bh_one(const float* b, float* outp, int j, int Fout, int H) {
    float s = 0.f;
    if (j < Fout)
        for (int h = 0; h < H; ++h) s += b[h * Fout + j];
    outp[j] = s;
}

#define P0 4915200
#define P1 14745600
#define P2 18432000
#define P3 18452480
#define P4 18472960
#define P5 18483200
#define P6 18513920
#define P7 18544640
#define P8 18575360
#define P9 18606080
#define P10 18626560
#define P11 18647040
#define P12 18667520
#define P13 18761728
#define P14 18855936
#define P15 18856000
#define P16 18856128
#define P17 18856256
#define P18 18858496

__global__ __launch_bounds__(256) void prep_kernel(
    const float* __restrict__ gg_nf, const float* __restrict__ gg_ef,
    const float* __restrict__ lg_nf,
    const float* __restrict__ W_ni1, const float* __restrict__ W_nj1,
    const float* __restrict__ W_fij1,
    const float* __restrict__ W_ni2a, const float* __restrict__ W_nj2a,
    const float* __restrict__ W_ni2b, const float* __restrict__ W_nj2b,
    const float* __restrict__ W_fij2a, const float* __restrict__ W_fij2b,
    const float* __restrict__ W_node1, const float* __restrict__ W_node2a,
    const float* __restrict__ W_node2b,
    const float* __restrict__ b_node1, const float* __restrict__ b_node2a,
    const float* __restrict__ b_node2b,
    const float* __restrict__ attn1, const float* __restrict__ bias1,
    const float* __restrict__ b2a, const float* __restrict__ b2b,
    u16* __restrict__ gg_nf_bf, u16* __restrict__ gg_ef_bf, u16* __restrict__ lg_nf_bf,
    u16* __restrict__ wt_ninj1, u16* __restrict__ wt_fij1,
    u16* __restrict__ wt_ninj2a, u16* __restrict__ wt_ninj2b,
    u16* __restrict__ wt_fij2a, u16* __restrict__ wt_fij2b,
    u16* __restrict__ wt_cat1, u16* __restrict__ wt_cat2a, u16* __restrict__ wt_cat2b,
    float* __restrict__ bsum1, float* __restrict__ bsum2a, float* __restrict__ bsum2b,
    float* __restrict__ attn_p1, float* __restrict__ bias_cat1,
    float* __restrict__ bias_cat2a, float* __restrict__ bias_cat2b) {
    int i = blockIdx.x * 256 + threadIdx.x;
    if (i >= P18) return;
    if (i < P0) cvt_one(gg_nf, gg_nf_bf, i, 40, 64);
    else if (i < P1) cvt_one(gg_ef, gg_ef_bf, i - P0, 10, 32);
    else if (i < P2) cvt_one(lg_nf, lg_nf_bf, i - P1, 92, 96);
    else if (i < P3) whp_one(W_ni1, 288, wt_ninj1, i - P2, 40, 64);
    else if (i < P4) whp_one(W_nj1, 288, wt_ninj1 + 320 * 64, i - P3, 40, 64);
    else if (i < P5) whp_one(W_fij1, 288, wt_fij1, i - P4, 10, 32);
    else if (i < P6) wtr_one(W_ni2a, 320, wt_ninj2a, i - P5, 92, 96);
    else if (i < P7) wtr_one(W_nj2a, 320, wt_ninj2a + 320 * 96, i - P6, 92, 96);
    else if (i < P8) wtr_one(W_ni2b, 320, wt_ninj2b, i - P7, 92, 96);
    else if (i < P9) wtr_one(W_nj2b, 320, wt_ninj2b + 320 * 96, i - P8, 92, 96);
    else if (i < P10) wtr_one(W_fij2a, 320, wt_fij2a, i - P9, 40, 64);
    else if (i < P11) wtr_one(W_fij2b, 320, wt_fij2b, i - P10, 40, 64);
    else if (i < P12) wcat_one(W_node1, 320, wt_cat1, i - P11, 40, 40, 320);
    else if (i < P13) wcat_one(W_node2a, 736, wt_cat2a, i - P12, 92, 92, 736);
    else if (i < P14) wcat_one(W_node2b, 736, wt_cat2b, i - P13, 92, 92, 736);
    else if (i < P15) bh_one(b_node1, bsum1, i - P14, 40, 8);
    else if (i < P16) bh_one(b_node2a, bsum2a, i - P15, 92, 8);
    else if (i < P17) bh_one(b_node2b, bsum2b, i - P16, 92, 8);
    else {
        int j = i - P17;
        if (j < 320) {
            int hh = j / 40, f = j - hh * 40;
            attn_p1[j] = (f < 36) ? attn1[hh * 36 + f] : 0.f;
        } else if (j < 960) {
            int m = j - 320;
            int hh = m / 40, f = m - hh * 40;
            bias_cat1[m] = (m < 320 && f < 36) ? bias1[hh * 36 + f]
                                               : ((m < 320) ? 0.f : 0.f);
            if (m >= 320) bias_cat1[m] = 0.f;
        } else if (j < 1600) {
            int m = j - 960;
            bias_cat2a[m] = (m < 320) ? b2a[m] : 0.f;
        } else {
            int m = j - 1600;
            bias_cat2b[m] = (m < 320) ? b2b[m] : 0.f;
        }
    }
}

// ---------------- row-strip bf16 MFMA GEMM, LDS-staged full-line epilogue ----------------
template <int KPAD>
__global__ __launch_bounds__(256) void gemm_bf_kernel(const u16* __restrict__ A,
                                                      const u16* __restrict__ Wt,
                                                      const float* __restrict__ bias,
                                                      u16* __restrict__ C, int Ncols,
                                                      int Nstride, int ytiles) {
    __shared__ u16 st[4][16 * 72];
    const int m0 = blockIdx.x * 64;
    const int wv = threadIdx.x >> 6;
    const int lane = threadIdx.x & 63;
    const int q = lane >> 4;
    const int mr = lane & 15;
    constexpr int KS = KPAD / 32;

    const u16* Arow = A + (size_t)(m0 + wv * 16 + mr) * KPAD;
    bf16x8 af[KS];
#pragma unroll
    for (int k = 0; k < KS; ++k) af[k] = *(const bf16x8*)(Arow + k * 32 + q * 8);

    u16* myst = st[wv];
    const int rrow = lane >> 3;
    const int rcol = (lane & 7) * 8;
    const int yend = blockIdx.y * ytiles + ytiles;

    for (int yt = blockIdx.y * ytiles; yt < yend; ++yt) {
        const int n0 = yt * 64;
        f32x4 acc[4];
#pragma unroll
        for (int t = 0; t < 4; ++t) acc[t] = (f32x4){0.f, 0.f, 0.f, 0.f};
#pragma unroll
        for (int k = 0; k < KS; ++k)
#pragma unroll
            for (int t = 0; t < 4; ++t) {
                bf16x8 bv = *(const bf16x8*)(Wt + (size_t)(n0 + t * 16 + mr) * KPAD + k * 32 + q * 8);
                acc[t] = __builtin_amdgcn_mfma_f32_16x16x32_bf16(af[k], bv, acc[t], 0, 0, 0);
            }
#pragma unroll
        for (int t = 0; t < 4; ++t) {
            const int colme = n0 + t * 16 + mr;
            const float bb = (bias && colme < Ncols) ? bias[colme] : 0.f;
#pragma unroll
            for (int r = 0; r < 4; ++r)
                myst[(q * 4 + r) * 72 + t * 16 + mr] = f2bf(acc[t][r] + bb);
        }
        bf16x8 v0 = *(const bf16x8*)(myst + rrow * 72 + rcol);
        bf16x8 v1 = *(const bf16x8*)(myst + (rrow + 8) * 72 + rcol);
        const int gcol = n0 + rcol;
        if (gcol < Ncols) {
            const int grow = m0 + wv * 16 + rrow;
            *(bf16x8*)(C + (size_t)grow * Nstride + gcol) = v0;
            *(bf16x8*)(C + (size_t)(grow + 8) * Nstride + gcol) = v1;
        }
    }
}

// ---------------- FUSED: edge-projection GEMM (-> LDS) + edge combine ----------------
// AMODE 0: A = bf16 slab [CH][KPAD]. AMODE 1 (KPAD=64): A row e composed on
// the fly as bf16(ef32[e][c] + y2n[e>>1][c]) for c<40, 0 pad (kills ef2a).
// FSMODE: 0 none; 1 fp32 out stride 36; 2 bf16 out stride 64 (cols 40..63
// zeroed by h==1 lanes so downstream KPAD=64 reads see clean pad).
template <int KPAD, int FSMODE, int AMODE>
__global__ __launch_bounds__(128) void pe_edge_kernel(
    const u16* __restrict__ A,
    const u16* __restrict__ Wt,       // [320][KPAD]
    const int* __restrict__ src, const int* __restrict__ dst,
    const u16* __restrict__ Pn,       // [N][640]
    const float* __restrict__ attn,   // [320]
    float* __restrict__ esc,          // [E][8]
    void* __restrict__ fsum,
    const float* __restrict__ ef32,   // AMODE 1: [E][40] fp32
    const u16* __restrict__ yadd,     // AMODE 1: [E/2][40] bf16
    int e0, int CH, int fsumE) {
    constexpr int KS = KPAD / 32;
    __shared__ u16 pe[16][328];
    const int wv = threadIdx.x >> 6;  // 0..1
    const int lane = threadIdx.x & 63;
    const int q = lane >> 4;
    const int mr = lane & 15;
    const int m0 = blockIdx.x * 16;

    // ---- phase 1: GEMM into LDS ----
    {
        bf16x8 af[KS];
        if (AMODE == 0) {
            const u16* Arow = A + (size_t)(m0 + mr) * KPAD;
#pragma unroll
            for (int k = 0; k < KS; ++k) af[k] = *(const bf16x8*)(Arow + k * 32 + q * 8);
        } else {
            const int row = m0 + mr;
            {
                const float* ep = ef32 + (size_t)row * 40 + q * 8;
                f32x4 eA = *(const f32x4*)ep;
                f32x4 eB = *(const f32x4*)(ep + 4);
                bf16x8 yv = *(const bf16x8*)(yadd + (size_t)(row >> 1) * 40 + q * 8);
                bf16x8 r;
#pragma unroll
                for (int j = 0; j < 4; ++j) r[j] = (short)f2bf(eA[j] + bf2f((u16)yv[j]));
#pragma unroll
                for (int j = 4; j < 8; ++j) r[j] = (short)f2bf(eB[j - 4] + bf2f((u16)yv[j]));
                af[0] = r;
            }
            {
                bf16x8 r = (bf16x8){0, 0, 0, 0, 0, 0, 0, 0};
                if (q == 0) {
                    const float* ep = ef32 + (size_t)row * 40 + 32;
                    f32x4 eA = *(const f32x4*)ep;
                    f32x4 eB = *(const f32x4*)(ep + 4);
                    bf16x8 yv = *(const bf16x8*)(yadd + (size_t)(row >> 1) * 40 + 32);
#pragma unroll
                    for (int j = 0; j < 4; ++j) r[j] = (short)f2bf(eA[j] + bf2f((u16)yv[j]));
#pragma unroll
                    for (int j = 4; j < 8; ++j) r[j] = (short)f2bf(eB[j - 4] + bf2f((u16)yv[j]));
                }
                af[1] = r;
            }
        }
        const int t0 = wv * 10;
        f32x4 acc[10];
#pragma unroll
        for (int t = 0; t < 10; ++t) acc[t] = (f32x4){0.f, 0.f, 0.f, 0.f};
#pragma unroll
        for (int k = 0; k < KS; ++k)
#pragma unroll
            for (int t = 0; t < 10; ++t) {
                bf16x8 bv = *(const bf16x8*)(Wt + (size_t)((t0 + t) * 16 + mr) * KPAD + k * 32 + q * 8);
                acc[t] = __builtin_amdgcn_mfma_f32_16x16x32_bf16(af[k], bv, acc[t], 0, 0, 0);
            }
#pragma unroll
        for (int t = 0; t < 10; ++t)
#pragma unroll
            for (int r = 0; r < 4; ++r)
                pe[q * 4 + r][(t0 + t) * 16 + mr] = f2bf(acc[t][r]);
    }
    __syncthreads();

    // ---- phase 2: combine, 8 edges per wave, 1-deep prefetch ----
    const int lc = (lane < 40) ? lane : 39;
    const int h = lc / 5, o = lc - h * 5;
    const int c = h * 40 + o * 8;
    const bool act = (lane < 40);

    float attn_r[8];
#pragma unroll
    for (int j = 0; j < 8; ++j) attn_r[j] = attn[c + j];

    const int row0 = wv * 8;
    int e = e0 + m0 + row0;
    int s = src[e], d = dst[e];
    bf16x8 api = *(const bf16x8*)(Pn + (size_t)s * 640 + c);
    bf16x8 apj = *(const bf16x8*)(Pn + (size_t)d * 640 + 320 + c);

#pragma unroll
    for (int ei = 0; ei < 8; ++ei) {
        bf16x8 napi, napj;
        if (ei < 7) {
            const int ne = e + 1;
            const int ns = src[ne], nd = dst[ne];
            napi = *(const bf16x8*)(Pn + (size_t)ns * 640 + c);
            napj = *(const bf16x8*)(Pn + (size_t)nd * 640 + 320 + c);
        }
        const int row = row0 + ei;
        bf16x8 ape = *(const bf16x8*)(&pe[row][c]);

        float v[8];
        float ehp = 0.f;
#pragma unroll
        for (int j = 0; j < 8; ++j) {
            float x = bf2f((u16)api[j]) + bf2f((u16)apj[j]) + bf2f((u16)ape[j]);
            x = x > 0.f ? x : 0.01f * x;   // leaky_relu(0.01)
            v[j] = x;
            ehp += x * attn_r[j];
        }
        float eh = 0.f;
#pragma unroll
        for (int k = 0; k < 5; ++k) eh += __shfl(ehp, h * 5 + k, 64);
        if (act && o == 0) esc[(size_t)e * 8 + h] = eh;

        if (FSMODE != 0 && e < fsumE) {
#pragma unroll
            for (int m = 4; m >= 1; m >>= 1) {
                const int p = (h ^ m) * 5 + o;
#pragma unroll
                for (int j = 0; j < 8; ++j) v[j] += __shfl(v[j], p, 64);
            }
            if (act && h == 0) {
#pragma unroll
                for (int j = 0; j < 8; ++j) {
                    const int f = o * 8 + j;
                    if (FSMODE == 1) {
                        if (f < 36) ((float*)fsum)[(size_t)e * 36 + f] = v[j];
                    } else {
                        ((u16*)fsum)[(size_t)e * 64 + f] = f2bf(v[j]);
                    }
                }
            }
            if (FSMODE == 2 && act && h == 1 && o < 3) {
#pragma unroll
                for (int j = 0; j < 8; ++j)
                    ((u16*)fsum)[(size_t)e * 64 + 40 + o * 8 + j] = (u16)0;
            }
        }
        if (ei < 7) {
            api = napi;
            apj = napj;
        }
        ++e;
    }
}

// ---------------- CSR build (both graphs fused) ----------------
__global__ __launch_bounds__(256) void hist2_kernel(const int* __restrict__ gdst,
                                                    const int* __restrict__ ldst,
                                                    int* __restrict__ gcnt,
                                                    int* __restrict__ lcnt) {
    int i = blockIdx.x * 256 + threadIdx.x;
    if (i < EG) atomicAdd(&gcnt[gdst[i]], 1);
    else if (i < EG + EL) atomicAdd(&lcnt[ldst[i - EG]], 1);
}

__global__ __launch_bounds__(1024) void scan_block2_kernel(const int* __restrict__ gcnt,
                                                           const int* __restrict__ lcnt,
                                                           int* __restrict__ grow,
                                                           int* __restrict__ lrow,
                                                           int* __restrict__ bsum) {
    __shared__ int sd[1024];
    const bool isg = blockIdx.x < 75;
    const int* cnt = isg ? gcnt : lcnt;
    int* excl = isg ? grow : lrow;
    const int N = isg ? NG : NL;
    const int b = isg ? blockIdx.x : blockIdx.x - 75;
    int* bs = bsum + (isg ? 0 : 75);
    const int tid = threadIdx.x;
    const int i = b * 1024 + tid;
    int v = (i < N) ? cnt[i] : 0;
    sd[tid] = v;
    __syncthreads();
    for (int off = 1; off < 1024; off <<= 1) {
        int t = (tid >= off) ? sd[tid - off] : 0;
        __syncthreads();
        sd[tid] += t;
        __syncthreads();
    }
    if (i < N) excl[i] = sd[tid] - v;
    if (tid == 1023) bs[b] = sd[1023];
}

__global__ void scan_top2_kernel(int* __restrict__ bsum) {
    if (blockIdx.x == 0 && threadIdx.x < 2) {
        const int b0 = (threadIdx.x == 0) ? 0 : 75;
        const int nb = (threadIdx.x == 0) ? 75 : 38;
        int run = 0;
        for (int b = 0; b < nb; ++b) {
            int t = bsum[b0 + b];
            bsum[b0 + b] = run;
            run += t;
        }
    }
}

__global__ __launch_bounds__(256) void scan_add2_kernel(int* __restrict__ grow,
                                                        int* __restrict__ lrow,
                                                        const int* __restrict__ bsum) {
    int i = blockIdx.x * 256 + threadIdx.x;
    if (i < NG) {
        grow[i] += bsum[i >> 10];
        if (i == 0) grow[NG] = EG;
    } else if (i < NG + NL) {
        int j = i - NG;
        lrow[j] += bsum[75 + (j >> 10)];
        if (j == 0) lrow[NL] = EL;
    }
}

__global__ __launch_bounds__(256) void scatter2_kernel(const int* __restrict__ gdst,
                                                       const int* __restrict__ gsrc,
                                                       const int* __restrict__ ldst,
                                                       const int* __restrict__ lsrc,
                                                       const int* __restrict__ grow,
                                                       const int* __restrict__ lrow,
                                                       int* __restrict__ gcur,
                                                       int* __restrict__ lcur,
                                                       int* __restrict__ geidx,
                                                       int* __restrict__ gsrcs,
                                                       int* __restrict__ leidx,
                                                       int* __restrict__ lsrcs) {
    int i = blockIdx.x * 256 + threadIdx.x;
    if (i < EG) {
        int d = gdst[i];
        int pos = grow[d] + atomicAdd(&gcur[d], 1);
        geidx[pos] = i;
        gsrcs[pos] = gsrc[i];
    } else if (i < EG + EL) {
        int j = i - EG;
        int d = ldst[j];
        int pos = lrow[d] + atomicAdd(&lcur[d], 1);
        leidx[pos] = j;
        lsrcs[pos] = lsrc[j];
    }
}

// ---------------- CSR softmax ----------------
template <int GH>
__global__ __launch_bounds__(256) void csr_softmax_kernel(
    const int* __restrict__ row_ptr, const int* __restrict__ eidx,
    const float* __restrict__ esc, float* __restrict__ wcsr, int N) {
    constexpr int NS = 64 / GH;
    const int wid = threadIdx.x >> 6;
    const int lane = threadIdx.x & 63;
    const int nid = blockIdx.x * 4 + wid;
    if (nid >= N) return;
    const int r0 = row_ptr[nid], r1 = row_ptr[nid + 1];
    const int h = lane & (GH - 1);
    const int slot = lane / GH;

    float mx = -1e30f;
    for (int i = r0 + slot; i < r1; i += NS)
        mx = fmaxf(mx, esc[(size_t)eidx[i] * GH + h]);
#pragma unroll
    for (int m = GH; m < 64; m <<= 1) mx = fmaxf(mx, __shfl_xor(mx, m, 64));

    float den = 0.f;
    for (int i = r0 + slot; i < r1; i += NS)
        den += expf(esc[(size_t)eidx[i] * GH + h] - mx);
#pragma unroll
    for (int m = GH; m < 64; m <<= 1) den += __shfl_xor(den, m, 64);
    const float rden = 1.f / den;

    for (int i = r0 + slot; i < r1; i += NS)
        wcsr[(size_t)i * GH + h] = expf(esc[(size_t)eidx[i] * GH + h] - mx) * rden;
}

// ---------------- FUSED: raw node aggregation (16 nodes -> LDS) + Wcat GEMM ----------------
template <int Fn, int GH, int NFS, int KIN, int NOUT, int NTILES>
__global__ __launch_bounds__(256) void node_agg_gemm_kernel(
    const int* __restrict__ row_ptr,
    const int* __restrict__ srcs,
    const float* __restrict__ wcsr,
    const u16* __restrict__ nf,
    const u16* __restrict__ Wcat,
    const float* __restrict__ bsum,
    u16* __restrict__ outp,
    int N) {
    constexpr int PAIRS = Fn / 2;
    constexpr int KINP = KIN + 8;
    __shared__ u16 tile[16][KINP];
    __shared__ u16 ot[16][NTILES * 16];
    const int wv = threadIdx.x >> 6;
    const int lane = threadIdx.x & 63;
    const int q = lane >> 4;
    const int mr = lane & 15;
    const int nblk = blockIdx.x * 16;

    {
        const int col = 2 * lane;
        const bool act = (lane < PAIRS);
#pragma unroll
        for (int nn = 0; nn < 4; ++nn) {
            const int nid = nblk + wv * 4 + nn;
            const int r0 = row_ptr[nid], r1 = row_ptr[nid + 1];
            float a0[GH], a1[GH];
#pragma unroll
            for (int h = 0; h < GH; ++h) { a0[h] = 0.f; a1[h] = 0.f; }
            for (int i = r0; i < r1; i += 4) {
                const u16* prs[4];
                float wvv[4][GH];
#pragma unroll
                for (int b = 0; b < 4; ++b) {
                    const int ii = (i + b < r1) ? (i + b) : (r1 - 1);
                    prs[b] = nf + (size_t)srcs[ii] * NFS;
                    const float live = (i + b < r1) ? 1.f : 0.f;
                    const float* wp = wcsr + (size_t)ii * GH;
#pragma unroll
                    for (int h = 0; h < GH; ++h) wvv[b][h] = wp[h] * live;
                }
                if (act) {
                    unsigned pv[4];
#pragma unroll
                    for (int b = 0; b < 4; ++b) pv[b] = *(const unsigned*)(prs[b] + col);
#pragma unroll
                    for (int b = 0; b < 4; ++b) {
                        const float lo = bf2f((u16)(pv[b] & 0xFFFFu));
                        const float hi = bf2f((u16)(pv[b] >> 16));
#pragma unroll
                        for (int h = 0; h < GH; ++h) {
                            a0[h] += wvv[b][h] * lo;
                            a1[h] += wvv[b][h] * hi;
                        }
                    }
                }
            }
            if (act) {
                u16* ob = tile[wv * 4 + nn];
#pragma unroll
                for (int h = 0; h < GH; ++h) {
                    unsigned pk = (unsigned)f2bf(a0[h]) | ((unsigned)f2bf(a1[h]) << 16);
                    *(unsigned*)(ob + h * Fn + col) = pk;
                }
            }
        }
    }
    __syncthreads();

    {
        const int t0 = wv;
        const int t1 = wv + 4;
        f32x4 acc0 = (f32x4){0.f, 0.f, 0.f, 0.f};
        f32x4 acc1 = (f32x4){0.f, 0.f, 0.f, 0.f};
#pragma unroll
        for (int k0 = 0; k0 < KIN; k0 += 32) {
            bf16x8 af = *(const bf16x8*)(&tile[mr][k0 + q * 8]);
            if (t0 < NTILES) {
                bf16x8 bv = *(const bf16x8*)(Wcat + (size_t)(t0 * 16 + mr) * KIN + k0 + q * 8);
                acc0 = __builtin_amdgcn_mfma_f32_16x16x32_bf16(af, bv, acc0, 0, 0, 0);
            }
            if (t1 < NTILES) {
                bf16x8 bv = *(const bf16x8*)(Wcat + (size_t)(t1 * 16 + mr) * KIN + k0 + q * 8);
                acc1 = __builtin_amdgcn_mfma_f32_16x16x32_bf16(af, bv, acc1, 0, 0, 0);
            }
        }
        if (t0 < NTILES) {
            const float bb = bsum[t0 * 16 + mr];
#pragma unroll
            for (int r = 0; r < 4; ++r) ot[q * 4 + r][t0 * 16 + mr] = f2bf(acc0[r] + bb);
        }
        if (t1 < NTILES) {
            const float bb = bsum[t1 * 16 + mr];
#pragma unroll
            for (int r = 0; r < 4; ++r) ot[q * 4 + r][t1 * 16 + mr] = f2bf(acc1[r] + bb);
        }
    }
    __syncthreads();

    constexpr int DW = NOUT / 2;
    for (int idx = threadIdx.x; idx < 16 * DW; idx += 256) {
        const int row = idx / DW, c2 = idx - row * DW;
        unsigned pk = *(const unsigned*)(&ot[row][c2 * 2]);
        *(unsigned*)(outp + (size_t)(nblk + row) * NOUT + c2 * 2) = pk;
    }
}

// ---------------- readout: cooperative row-major reads + LDS reduce ----------------
__global__ __launch_bounds__(256) void readout_kernel(const u16* __restrict__ nfb,
                                                      const float* __restrict__ y22p,
                                                      const float* __restrict__ Wr1,
                                                      const float* __restrict__ br1,
                                                      const float* __restrict__ Wr2,
                                                      const float* __restrict__ br2,
                                                      float* __restrict__ out) {
    const int b = blockIdx.x;
    const int t = threadIdx.x;
    __shared__ float sA[20][96];
    __shared__ float sB[28][36];
    __shared__ float y[128];
    __shared__ float hh[128];
    __shared__ float red[128];
    if (t < 240) {
        const int cc = t % 12, rg = t / 12;
        float s[8];
#pragma unroll
        for (int j = 0; j < 8; ++j) s[j] = 0.f;
        const u16* base = nfb + (size_t)b * 600 * 96 + cc * 8;
        for (int i = rg; i < 600; i += 20) {
            bf16x8 v = *(const bf16x8*)(base + (size_t)i * 96);
#pragma unroll
            for (int j = 0; j < 8; ++j) s[j] += bf2f((u16)v[j]);
        }
#pragma unroll
        for (int j = 0; j < 8; ++j) sA[rg][cc * 8 + j] = s[j];
    }
    if (t < 252) {
        const int cc = t % 9, rg = t / 9;
        float s0 = 0.f, s1 = 0.f, s2 = 0.f, s3 = 0.f;
        const float* base = y22p + (size_t)b * 1200 * 36 + cc * 4;
        for (int i = rg; i < 1200; i += 28) {
            const float* p = base + (size_t)i * 36;
            s0 += p[0]; s1 += p[1]; s2 += p[2]; s3 += p[3];
        }
        sB[rg][cc * 4 + 0] = s0;
        sB[rg][cc * 4 + 1] = s1;
        sB[rg][cc * 4 + 2] = s2;
        sB[rg][cc * 4 + 3] = s3;
    }
    __syncthreads();
    if (t < 92) {
        float s = 0.f;
        for (int r = 0; r < 20; ++r) s += sA[r][t];
        y[t] = s * (1.f / 600.f);
    } else if (t >= 128 && t < 164) {
        const int f = t - 128;
        float s = 0.f;
        for (int r = 0; r < 28; ++r) s += sB[r][f];
        y[92 + f] = s * (1.f / 1200.f);
    }
    __syncthreads();
    if (t < 128) {
        float s = br1[t];
        for (int c = 0; c < 128; ++c) s += y[c] * Wr1[(size_t)c * 128 + t];
        hh[t] = sigmoidf(s);
    }
    __syncthreads();
    if (t < 128) red[t] = hh[t] * Wr2[t];
    __syncthreads();
    for (int k = 64; k > 0; k >>= 1) {
        if (t < k) red[t] += red[t + k];
        __syncthreads();
    }
    if (t == 0) out[b] = sigmoidf(red[0] + br2[0]);
}

// ---------------- host side ----------------
static inline int cdiv(int a, int b) { return (a + b - 1) / b; }

extern "C" void kernel_launch(void* const* d_in, const int* in_sizes, int n_in,
                              void* d_out, int out_size, void* d_ws, size_t ws_size,
                              hipStream_t stream) {
    const int* gg_src = (const int*)d_in[0];
    const int* gg_dst = (const int*)d_in[1];
    const float* gg_nf = (const float*)d_in[2];
    const float* gg_ef = (const float*)d_in[3];
    const int* lg_src = (const int*)d_in[4];
    const int* lg_dst = (const int*)d_in[5];
    const float* lg_nf = (const float*)d_in[6];
    const float* lg_ef = (const float*)d_in[7];
    const float* W_node1 = (const float*)d_in[8];
    const float* b_node1 = (const float*)d_in[9];
    const float* W_ni1 = (const float*)d_in[10];
    const float* W_nj1 = (const float*)d_in[11];
    const float* W_fij1 = (const float*)d_in[12];
    const float* attn1 = (const float*)d_in[13];
    const float* bias1 = (const float*)d_in[14];
    const float* W_node2a = (const float*)d_in[15];
    const float* b_node2a = (const float*)d_in[16];
    const float* W_ni2a = (const float*)d_in[17];
    const float* W_nj2a = (const float*)d_in[18];
    const float* W_fij2a = (const float*)d_in[19];
    const float* attn2a = (const float*)d_in[20];
    const float* bias2a = (const float*)d_in[21];
    const float* W_node2b = (const float*)d_in[22];
    const float* b_node2b = (const float*)d_in[23];
    const float* W_ni2b = (const float*)d_in[24];
    const float* W_nj2b = (const float*)d_in[25];
    const float* W_fij2b = (const float*)d_in[26];
    const float* attn2b = (const float*)d_in[27];
    const float* bias2b = (const float*)d_in[28];
    const float* Wr1 = (const float*)d_in[29];
    const float* br1 = (const float*)d_in[30];
    const float* Wr2 = (const float*)d_in[31];
    const float* br2 = (const float*)d_in[32];
    float* out = (float*)d_out;

    char* ws = (char*)d_ws;
    size_t off = 0;
    auto take = [&](size_t bytes) {
        size_t o = off;
        off += (bytes + 255) & ~(size_t)255;
        return (void*)(ws + o);
    };
    u16* y2n = (u16*)take((size_t)NG * 40 * 2);
    float* y22p = (float*)take((size_t)NG * 36 * 4);
    float* esc = (float*)take((size_t)EG * 8 * 4);
    float* wcsr = (float*)take((size_t)EG * 8 * 4);
    int* gg_row = (int*)take((size_t)(NG + 1) * 4);
    int* gg_eidx = (int*)take((size_t)EG * 4);
    int* gg_srcs = (int*)take((size_t)EG * 4);
    int* lg_row = (int*)take((size_t)(NL + 1) * 4);
    int* lg_eidx = (int*)take((size_t)EL * 4);
    int* lg_srcs = (int*)take((size_t)EL * 4);
    int* cnt_both = (int*)take((size_t)(NG + NL) * 4);
    int* gg_cnt = cnt_both;
    int* lg_cnt = cnt_both + NG;
    int* bsum = (int*)take((size_t)128 * 4);
    u16* gg_nf_bf = (u16*)take((size_t)NG * 64 * 2);
    u16* gg_ef_bf = (u16*)take((size_t)EG * 32 * 2);
    u16* lg_nf_bf = (u16*)take((size_t)NL * 96 * 2);
    u16* nfa_bf = (u16*)take((size_t)NL * 96 * 2);
    u16* nfb_bf = (u16*)take((size_t)NL * 96 * 2);
    u16* ef_shared = (u16*)take((size_t)EL * 64 * 2);   // efa fsum (2a writes, 2b reads)
    u16* wt_ninj1 = (u16*)take((size_t)640 * 64 * 2);
    u16* wt_fij1 = (u16*)take((size_t)320 * 32 * 2);
    u16* wt_ninj2a = (u16*)take((size_t)640 * 96 * 2);
    u16* wt_ninj2b = (u16*)take((size_t)640 * 96 * 2);
    u16* wt_fij2a = (u16*)take((size_t)320 * 64 * 2);
    u16* wt_fij2b = (u16*)take((size_t)320 * 64 * 2);
    u16* wt_cat1 = (u16*)take((size_t)64 * 320 * 2);
    u16* wt_cat2a = (u16*)take((size_t)128 * 736 * 2);
    u16* wt_cat2b = (u16*)take((size_t)128 * 736 * 2);
    float* bsum1 = (float*)take((size_t)64 * 4);
    float* bsum2a = (float*)take((size_t)128 * 4);
    float* bsum2b = (float*)take((size_t)128 * 4);
    float* attn_p1 = (float*)take((size_t)320 * 4);
    float* bias_cat1 = (float*)take((size_t)640 * 4);
    float* bias_cat2a = (float*)take((size_t)640 * 4);
    float* bias_cat2b = (float*)take((size_t)640 * 4);
    u16* slab = (u16*)take((size_t)NG * 640 * 2);   // Pn1 / Pn2 slabs

    // ---------------- CSR build (fused both graphs) ----------------
    hipMemsetAsync(cnt_both, 0, (size_t)(NG + NL) * 4, stream);
    hist2_kernel<<<cdiv(EG + EL, 256), 256, 0, stream>>>(gg_dst, lg_dst, gg_cnt, lg_cnt);
    scan_block2_kernel<<<113, 1024, 0, stream>>>(gg_cnt, lg_cnt, gg_row, lg_row, bsum);
    scan_top2_kernel<<<1, 64, 0, stream>>>(bsum);
    scan_add2_kernel<<<cdiv(NG + NL, 256), 256, 0, stream>>>(gg_row, lg_row, bsum);
    hipMemsetAsync(cnt_both, 0, (size_t)(NG + NL) * 4, stream);
    scatter2_kernel<<<cdiv(EG + EL, 256), 256, 0, stream>>>(
        gg_dst, gg_src, lg_dst, lg_src, gg_row, lg_row, gg_cnt, lg_cnt,
        gg_eidx, gg_srcs, lg_eidx, lg_srcs);

    // ---------------- mega prep ----------------
    prep_kernel<<<cdiv(P18, 256), 256, 0, stream>>>(
        gg_nf, gg_ef, lg_nf,
        W_ni1, W_nj1, W_fij1,
        W_ni2a, W_nj2a, W_ni2b, W_nj2b, W_fij2a, W_fij2b,
        W_node1, W_node2a, W_node2b,
        b_node1, b_node2a, b_node2b,
        attn1, bias1, bias2a, bias2b,
        gg_nf_bf, gg_ef_bf, lg_nf_bf,
        wt_ninj1, wt_fij1, wt_ninj2a, wt_ninj2b, wt_fij2a, wt_fij2b,
        wt_cat1, wt_cat2a, wt_cat2b,
        bsum1, bsum2a, bsum2b,
        attn_p1, bias_cat1, bias_cat2a, bias_cat2b);

    // ---------------- stage 1 (gg) ----------------
    {
        u16* Pn1 = slab;                                  // [NG][640]
        gemm_bf_kernel<64><<<dim3(NG / 64, 2), 256, 0, stream>>>(
            gg_nf_bf, wt_ninj1, bias_cat1, Pn1, 640, 640, 5);
        pe_edge_kernel<32, 1, 0><<<EG / 16, 128, 0, stream>>>(
            gg_ef_bf, wt_fij1, gg_src, gg_dst, Pn1, attn_p1, esc, y22p,
            nullptr, nullptr, 0, EG, NG);
        csr_softmax_kernel<8><<<NG / 4, 256, 0, stream>>>(gg_row, gg_eidx, esc, wcsr, NG);
        node_agg_gemm_kernel<40, 8, 64, 320, 40, 3><<<NG / 16, 256, 0, stream>>>(
            gg_row, gg_srcs, wcsr, gg_nf_bf, wt_cat1, bsum1, y2n, NG);
    }

    // ---------------- stage 2 (lg), two layers ----------------
    for (int layer = 0; layer < 2; ++layer) {
        const bool a = (layer == 0);
        const u16* nf_in = a ? lg_nf_bf : nfa_bf;
        const u16* Wninj = a ? wt_ninj2a : wt_ninj2b;
        const u16* Wfij = a ? wt_fij2a : wt_fij2b;
        const u16* Wcat = a ? wt_cat2a : wt_cat2b;
        const float* bs = a ? bsum2a : bsum2b;
        const float* bcat = a ? bias_cat2a : bias_cat2b;
        const float* at = a ? attn2a : attn2b;
        u16* nf_out = a ? nfa_bf : nfb_bf;

        u16* Pn2 = slab;                                  // [NL][640]
        gemm_bf_kernel<96><<<dim3(NL / 64, 5), 256, 0, stream>>>(
            nf_in, Wninj, bcat, Pn2, 640, 640, 2);
        if (a)
            pe_edge_kernel<64, 2, 1><<<EL / 16, 128, 0, stream>>>(
                nullptr, Wfij, lg_src, lg_dst, Pn2, at, esc, ef_shared,
                lg_ef, y2n, 0, EL, EL);
        else
            pe_edge_kernel<64, 0, 0><<<EL / 16, 128, 0, stream>>>(
                ef_shared, Wfij, lg_src, lg_dst, Pn2, at, esc, nullptr,
                nullptr, nullptr, 0, EL, 0);
        csr_softmax_kernel<8><<<NL / 4, 256, 0, stream>>>(lg_row, lg_eidx, esc, wcsr, NL);
        node_agg_gemm_kernel<92, 8, 96, 736, 96, 6><<<NL / 16, 256, 0, stream>>>(
            lg_row, lg_srcs, wcsr, nf_in, Wcat, bs, nf_out, NL);
    }

    // ---------------- readout ----------------
    readout_kernel<<<NB, 256, 0, stream>>>(nfb_bf, y22p, Wr1, br1, Wr2, br2, out);
}